// Round 8
// baseline (2862.010 us; speedup 1.0000x reference)
//
#include <hip/hip_runtime.h>
#include <cstdint>

#define HID 2048
#define SLEN 2048
#define NH 8
#define HD 256
#define MTOT 4096

constexpr float SCALING = 0.0625f;   // 256^-0.5
constexpr float SOFTCAP = 50.0f;

// ---------------- fp32 GEMM: C[M,N] = A[M,K] @ B[K,N], all row-major ----------------
// 128x128 tile, BK=16, 256 threads, 8x8 accumulators per thread.
__global__ __launch_bounds__(256) void gemm128(
    const float* __restrict__ A, const float* __restrict__ B,
    float* __restrict__ C, int M, int N, int K) {
  __shared__ __align__(16) float As[16][132];  // [k][m], +4 pad
  __shared__ __align__(16) float Bs[16][132];  // [k][n], +4 pad
  const int tid = threadIdx.x;
  const int row0 = blockIdx.y * 128;
  const int col0 = blockIdx.x * 128;
  const int ty = tid >> 4, tx = tid & 15;
  const int a_r = tid >> 2;          // 0..63
  const int a_c = (tid & 3) * 4;     // 0,4,8,12
  const int b_k = tid >> 5;          // 0..7
  const int b_n = (tid & 31) * 4;    // 0..124

  float acc[8][8];
  #pragma unroll
  for (int i = 0; i < 8; ++i)
    #pragma unroll
    for (int j = 0; j < 8; ++j) acc[i][j] = 0.f;

  for (int k0 = 0; k0 < K; k0 += 16) {
    const float4 av0 = *(const float4*)&A[(size_t)(row0 + a_r) * K + k0 + a_c];
    const float4 av1 = *(const float4*)&A[(size_t)(row0 + a_r + 64) * K + k0 + a_c];
    const float4 bv0 = *(const float4*)&B[(size_t)(k0 + b_k) * N + col0 + b_n];
    const float4 bv1 = *(const float4*)&B[(size_t)(k0 + b_k + 8) * N + col0 + b_n];
    __syncthreads();  // previous tile fully consumed before overwrite
    As[a_c + 0][a_r] = av0.x; As[a_c + 1][a_r] = av0.y;
    As[a_c + 2][a_r] = av0.z; As[a_c + 3][a_r] = av0.w;
    As[a_c + 0][a_r + 64] = av1.x; As[a_c + 1][a_r + 64] = av1.y;
    As[a_c + 2][a_r + 64] = av1.z; As[a_c + 3][a_r + 64] = av1.w;
    *(float4*)&Bs[b_k][b_n] = bv0;
    *(float4*)&Bs[b_k + 8][b_n] = bv1;
    __syncthreads();
    #pragma unroll
    for (int kk = 0; kk < 16; ++kk) {
      const float4 A0 = *(const float4*)&As[kk][ty * 8];
      const float4 A1 = *(const float4*)&As[kk][ty * 8 + 4];
      const float4 B0 = *(const float4*)&Bs[kk][tx * 8];
      const float4 B1 = *(const float4*)&Bs[kk][tx * 8 + 4];
      const float a_[8] = {A0.x, A0.y, A0.z, A0.w, A1.x, A1.y, A1.z, A1.w};
      const float b_[8] = {B0.x, B0.y, B0.z, B0.w, B1.x, B1.y, B1.z, B1.w};
      #pragma unroll
      for (int i = 0; i < 8; ++i)
        #pragma unroll
        for (int j = 0; j < 8; ++j)
          acc[i][j] = fmaf(a_[i], b_[j], acc[i][j]);
    }
  }
  #pragma unroll
  for (int i = 0; i < 8; ++i) {
    float* cp = &C[(size_t)(row0 + ty * 8 + i) * N + col0 + tx * 8];
    float4 c0 = {acc[i][0], acc[i][1], acc[i][2], acc[i][3]};
    float4 c1 = {acc[i][4], acc[i][5], acc[i][6], acc[i][7]};
    *(float4*)&cp[0] = c0;
    *(float4*)&cp[4] = c1;
  }
}

// ------------- A-projections + RoPE + rank contraction, one block per token -------------
// Writes q,k,v in [B, NH, S, HD] layout; q pre-scaled by SCALING/Q_RANK, k,v by 1/2.
__global__ __launch_bounds__(256) void qkv_rope(
    const float* __restrict__ hs,
    const float* __restrict__ WAq, const float* __restrict__ WAk,
    const float* __restrict__ WAv,
    const float* __restrict__ Bq, const float* __restrict__ Bk,
    const float* __restrict__ Bv,
    const float* __restrict__ fc, const float* __restrict__ fs,
    float* __restrict__ q, float* __restrict__ k, float* __restrict__ v) {
  const int m = blockIdx.x;        // 0..4095  (b*SLEN + s)
  const int s = m & (SLEN - 1);
  const int b = m >> 11;
  const int tid = threadIdx.x;
  __shared__ __align__(16) float xs[HID];   // hidden row, 8 KB
  __shared__ float part[240];
  __shared__ float Al[80];                  // A_q[48] | A_k[16] | A_v[16]

  #pragma unroll
  for (int it = 0; it < 2; ++it) {
    const int idx = tid + 256 * it;  // float4 index 0..511
    *(float4*)&xs[idx * 4] = *(const float4*)&hs[(size_t)m * HID + idx * 4];
  }
  __syncthreads();

  if (tid < 240) {
    int c = tid % 80;
    const int seg = tid / 80;
    const int kb = (seg * HID) / 3, ke = ((seg + 1) * HID) / 3;
    const float* W; int nc;
    if (c < 48)      { W = WAq; nc = 48; }
    else if (c < 64) { W = WAk; nc = 16; c -= 48; }
    else             { W = WAv; nc = 16; c -= 64; }
    float acc = 0.f;
    for (int kk = kb; kk < ke; ++kk) acc = fmaf(xs[kk], W[(size_t)kk * nc + c], acc);
    part[tid] = acc;
  }
  __syncthreads();
  if (tid < 80) Al[tid] = part[tid] + part[tid + 80] + part[tid + 160];
  __syncthreads();

  const size_t tbase = (size_t)b * NH * SLEN * HD + (size_t)s * HD;
  if (tid < 128) {
    // q: rank 6, 8 heads. Thread owns rope-pair j.
    const int j = tid;
    const float cz = fc[s * 128 + j], sz = fs[s * 128 + j];
    float qe[8], qo[8];
    #pragma unroll
    for (int hh = 0; hh < 8; ++hh) { qe[hh] = 0.f; qo[hh] = 0.f; }
    #pragma unroll
    for (int r = 0; r < 6; ++r) {
      const float2 x = *(const float2*)&Bq[(size_t)m * 1536 + r * 256 + 2 * j];
      const float re = x.x * cz - x.y * sz;
      const float ro = x.x * sz + x.y * cz;
      #pragma unroll
      for (int hh = 0; hh < 8; ++hh) {
        const float a = Al[hh * 6 + r];
        qe[hh] = fmaf(a, re, qe[hh]);
        qo[hh] = fmaf(a, ro, qo[hh]);
      }
    }
    const float qs = SCALING / 6.f;
    #pragma unroll
    for (int hh = 0; hh < 8; ++hh) {
      float2 o; o.x = qe[hh] * qs; o.y = qo[hh] * qs;
      *(float2*)&q[tbase + (size_t)hh * SLEN * HD + 2 * j] = o;
    }
  } else {
    // k (rank 2, roped) and v (rank 2, no rope)
    const int j = tid - 128;
    const float cz = fc[s * 128 + j], sz = fs[s * 128 + j];
    float ke_[8], ko_[8], ve_[8], vo_[8];
    #pragma unroll
    for (int hh = 0; hh < 8; ++hh) { ke_[hh]=0.f; ko_[hh]=0.f; ve_[hh]=0.f; vo_[hh]=0.f; }
    #pragma unroll
    for (int r = 0; r < 2; ++r) {
      const float2 xk = *(const float2*)&Bk[(size_t)m * 512 + r * 256 + 2 * j];
      const float2 xv = *(const float2*)&Bv[(size_t)m * 512 + r * 256 + 2 * j];
      const float re = xk.x * cz - xk.y * sz;
      const float ro = xk.x * sz + xk.y * cz;
      #pragma unroll
      for (int hh = 0; hh < 8; ++hh) {
        const float ak = Al[48 + hh * 2 + r];
        const float av = Al[64 + hh * 2 + r];
        ke_[hh] = fmaf(ak, re, ke_[hh]);
        ko_[hh] = fmaf(ak, ro, ko_[hh]);
        ve_[hh] = fmaf(av, xv.x, ve_[hh]);
        vo_[hh] = fmaf(av, xv.y, vo_[hh]);
      }
    }
    #pragma unroll
    for (int hh = 0; hh < 8; ++hh) {
      float2 ok; ok.x = ke_[hh] * 0.5f; ok.y = ko_[hh] * 0.5f;
      *(float2*)&k[tbase + (size_t)hh * SLEN * HD + 2 * j] = ok;
      float2 ov; ov.x = ve_[hh] * 0.5f; ov.y = vo_[hh] * 0.5f;
      *(float2*)&v[tbase + (size_t)hh * SLEN * HD + 2 * j] = ov;
    }
  }
}

// ------------- causal softcapped attention, fixed-max softmax (scores bounded ±50) -----
// v3: row-pair reuse. 512 threads = 32 row-pairs x 16 lanes (16-float d-slice).
// Thread owns rows (p, p+32): every K/V float4 read from LDS feeds BOTH rows
// (1 FLOP/B, was 0.5), and the wave's 4 row-pair groups read the SAME K/V row j
// -> same-address LDS broadcast, cutting distinct bank traffic ~8x. Kernel moves
// from LDS-BW-bound (52 of 69 TB/s, r7 counters) to VALU-issue-bound.
__global__ __launch_bounds__(512, 4) void attn(
    const float* __restrict__ q, const float* __restrict__ k,
    const float* __restrict__ v, float* __restrict__ out) {
  __shared__ __align__(16) float Ks[32 * 256];  // 32 KB
  __shared__ __align__(16) float Vs[32 * 256];  // 32 KB
  const int tid = threadIdx.x;
  const int p = tid >> 4;     // row-pair index 0..31 -> rows p, p+32
  const int g = tid & 15;     // 16-float d-slice
  const int bid = blockIdx.x;
  const int qt = 31 - (bid >> 4);   // heavy tiles dispatched first (LPT)
  const int bh = bid & 15;          // b*8 + h
  const int b = bh >> 3;
  const int h = bh & 7;
  const int q0 = qt * 64;
  const size_t base = (size_t)bh * SLEN * HD;

  float qr[2][16], accv[2][16];
  float den[2] = {0.f, 0.f};
  #pragma unroll
  for (int r = 0; r < 2; ++r) {
    const float* qp = &q[base + (size_t)(q0 + p + 32 * r) * HD + g * 16];
    #pragma unroll
    for (int c4 = 0; c4 < 4; ++c4) {
      const float4 t = *(const float4*)&qp[c4 * 4];
      qr[r][c4*4+0] = t.x; qr[r][c4*4+1] = t.y;
      qr[r][c4*4+2] = t.z; qr[r][c4*4+3] = t.w;
    }
    #pragma unroll
    for (int c = 0; c < 16; ++c) accv[r][c] = 0.f;
  }

  const int nkt = 2 * qt + 2;
  const float* kb_ = &k[base];
  const float* vb_ = &v[base];
  for (int kt = 0; kt < nkt; ++kt) {
    const int k0 = kt * 32;
    __syncthreads();
    #pragma unroll
    for (int it = 0; it < 4; ++it) {
      const int l = tid + 512 * it;  // float4 index within 32x256 tile
      const int row = l >> 6;
      const int ch = l & 63;
      const int chs = ch ^ ((ch >> 3) & 7);
      *(float4*)&Ks[row * 256 + chs * 4] =
          *(const float4*)&kb_[(size_t)(k0 + row) * HD + ch * 4];
      *(float4*)&Vs[row * 256 + chs * 4] =
          *(const float4*)&vb_[(size_t)(k0 + row) * HD + ch * 4];
    }
    __syncthreads();
    const int jm0 = q0 + p - k0 + 1;        // causal bound for row p
    const int jm1 = jm0 + 32;               // and for row p+32
    for (int j = 0; j < 32; ++j) {
      const float* krow = &Ks[j * 256];
      float p0a = 0.f, p0b = 0.f, p1a = 0.f, p1b = 0.f;  // 2 chains per row
      #pragma unroll
      for (int c4 = 0; c4 < 4; ++c4) {
        const int ch = g * 4 + c4;
        const float4 t = *(const float4*)&krow[(ch ^ ((ch >> 3) & 7)) * 4];
        p0a = fmaf(qr[0][c4*4+0], t.x, p0a);
        p0a = fmaf(qr[0][c4*4+1], t.y, p0a);
        p0b = fmaf(qr[0][c4*4+2], t.z, p0b);
        p0b = fmaf(qr[0][c4*4+3], t.w, p0b);
        p1a = fmaf(qr[1][c4*4+0], t.x, p1a);
        p1a = fmaf(qr[1][c4*4+1], t.y, p1a);
        p1b = fmaf(qr[1][c4*4+2], t.z, p1b);
        p1b = fmaf(qr[1][c4*4+3], t.w, p1b);
      }
      float pd0 = p0a + p0b, pd1 = p1a + p1b;
      pd0 += __shfl_xor(pd0, 1); pd1 += __shfl_xor(pd1, 1);
      pd0 += __shfl_xor(pd0, 2); pd1 += __shfl_xor(pd1, 2);
      pd0 += __shfl_xor(pd0, 4); pd1 += __shfl_xor(pd1, 4);
      pd0 += __shfl_xor(pd0, 8); pd1 += __shfl_xor(pd1, 8);
      // fused softcap+exp (fixed-max): e = exp(50*tanh(pd/50) - 50)
      //   = exp2(-144.26950409 / (exp2(0.0577078016*pd) + 1)); rcp via v_rcp_f32.
      const float t0 = exp2f(pd0 * 0.0577078016f);
      const float t1 = exp2f(pd1 * 0.0577078016f);
      float e0 = exp2f(-144.26950409f * __builtin_amdgcn_rcpf(t0 + 1.f));
      float e1 = exp2f(-144.26950409f * __builtin_amdgcn_rcpf(t1 + 1.f));
      if (j >= jm0) e0 = 0.f;
      if (j >= jm1) e1 = 0.f;
      den[0] += e0; den[1] += e1;
      const float* vrow = &Vs[j * 256];
      #pragma unroll
      for (int c4 = 0; c4 < 4; ++c4) {
        const int ch = g * 4 + c4;
        const float4 t = *(const float4*)&vrow[(ch ^ ((ch >> 3) & 7)) * 4];
        accv[0][c4*4+0] = fmaf(e0, t.x, accv[0][c4*4+0]);
        accv[0][c4*4+1] = fmaf(e0, t.y, accv[0][c4*4+1]);
        accv[0][c4*4+2] = fmaf(e0, t.z, accv[0][c4*4+2]);
        accv[0][c4*4+3] = fmaf(e0, t.w, accv[0][c4*4+3]);
        accv[1][c4*4+0] = fmaf(e1, t.x, accv[1][c4*4+0]);
        accv[1][c4*4+1] = fmaf(e1, t.y, accv[1][c4*4+1]);
        accv[1][c4*4+2] = fmaf(e1, t.z, accv[1][c4*4+2]);
        accv[1][c4*4+3] = fmaf(e1, t.w, accv[1][c4*4+3]);
      }
    }
  }
  #pragma unroll
  for (int r = 0; r < 2; ++r) {
    const float inv = 1.f / den[r];
    float* op = &out[((size_t)(b * SLEN + q0 + p + 32 * r)) * (NH * HD) + h * HD + g * 16];
    #pragma unroll
    for (int c4 = 0; c4 < 4; ++c4) {
      float4 o = {accv[r][c4*4]*inv, accv[r][c4*4+1]*inv,
                  accv[r][c4*4+2]*inv, accv[r][c4*4+3]*inv};
      *(float4*)&op[c4 * 4] = o;
    }
  }
}

extern "C" void kernel_launch(void* const* d_in, const int* in_sizes, int n_in,
                              void* d_out, int out_size, void* d_ws, size_t ws_size,
                              hipStream_t stream) {
  const float* hs  = (const float*)d_in[0];
  const float* fc  = (const float*)d_in[1];
  const float* fs  = (const float*)d_in[2];
  // d_in[3] = mask: pure causal by construction, handled analytically.
  const float* WAq = (const float*)d_in[4];
  const float* WAk = (const float*)d_in[5];
  const float* WAv = (const float*)d_in[6];
  const float* WBq = (const float*)d_in[7];
  const float* WBk = (const float*)d_in[8];
  const float* WBv = (const float*)d_in[9];
  const float* Wo  = (const float*)d_in[10];
  float* out = (float*)d_out;

  // Workspace layout (floats).
  // att ALIASES Bq+Bk: Bq/Bk are last read by qkv_rope, att first written by
  // attn (runs strictly after) -> safe. Peak footprint = 142.6 MB.
  float* ws  = (float*)d_ws;
  float* Bq  = ws;                               // 4096*1536          (25.2 MB)
  float* Bk  = Bq + (size_t)MTOT * 1536;         // 4096*512           ( 8.4 MB)
  float* Bv  = Bk + (size_t)MTOT * 512;          // 4096*512           ( 8.4 MB)
  float* qT  = Bv + (size_t)MTOT * 512;          // [2,8,2048,256]     (33.5 MB)
  float* kT  = qT + (size_t)2 * NH * SLEN * HD;  //                    (33.5 MB)
  float* vT  = kT + (size_t)2 * NH * SLEN * HD;  //                    (33.5 MB)
  float* att = ws;                               // [4096,2048] over Bq+Bk (33.5 MB)

  gemm128<<<dim3(1536 / 128, MTOT / 128), 256, 0, stream>>>(hs, WBq, Bq, MTOT, 1536, HID);
  gemm128<<<dim3(512 / 128,  MTOT / 128), 256, 0, stream>>>(hs, WBk, Bk, MTOT, 512, HID);
  gemm128<<<dim3(512 / 128,  MTOT / 128), 256, 0, stream>>>(hs, WBv, Bv, MTOT, 512, HID);
  qkv_rope<<<MTOT, 256, 0, stream>>>(hs, WAq, WAk, WAv, Bq, Bk, Bv, fc, fs, qT, kT, vT);
  attn<<<dim3(32 * 16), 512, 0, stream>>>(qT, kT, vT, att);
  gemm128<<<dim3(HID / 128, MTOT / 128), 256, 0, stream>>>(att, Wo, out, MTOT, HID, HID);
}

// Round 9
// 2064.253 us; speedup vs baseline: 1.3865x; 1.3865x over previous
//
#include <hip/hip_runtime.h>
#include <cstdint>

#define HID 2048
#define SLEN 2048
#define NH 8
#define HD 256
#define MTOT 4096

constexpr float SCALING = 0.0625f;   // 256^-0.5
constexpr float SOFTCAP = 50.0f;

typedef __attribute__((ext_vector_type(8))) short short8;
typedef __attribute__((ext_vector_type(4))) float f32x4;

// ---------------- split-bf16 MFMA GEMM: C[M,N] = A[M,2048] @ B[2048,N] ----------------
// A = Ah + Al (truncation split: Ah = trunc-bf16(A), Al = trunc-bf16(A - Ah), exact sub).
// C ~= Ah*Bh + Ah*Bl + Al*Bh  (Al*Bl ~ 2^-16 rel, dropped) -> fp32-class accuracy.
// 128x128 block tile, 256 thr = 4 waves (2x2), wave tile 64x64 = 4x4 frags of
// mfma_f32_16x16x32_bf16. LDS holds tiles in FRAGMENT-NATIVE layout: frag f is
// 64 lanes x 8 bf16 contiguous (1040 B padded) -> ds_read_b128 at lane*16, dense,
// conflict-free. A-frag: lane l = A[f*16 + (l&15)][8*(l>>4)+e]; B-frag:
// lane l = B[8*(l>>4)+e][f*16 + (l&15)]; C/D: row=(l>>4)*4+reg, col=l&15 (m89).
__device__ __forceinline__ uint16_t bfhi(float x) {
  return (uint16_t)(__float_as_uint(x) >> 16);           // truncate
}
__device__ __forceinline__ float bf2f(uint16_t h) {
  return __uint_as_float((uint32_t)h << 16);
}

__global__ __launch_bounds__(256) void gemm_mfma(
    const float* __restrict__ A, const float* __restrict__ B,
    float* __restrict__ C, int N) {
  __shared__ uint16_t Ah[8 * 520], Al[8 * 520], Bh[8 * 520], Bl[8 * 520];
  const int tid = threadIdx.x;
  const int row0 = blockIdx.y * 128;
  const int col0 = blockIdx.x * 128;
  const int lane = tid & 63;
  const int wv = tid >> 6;
  const int wr = wv >> 1, wc = wv & 1;     // wave 2x2 within block

  f32x4 acc[4][4];
  #pragma unroll
  for (int m = 0; m < 4; ++m)
    #pragma unroll
    for (int n = 0; n < 4; ++n) acc[m][n] = (f32x4){0.f, 0.f, 0.f, 0.f};

  const int ar = tid >> 1;             // A stage: row 0..127
  const int akb = (tid & 1) * 16;      //          k half
  const int bkk = tid >> 3;            // B stage: k row 0..31
  const int bcg = tid & 7;             //          col group (16 cols)

  for (int k0 = 0; k0 < 2048; k0 += 32) {
    float4 av[4], bv[4];
    #pragma unroll
    for (int c = 0; c < 4; ++c)
      av[c] = *(const float4*)&A[(size_t)(row0 + ar) * 2048 + k0 + akb + 4 * c];
    #pragma unroll
    for (int c = 0; c < 4; ++c)
      bv[c] = *(const float4*)&B[(size_t)(k0 + bkk) * N + col0 + bcg * 16 + 4 * c];
    __syncthreads();   // previous tile fully consumed
    #pragma unroll
    for (int c = 0; c < 4; ++c) {
      const int kk = akb + 4 * c;
      const int idx = (ar >> 4) * 520 + (((ar & 15) | ((kk >> 3) << 4)) << 3) + (kk & 7);
      const float x0 = av[c].x, x1 = av[c].y, x2 = av[c].z, x3 = av[c].w;
      const uint16_t h0 = bfhi(x0), h1 = bfhi(x1), h2 = bfhi(x2), h3 = bfhi(x3);
      const uint16_t g0 = bfhi(x0 - bf2f(h0)), g1 = bfhi(x1 - bf2f(h1));
      const uint16_t g2 = bfhi(x2 - bf2f(h2)), g3 = bfhi(x3 - bf2f(h3));
      *(uint2*)&Ah[idx] = make_uint2((uint32_t)h0 | ((uint32_t)h1 << 16),
                                     (uint32_t)h2 | ((uint32_t)h3 << 16));
      *(uint2*)&Al[idx] = make_uint2((uint32_t)g0 | ((uint32_t)g1 << 16),
                                     (uint32_t)g2 | ((uint32_t)g3 << 16));
    }
    #pragma unroll
    for (int c = 0; c < 4; ++c) {
      const float xs4[4] = {bv[c].x, bv[c].y, bv[c].z, bv[c].w};
      #pragma unroll
      for (int i = 0; i < 4; ++i) {
        const int j = bcg * 16 + 4 * c + i;
        const uint16_t h = bfhi(xs4[i]);
        const uint16_t g = bfhi(xs4[i] - bf2f(h));
        const int idx = (j >> 4) * 520 + (((j & 15) | ((bkk >> 3) << 4)) << 3) + (bkk & 7);
        Bh[idx] = h;
        Bl[idx] = g;
      }
    }
    __syncthreads();
    short8 bhf[4], blf[4];
    #pragma unroll
    for (int nf = 0; nf < 4; ++nf) {
      bhf[nf] = *(const short8*)&Bh[(wc * 4 + nf) * 520 + lane * 8];
      blf[nf] = *(const short8*)&Bl[(wc * 4 + nf) * 520 + lane * 8];
    }
    #pragma unroll
    for (int m = 0; m < 4; ++m) {
      const short8 ahf = *(const short8*)&Ah[(wr * 4 + m) * 520 + lane * 8];
      const short8 alf = *(const short8*)&Al[(wr * 4 + m) * 520 + lane * 8];
      #pragma unroll
      for (int nf = 0; nf < 4; ++nf) {
        acc[m][nf] = __builtin_amdgcn_mfma_f32_16x16x32_bf16(ahf, bhf[nf], acc[m][nf], 0, 0, 0);
        acc[m][nf] = __builtin_amdgcn_mfma_f32_16x16x32_bf16(ahf, blf[nf], acc[m][nf], 0, 0, 0);
        acc[m][nf] = __builtin_amdgcn_mfma_f32_16x16x32_bf16(alf, bhf[nf], acc[m][nf], 0, 0, 0);
      }
    }
  }
  #pragma unroll
  for (int m = 0; m < 4; ++m)
    #pragma unroll
    for (int nf = 0; nf < 4; ++nf) {
      const int row = row0 + wr * 64 + m * 16 + ((lane >> 4) << 2);
      const int col = col0 + wc * 64 + nf * 16 + (lane & 15);
      #pragma unroll
      for (int ri = 0; ri < 4; ++ri)
        C[(size_t)(row + ri) * N + col] = acc[m][nf][ri];
    }
}

// ------------- A-projections + RoPE + rank contraction, one block per token -------------
// Writes q,k,v in [B, NH, S, HD] layout; q pre-scaled by SCALING/Q_RANK, k,v by 1/2.
__global__ __launch_bounds__(256) void qkv_rope(
    const float* __restrict__ hs,
    const float* __restrict__ WAq, const float* __restrict__ WAk,
    const float* __restrict__ WAv,
    const float* __restrict__ Bq, const float* __restrict__ Bk,
    const float* __restrict__ Bv,
    const float* __restrict__ fc, const float* __restrict__ fs,
    float* __restrict__ q, float* __restrict__ k, float* __restrict__ v) {
  const int m = blockIdx.x;        // 0..4095  (b*SLEN + s)
  const int s = m & (SLEN - 1);
  const int b = m >> 11;
  const int tid = threadIdx.x;
  __shared__ __align__(16) float xs[HID];   // hidden row, 8 KB
  __shared__ float part[240];
  __shared__ float Al[80];                  // A_q[48] | A_k[16] | A_v[16]

  #pragma unroll
  for (int it = 0; it < 2; ++it) {
    const int idx = tid + 256 * it;  // float4 index 0..511
    *(float4*)&xs[idx * 4] = *(const float4*)&hs[(size_t)m * HID + idx * 4];
  }
  __syncthreads();

  if (tid < 240) {
    int c = tid % 80;
    const int seg = tid / 80;
    const int kb = (seg * HID) / 3, ke = ((seg + 1) * HID) / 3;
    const float* W; int nc;
    if (c < 48)      { W = WAq; nc = 48; }
    else if (c < 64) { W = WAk; nc = 16; c -= 48; }
    else             { W = WAv; nc = 16; c -= 64; }
    float acc = 0.f;
    for (int kk = kb; kk < ke; ++kk) acc = fmaf(xs[kk], W[(size_t)kk * nc + c], acc);
    part[tid] = acc;
  }
  __syncthreads();
  if (tid < 80) Al[tid] = part[tid] + part[tid + 80] + part[tid + 160];
  __syncthreads();

  const size_t tbase = (size_t)b * NH * SLEN * HD + (size_t)s * HD;
  if (tid < 128) {
    // q: rank 6, 8 heads. Thread owns rope-pair j.
    const int j = tid;
    const float cz = fc[s * 128 + j], sz = fs[s * 128 + j];
    float qe[8], qo[8];
    #pragma unroll
    for (int hh = 0; hh < 8; ++hh) { qe[hh] = 0.f; qo[hh] = 0.f; }
    #pragma unroll
    for (int r = 0; r < 6; ++r) {
      const float2 x = *(const float2*)&Bq[(size_t)m * 1536 + r * 256 + 2 * j];
      const float re = x.x * cz - x.y * sz;
      const float ro = x.x * sz + x.y * cz;
      #pragma unroll
      for (int hh = 0; hh < 8; ++hh) {
        const float a = Al[hh * 6 + r];
        qe[hh] = fmaf(a, re, qe[hh]);
        qo[hh] = fmaf(a, ro, qo[hh]);
      }
    }
    const float qs = SCALING / 6.f;
    #pragma unroll
    for (int hh = 0; hh < 8; ++hh) {
      float2 o; o.x = qe[hh] * qs; o.y = qo[hh] * qs;
      *(float2*)&q[tbase + (size_t)hh * SLEN * HD + 2 * j] = o;
    }
  } else {
    // k (rank 2, roped) and v (rank 2, no rope)
    const int j = tid - 128;
    const float cz = fc[s * 128 + j], sz = fs[s * 128 + j];
    float ke_[8], ko_[8], ve_[8], vo_[8];
    #pragma unroll
    for (int hh = 0; hh < 8; ++hh) { ke_[hh]=0.f; ko_[hh]=0.f; ve_[hh]=0.f; vo_[hh]=0.f; }
    #pragma unroll
    for (int r = 0; r < 2; ++r) {
      const float2 xk = *(const float2*)&Bk[(size_t)m * 512 + r * 256 + 2 * j];
      const float2 xv = *(const float2*)&Bv[(size_t)m * 512 + r * 256 + 2 * j];
      const float re = xk.x * cz - xk.y * sz;
      const float ro = xk.x * sz + xk.y * cz;
      #pragma unroll
      for (int hh = 0; hh < 8; ++hh) {
        const float ak = Al[48 + hh * 2 + r];
        const float av = Al[64 + hh * 2 + r];
        ke_[hh] = fmaf(ak, re, ke_[hh]);
        ko_[hh] = fmaf(ak, ro, ko_[hh]);
        ve_[hh] = fmaf(av, xv.x, ve_[hh]);
        vo_[hh] = fmaf(av, xv.y, vo_[hh]);
      }
    }
    #pragma unroll
    for (int hh = 0; hh < 8; ++hh) {
      float2 ok; ok.x = ke_[hh] * 0.5f; ok.y = ko_[hh] * 0.5f;
      *(float2*)&k[tbase + (size_t)hh * SLEN * HD + 2 * j] = ok;
      float2 ov; ov.x = ve_[hh] * 0.5f; ov.y = vo_[hh] * 0.5f;
      *(float2*)&v[tbase + (size_t)hh * SLEN * HD + 2 * j] = ov;
    }
  }
}

// ------------- causal softcapped attention (v3, unchanged this round) -----
__global__ __launch_bounds__(512, 4) void attn(
    const float* __restrict__ q, const float* __restrict__ k,
    const float* __restrict__ v, float* __restrict__ out) {
  __shared__ __align__(16) float Ks[32 * 256];  // 32 KB
  __shared__ __align__(16) float Vs[32 * 256];  // 32 KB
  const int tid = threadIdx.x;
  const int p = tid >> 4;     // row-pair index 0..31 -> rows p, p+32
  const int g = tid & 15;     // 16-float d-slice
  const int bid = blockIdx.x;
  const int qt = 31 - (bid >> 4);   // heavy tiles dispatched first (LPT)
  const int bh = bid & 15;          // b*8 + h
  const int b = bh >> 3;
  const int h = bh & 7;
  const int q0 = qt * 64;
  const size_t base = (size_t)bh * SLEN * HD;

  float qr[2][16], accv[2][16];
  float den[2] = {0.f, 0.f};
  #pragma unroll
  for (int r = 0; r < 2; ++r) {
    const float* qp = &q[base + (size_t)(q0 + p + 32 * r) * HD + g * 16];
    #pragma unroll
    for (int c4 = 0; c4 < 4; ++c4) {
      const float4 t = *(const float4*)&qp[c4 * 4];
      qr[r][c4*4+0] = t.x; qr[r][c4*4+1] = t.y;
      qr[r][c4*4+2] = t.z; qr[r][c4*4+3] = t.w;
    }
    #pragma unroll
    for (int c = 0; c < 16; ++c) accv[r][c] = 0.f;
  }

  const int nkt = 2 * qt + 2;
  const float* kb_ = &k[base];
  const float* vb_ = &v[base];
  for (int kt = 0; kt < nkt; ++kt) {
    const int k0 = kt * 32;
    __syncthreads();
    #pragma unroll
    for (int it = 0; it < 4; ++it) {
      const int l = tid + 512 * it;  // float4 index within 32x256 tile
      const int row = l >> 6;
      const int ch = l & 63;
      const int chs = ch ^ ((ch >> 3) & 7);
      *(float4*)&Ks[row * 256 + chs * 4] =
          *(const float4*)&kb_[(size_t)(k0 + row) * HD + ch * 4];
      *(float4*)&Vs[row * 256 + chs * 4] =
          *(const float4*)&vb_[(size_t)(k0 + row) * HD + ch * 4];
    }
    __syncthreads();
    const int jm0 = q0 + p - k0 + 1;        // causal bound for row p
    const int jm1 = jm0 + 32;               // and for row p+32
    for (int j = 0; j < 32; ++j) {
      const float* krow = &Ks[j * 256];
      float p0a = 0.f, p0b = 0.f, p1a = 0.f, p1b = 0.f;  // 2 chains per row
      #pragma unroll
      for (int c4 = 0; c4 < 4; ++c4) {
        const int ch = g * 4 + c4;
        const float4 t = *(const float4*)&krow[(ch ^ ((ch >> 3) & 7)) * 4];
        p0a = fmaf(qr[0][c4*4+0], t.x, p0a);
        p0a = fmaf(qr[0][c4*4+1], t.y, p0a);
        p0b = fmaf(qr[0][c4*4+2], t.z, p0b);
        p0b = fmaf(qr[0][c4*4+3], t.w, p0b);
        p1a = fmaf(qr[1][c4*4+0], t.x, p1a);
        p1a = fmaf(qr[1][c4*4+1], t.y, p1a);
        p1b = fmaf(qr[1][c4*4+2], t.z, p1b);
        p1b = fmaf(qr[1][c4*4+3], t.w, p1b);
      }
      float pd0 = p0a + p0b, pd1 = p1a + p1b;
      pd0 += __shfl_xor(pd0, 1); pd1 += __shfl_xor(pd1, 1);
      pd0 += __shfl_xor(pd0, 2); pd1 += __shfl_xor(pd1, 2);
      pd0 += __shfl_xor(pd0, 4); pd1 += __shfl_xor(pd1, 4);
      pd0 += __shfl_xor(pd0, 8); pd1 += __shfl_xor(pd1, 8);
      // fused softcap+exp (fixed-max): e = exp(50*tanh(pd/50) - 50)
      const float t0 = exp2f(pd0 * 0.0577078016f);
      const float t1 = exp2f(pd1 * 0.0577078016f);
      float e0 = exp2f(-144.26950409f * __builtin_amdgcn_rcpf(t0 + 1.f));
      float e1 = exp2f(-144.26950409f * __builtin_amdgcn_rcpf(t1 + 1.f));
      if (j >= jm0) e0 = 0.f;
      if (j >= jm1) e1 = 0.f;
      den[0] += e0; den[1] += e1;
      const float* vrow = &Vs[j * 256];
      #pragma unroll
      for (int c4 = 0; c4 < 4; ++c4) {
        const int ch = g * 4 + c4;
        const float4 t = *(const float4*)&vrow[(ch ^ ((ch >> 3) & 7)) * 4];
        accv[0][c4*4+0] = fmaf(e0, t.x, accv[0][c4*4+0]);
        accv[0][c4*4+1] = fmaf(e0, t.y, accv[0][c4*4+1]);
        accv[0][c4*4+2] = fmaf(e0, t.z, accv[0][c4*4+2]);
        accv[0][c4*4+3] = fmaf(e0, t.w, accv[0][c4*4+3]);
        accv[1][c4*4+0] = fmaf(e1, t.x, accv[1][c4*4+0]);
        accv[1][c4*4+1] = fmaf(e1, t.y, accv[1][c4*4+1]);
        accv[1][c4*4+2] = fmaf(e1, t.z, accv[1][c4*4+2]);
        accv[1][c4*4+3] = fmaf(e1, t.w, accv[1][c4*4+3]);
      }
    }
  }
  #pragma unroll
  for (int r = 0; r < 2; ++r) {
    const float inv = 1.f / den[r];
    float* op = &out[((size_t)(b * SLEN + q0 + p + 32 * r)) * (NH * HD) + h * HD + g * 16];
    #pragma unroll
    for (int c4 = 0; c4 < 4; ++c4) {
      float4 o = {accv[r][c4*4]*inv, accv[r][c4*4+1]*inv,
                  accv[r][c4*4+2]*inv, accv[r][c4*4+3]*inv};
      *(float4*)&op[c4 * 4] = o;
    }
  }
}

extern "C" void kernel_launch(void* const* d_in, const int* in_sizes, int n_in,
                              void* d_out, int out_size, void* d_ws, size_t ws_size,
                              hipStream_t stream) {
  const float* hs  = (const float*)d_in[0];
  const float* fc  = (const float*)d_in[1];
  const float* fs  = (const float*)d_in[2];
  // d_in[3] = mask: pure causal by construction, handled analytically.
  const float* WAq = (const float*)d_in[4];
  const float* WAk = (const float*)d_in[5];
  const float* WAv = (const float*)d_in[6];
  const float* WBq = (const float*)d_in[7];
  const float* WBk = (const float*)d_in[8];
  const float* WBv = (const float*)d_in[9];
  const float* Wo  = (const float*)d_in[10];
  float* out = (float*)d_out;

  // Workspace layout (floats).
  // att ALIASES Bq+Bk: Bq/Bk are last read by qkv_rope, att first written by
  // attn (runs strictly after) -> safe. Peak footprint = 142.6 MB.
  float* ws  = (float*)d_ws;
  float* Bq  = ws;                               // 4096*1536          (25.2 MB)
  float* Bk  = Bq + (size_t)MTOT * 1536;         // 4096*512           ( 8.4 MB)
  float* Bv  = Bk + (size_t)MTOT * 512;          // 4096*512           ( 8.4 MB)
  float* qT  = Bv + (size_t)MTOT * 512;          // [2,8,2048,256]     (33.5 MB)
  float* kT  = qT + (size_t)2 * NH * SLEN * HD;  //                    (33.5 MB)
  float* vT  = kT + (size_t)2 * NH * SLEN * HD;  //                    (33.5 MB)
  float* att = ws;                               // [4096,2048] over Bq+Bk (33.5 MB)

  gemm_mfma<<<dim3(1536 / 128, MTOT / 128), 256, 0, stream>>>(hs, WBq, Bq, 1536);
  gemm_mfma<<<dim3(512 / 128,  MTOT / 128), 256, 0, stream>>>(hs, WBk, Bk, 512);
  gemm_mfma<<<dim3(512 / 128,  MTOT / 128), 256, 0, stream>>>(hs, WBv, Bv, 512);
  qkv_rope<<<MTOT, 256, 0, stream>>>(hs, WAq, WAk, WAv, Bq, Bk, Bv, fc, fs, qT, kT, vT);
  attn<<<dim3(32 * 16), 512, 0, stream>>>(qT, kT, vT, att);
  gemm_mfma<<<dim3(HID / 128, MTOT / 128), 256, 0, stream>>>(att, Wo, out, HID);
}

// Round 10
// 1079.034 us; speedup vs baseline: 2.6524x; 1.9131x over previous
//
#include <hip/hip_runtime.h>
#include <cstdint>

#define HID 2048
#define SLEN 2048
#define NH 8
#define HD 256
#define MTOT 4096

constexpr float SCALING = 0.0625f;   // 256^-0.5
constexpr float SOFTCAP = 50.0f;

typedef __attribute__((ext_vector_type(8))) short short8;
typedef __attribute__((ext_vector_type(4))) float f32x4;

__device__ __forceinline__ uint16_t bfhi(float x) {
  return (uint16_t)(__float_as_uint(x) >> 16);           // truncate
}
__device__ __forceinline__ float bf2f(uint16_t h) {
  return __uint_as_float((uint32_t)h << 16);
}
__device__ __forceinline__ void packsplit8(const float4 a, const float4 b,
                                           short8& hi, short8& lo) {
  const float x[8] = {a.x, a.y, a.z, a.w, b.x, b.y, b.z, b.w};
  #pragma unroll
  for (int i = 0; i < 8; ++i) {
    const uint32_t u = __float_as_uint(x[i]);
    const uint16_t h = (uint16_t)(u >> 16);
    const float r = x[i] - bf2f(h);
    hi[i] = (short)h;
    lo[i] = (short)(__float_as_uint(r) >> 16);
  }
}

// ---------------- split-bf16 MFMA GEMM: C[M,N] = A[M,2048] @ B[2048,N] ----------------
// (unchanged from round 9 — hardware-validated)
__global__ __launch_bounds__(256) void gemm_mfma(
    const float* __restrict__ A, const float* __restrict__ B,
    float* __restrict__ C, int N) {
  __shared__ uint16_t Ah[8 * 520], Al[8 * 520], Bh[8 * 520], Bl[8 * 520];
  const int tid = threadIdx.x;
  const int row0 = blockIdx.y * 128;
  const int col0 = blockIdx.x * 128;
  const int lane = tid & 63;
  const int wv = tid >> 6;
  const int wr = wv >> 1, wc = wv & 1;     // wave 2x2 within block

  f32x4 acc[4][4];
  #pragma unroll
  for (int m = 0; m < 4; ++m)
    #pragma unroll
    for (int n = 0; n < 4; ++n) acc[m][n] = (f32x4){0.f, 0.f, 0.f, 0.f};

  const int ar = tid >> 1;             // A stage: row 0..127
  const int akb = (tid & 1) * 16;      //          k half
  const int bkk = tid >> 3;            // B stage: k row 0..31
  const int bcg = tid & 7;             //          col group (16 cols)

  for (int k0 = 0; k0 < 2048; k0 += 32) {
    float4 av[4], bv[4];
    #pragma unroll
    for (int c = 0; c < 4; ++c)
      av[c] = *(const float4*)&A[(size_t)(row0 + ar) * 2048 + k0 + akb + 4 * c];
    #pragma unroll
    for (int c = 0; c < 4; ++c)
      bv[c] = *(const float4*)&B[(size_t)(k0 + bkk) * N + col0 + bcg * 16 + 4 * c];
    __syncthreads();   // previous tile fully consumed
    #pragma unroll
    for (int c = 0; c < 4; ++c) {
      const int kk = akb + 4 * c;
      const int idx = (ar >> 4) * 520 + (((ar & 15) | ((kk >> 3) << 4)) << 3) + (kk & 7);
      const float x0 = av[c].x, x1 = av[c].y, x2 = av[c].z, x3 = av[c].w;
      const uint16_t h0 = bfhi(x0), h1 = bfhi(x1), h2 = bfhi(x2), h3 = bfhi(x3);
      const uint16_t g0 = bfhi(x0 - bf2f(h0)), g1 = bfhi(x1 - bf2f(h1));
      const uint16_t g2 = bfhi(x2 - bf2f(h2)), g3 = bfhi(x3 - bf2f(h3));
      *(uint2*)&Ah[idx] = make_uint2((uint32_t)h0 | ((uint32_t)h1 << 16),
                                     (uint32_t)h2 | ((uint32_t)h3 << 16));
      *(uint2*)&Al[idx] = make_uint2((uint32_t)g0 | ((uint32_t)g1 << 16),
                                     (uint32_t)g2 | ((uint32_t)g3 << 16));
    }
    #pragma unroll
    for (int c = 0; c < 4; ++c) {
      const float xs4[4] = {bv[c].x, bv[c].y, bv[c].z, bv[c].w};
      #pragma unroll
      for (int i = 0; i < 4; ++i) {
        const int j = bcg * 16 + 4 * c + i;
        const uint16_t h = bfhi(xs4[i]);
        const uint16_t g = bfhi(xs4[i] - bf2f(h));
        const int idx = (j >> 4) * 520 + (((j & 15) | ((bkk >> 3) << 4)) << 3) + (bkk & 7);
        Bh[idx] = h;
        Bl[idx] = g;
      }
    }
    __syncthreads();
    short8 bhf[4], blf[4];
    #pragma unroll
    for (int nf = 0; nf < 4; ++nf) {
      bhf[nf] = *(const short8*)&Bh[(wc * 4 + nf) * 520 + lane * 8];
      blf[nf] = *(const short8*)&Bl[(wc * 4 + nf) * 520 + lane * 8];
    }
    #pragma unroll
    for (int m = 0; m < 4; ++m) {
      const short8 ahf = *(const short8*)&Ah[(wr * 4 + m) * 520 + lane * 8];
      const short8 alf = *(const short8*)&Al[(wr * 4 + m) * 520 + lane * 8];
      #pragma unroll
      for (int nf = 0; nf < 4; ++nf) {
        acc[m][nf] = __builtin_amdgcn_mfma_f32_16x16x32_bf16(ahf, bhf[nf], acc[m][nf], 0, 0, 0);
        acc[m][nf] = __builtin_amdgcn_mfma_f32_16x16x32_bf16(ahf, blf[nf], acc[m][nf], 0, 0, 0);
        acc[m][nf] = __builtin_amdgcn_mfma_f32_16x16x32_bf16(alf, bhf[nf], acc[m][nf], 0, 0, 0);
      }
    }
  }
  #pragma unroll
  for (int m = 0; m < 4; ++m)
    #pragma unroll
    for (int nf = 0; nf < 4; ++nf) {
      const int row = row0 + wr * 64 + m * 16 + ((lane >> 4) << 2);
      const int col = col0 + wc * 64 + nf * 16 + (lane & 15);
      #pragma unroll
      for (int ri = 0; ri < 4; ++ri)
        C[(size_t)(row + ri) * N + col] = acc[m][nf][ri];
    }
}

// ------------- A-projections + RoPE + rank contraction (unchanged) -------------
__global__ __launch_bounds__(256) void qkv_rope(
    const float* __restrict__ hs,
    const float* __restrict__ WAq, const float* __restrict__ WAk,
    const float* __restrict__ WAv,
    const float* __restrict__ Bq, const float* __restrict__ Bk,
    const float* __restrict__ Bv,
    const float* __restrict__ fc, const float* __restrict__ fs,
    float* __restrict__ q, float* __restrict__ k, float* __restrict__ v) {
  const int m = blockIdx.x;        // 0..4095  (b*SLEN + s)
  const int s = m & (SLEN - 1);
  const int b = m >> 11;
  const int tid = threadIdx.x;
  __shared__ __align__(16) float xs[HID];   // hidden row, 8 KB
  __shared__ float part[240];
  __shared__ float Al[80];                  // A_q[48] | A_k[16] | A_v[16]

  #pragma unroll
  for (int it = 0; it < 2; ++it) {
    const int idx = tid + 256 * it;  // float4 index 0..511
    *(float4*)&xs[idx * 4] = *(const float4*)&hs[(size_t)m * HID + idx * 4];
  }
  __syncthreads();

  if (tid < 240) {
    int c = tid % 80;
    const int seg = tid / 80;
    const int kb = (seg * HID) / 3, ke = ((seg + 1) * HID) / 3;
    const float* W; int nc;
    if (c < 48)      { W = WAq; nc = 48; }
    else if (c < 64) { W = WAk; nc = 16; c -= 48; }
    else             { W = WAv; nc = 16; c -= 64; }
    float acc = 0.f;
    for (int kk = kb; kk < ke; ++kk) acc = fmaf(xs[kk], W[(size_t)kk * nc + c], acc);
    part[tid] = acc;
  }
  __syncthreads();
  if (tid < 80) Al[tid] = part[tid] + part[tid + 80] + part[tid + 160];
  __syncthreads();

  const size_t tbase = (size_t)b * NH * SLEN * HD + (size_t)s * HD;
  if (tid < 128) {
    const int j = tid;
    const float cz = fc[s * 128 + j], sz = fs[s * 128 + j];
    float qe[8], qo[8];
    #pragma unroll
    for (int hh = 0; hh < 8; ++hh) { qe[hh] = 0.f; qo[hh] = 0.f; }
    #pragma unroll
    for (int r = 0; r < 6; ++r) {
      const float2 x = *(const float2*)&Bq[(size_t)m * 1536 + r * 256 + 2 * j];
      const float re = x.x * cz - x.y * sz;
      const float ro = x.x * sz + x.y * cz;
      #pragma unroll
      for (int hh = 0; hh < 8; ++hh) {
        const float a = Al[hh * 6 + r];
        qe[hh] = fmaf(a, re, qe[hh]);
        qo[hh] = fmaf(a, ro, qo[hh]);
      }
    }
    const float qs = SCALING / 6.f;
    #pragma unroll
    for (int hh = 0; hh < 8; ++hh) {
      float2 o; o.x = qe[hh] * qs; o.y = qo[hh] * qs;
      *(float2*)&q[tbase + (size_t)hh * SLEN * HD + 2 * j] = o;
    }
  } else {
    const int j = tid - 128;
    const float cz = fc[s * 128 + j], sz = fs[s * 128 + j];
    float ke_[8], ko_[8], ve_[8], vo_[8];
    #pragma unroll
    for (int hh = 0; hh < 8; ++hh) { ke_[hh]=0.f; ko_[hh]=0.f; ve_[hh]=0.f; vo_[hh]=0.f; }
    #pragma unroll
    for (int r = 0; r < 2; ++r) {
      const float2 xk = *(const float2*)&Bk[(size_t)m * 512 + r * 256 + 2 * j];
      const float2 xv = *(const float2*)&Bv[(size_t)m * 512 + r * 256 + 2 * j];
      const float re = xk.x * cz - xk.y * sz;
      const float ro = xk.x * sz + xk.y * cz;
      #pragma unroll
      for (int hh = 0; hh < 8; ++hh) {
        const float ak = Al[48 + hh * 2 + r];
        const float av = Al[64 + hh * 2 + r];
        ke_[hh] = fmaf(ak, re, ke_[hh]);
        ko_[hh] = fmaf(ak, ro, ko_[hh]);
        ve_[hh] = fmaf(av, xv.x, ve_[hh]);
        vo_[hh] = fmaf(av, xv.y, vo_[hh]);
      }
    }
    #pragma unroll
    for (int hh = 0; hh < 8; ++hh) {
      float2 ok; ok.x = ke_[hh] * 0.5f; ok.y = ko_[hh] * 0.5f;
      *(float2*)&k[tbase + (size_t)hh * SLEN * HD + 2 * j] = ok;
      float2 ov; ov.x = ve_[hh] * 0.5f; ov.y = vo_[hh] * 0.5f;
      *(float2*)&v[tbase + (size_t)hh * SLEN * HD + 2 * j] = ov;
    }
  }
}

// ------------- causal softcapped attention v4: MFMA -----------------------------------
// One (b,h) + 64 q-rows per block; 4 waves x 16 rows. Q split-bf16 in registers.
// QK^T = 3-term split (qh*kh + qh*kl + ql*kh) -> fp32-class scores; P,V plain bf16.
// K staged row-major bf16 [32][KLD=264] (pad -> <=2-way); V staged TRANSPOSED
// [256][VLD=34] so PV B-frags are contiguous b128; P round-trips via wave-private
// LDS [16][PLD=36]. Frag layouts identical to gemm_mfma (validated r9).
#define KLD 264
#define VLD 34
#define PLD 36
__global__ __launch_bounds__(256, 2) void attn_mfma(
    const float* __restrict__ q, const float* __restrict__ k,
    const float* __restrict__ v, float* __restrict__ out) {
  __shared__ uint16_t Khs[32 * KLD];   // 16896 B
  __shared__ uint16_t Kls[32 * KLD];   // 16896 B
  __shared__ uint16_t Vts[256 * VLD];  // 17408 B
  __shared__ uint16_t Ps[4 * 16 * PLD];//  4608 B   (total 55808 B -> 2 blocks/CU)
  const int tid = threadIdx.x;
  const int lane = tid & 63;
  const int w = tid >> 6;
  const int l15 = lane & 15;
  const int l4 = lane >> 4;
  const int bid = blockIdx.x;
  const int qt = 31 - (bid >> 4);      // heavy q-tiles first (LPT)
  const int bh = bid & 15;
  const int b = bh >> 3, h = bh & 7;
  const int q0 = qt * 64;
  const size_t base = (size_t)bh * SLEN * HD;

  // Q fragments in registers: rows q0+16w+l15, d = 32f + 8*l4 + e
  short8 qh[8], ql[8];
  {
    const float* qp = &q[base + (size_t)(q0 + w * 16 + l15) * HD + 8 * l4];
    #pragma unroll
    for (int f = 0; f < 8; ++f) {
      const float4 a = *(const float4*)&qp[32 * f];
      const float4 bb = *(const float4*)&qp[32 * f + 4];
      packsplit8(a, bb, qh[f], ql[f]);
    }
  }
  f32x4 acc[16];
  #pragma unroll
  for (int df = 0; df < 16; ++df) acc[df] = (f32x4){0.f, 0.f, 0.f, 0.f};
  float den[4] = {0.f, 0.f, 0.f, 0.f};

  const int myrow = q0 + w * 16 + l4 * 4;   // lane's base C row
  const int rowmax = q0 + w * 16 + 15;      // wave's last row
  const int nkt = 2 * qt + 2;
  const int sr = tid & 31;                  // staging: K/V row
  const int sc = (tid >> 5) * 32;           //          col chunk (32 f32)

  for (int kt = 0; kt < nkt; ++kt) {
    const int k0 = kt * 32;
    __syncthreads();   // everyone done reading previous tile
    {
      const float* kp = &k[base + (size_t)(k0 + sr) * HD + sc];
      #pragma unroll
      for (int j = 0; j < 4; ++j) {
        const float4 a = *(const float4*)&kp[8 * j];
        const float4 bb = *(const float4*)&kp[8 * j + 4];
        short8 hi, lo;
        packsplit8(a, bb, hi, lo);
        *(short8*)&Khs[sr * KLD + sc + 8 * j] = hi;
        *(short8*)&Kls[sr * KLD + sc + 8 * j] = lo;
      }
      const float* vp = &v[base + (size_t)(k0 + sr) * HD + sc];
      #pragma unroll
      for (int j = 0; j < 8; ++j) {
        const float4 a = *(const float4*)&vp[4 * j];
        Vts[(sc + 4 * j + 0) * VLD + sr] = bfhi(a.x);
        Vts[(sc + 4 * j + 1) * VLD + sr] = bfhi(a.y);
        Vts[(sc + 4 * j + 2) * VLD + sr] = bfhi(a.z);
        Vts[(sc + 4 * j + 3) * VLD + sr] = bfhi(a.w);
      }
    }
    __syncthreads();
    if (k0 > rowmax) continue;   // tile fully masked for this wave (barrier at loop top)

    // QK^T: 2 k-frags x 8 d-chunks x 3 split terms
    f32x4 sfr[2];
    #pragma unroll
    for (int kf = 0; kf < 2; ++kf) {
      f32x4 c = (f32x4){0.f, 0.f, 0.f, 0.f};
      #pragma unroll
      for (int dc = 0; dc < 8; ++dc) {
        const int off = (16 * kf + l15) * KLD + 32 * dc + 8 * l4;
        const short8 kh = *(const short8*)&Khs[off];
        const short8 kl = *(const short8*)&Kls[off];
        c = __builtin_amdgcn_mfma_f32_16x16x32_bf16(qh[dc], kh, c, 0, 0, 0);
        c = __builtin_amdgcn_mfma_f32_16x16x32_bf16(qh[dc], kl, c, 0, 0, 0);
        c = __builtin_amdgcn_mfma_f32_16x16x32_bf16(ql[dc], kh, c, 0, 0, 0);
      }
      sfr[kf] = c;
    }
    // softcap + exp (fixed-max) + causal mask; P -> wave-private LDS (bf16)
    uint16_t* pw = &Ps[w * 16 * PLD];
    #pragma unroll
    for (int kf = 0; kf < 2; ++kf) {
      #pragma unroll
      for (int ri = 0; ri < 4; ++ri) {
        const float pd = sfr[kf][ri];
        const float t1 = exp2f(pd * 0.0577078016f);
        float e = exp2f(-144.26950409f * __builtin_amdgcn_rcpf(t1 + 1.f));
        if (k0 + 16 * kf + l15 > myrow + ri) e = 0.f;
        den[ri] += e;
        pw[(l4 * 4 + ri) * PLD + 16 * kf + l15] = bfhi(e);
      }
    }
    // PV: A = P[16q][32j], B = Vt frags [32j][16d], 16 d-frags
    const short8 pa = *(const short8*)&pw[l15 * PLD + 8 * l4];
    #pragma unroll
    for (int df = 0; df < 16; ++df) {
      const short8 vb = *(const short8*)&Vts[(16 * df + l15) * VLD + 8 * l4];
      acc[df] = __builtin_amdgcn_mfma_f32_16x16x32_bf16(pa, vb, acc[df], 0, 0, 0);
    }
  }
  // den: reduce across the 16 lanes of each row group
  #pragma unroll
  for (int ri = 0; ri < 4; ++ri) {
    den[ri] += __shfl_xor(den[ri], 1);
    den[ri] += __shfl_xor(den[ri], 2);
    den[ri] += __shfl_xor(den[ri], 4);
    den[ri] += __shfl_xor(den[ri], 8);
  }
  float* op = &out[((size_t)(b * SLEN + myrow)) * (NH * HD) + h * HD + l15];
  #pragma unroll
  for (int ri = 0; ri < 4; ++ri) {
    const float inv = 1.f / den[ri];
    #pragma unroll
    for (int df = 0; df < 16; ++df)
      op[(size_t)ri * (NH * HD) + 16 * df] = acc[df][ri] * inv;
  }
}

extern "C" void kernel_launch(void* const* d_in, const int* in_sizes, int n_in,
                              void* d_out, int out_size, void* d_ws, size_t ws_size,
                              hipStream_t stream) {
  const float* hs  = (const float*)d_in[0];
  const float* fc  = (const float*)d_in[1];
  const float* fs  = (const float*)d_in[2];
  // d_in[3] = mask: pure causal by construction, handled analytically.
  const float* WAq = (const float*)d_in[4];
  const float* WAk = (const float*)d_in[5];
  const float* WAv = (const float*)d_in[6];
  const float* WBq = (const float*)d_in[7];
  const float* WBk = (const float*)d_in[8];
  const float* WBv = (const float*)d_in[9];
  const float* Wo  = (const float*)d_in[10];
  float* out = (float*)d_out;

  // Workspace layout (floats). att aliases Bq+Bk (dead after qkv_rope). 142.6 MB peak.
  float* ws  = (float*)d_ws;
  float* Bq  = ws;                               // 4096*1536
  float* Bk  = Bq + (size_t)MTOT * 1536;         // 4096*512
  float* Bv  = Bk + (size_t)MTOT * 512;          // 4096*512
  float* qT  = Bv + (size_t)MTOT * 512;          // [2,8,2048,256]
  float* kT  = qT + (size_t)2 * NH * SLEN * HD;
  float* vT  = kT + (size_t)2 * NH * SLEN * HD;
  float* att = ws;                               // [4096,2048] over Bq+Bk

  gemm_mfma<<<dim3(1536 / 128, MTOT / 128), 256, 0, stream>>>(hs, WBq, Bq, 1536);
  gemm_mfma<<<dim3(512 / 128,  MTOT / 128), 256, 0, stream>>>(hs, WBk, Bk, 512);
  gemm_mfma<<<dim3(512 / 128,  MTOT / 128), 256, 0, stream>>>(hs, WBv, Bv, 512);
  qkv_rope<<<MTOT, 256, 0, stream>>>(hs, WAq, WAk, WAv, Bq, Bk, Bv, fc, fs, qT, kT, vT);
  attn_mfma<<<dim3(32 * 16), 256, 0, stream>>>(qT, kT, vT, att);
  gemm_mfma<<<dim3(HID / 128, MTOT / 128), 256, 0, stream>>>(att, Wo, out, HID);
}

// Round 11
// 762.226 us; speedup vs baseline: 3.7548x; 1.4156x over previous
//
#include <hip/hip_runtime.h>
#include <cstdint>

#define HID 2048
#define SLEN 2048
#define NH 8
#define HD 256
#define MTOT 4096

constexpr float SCALING = 0.0625f;   // 256^-0.5
constexpr float SOFTCAP = 50.0f;

typedef __attribute__((ext_vector_type(8))) short short8;
typedef __attribute__((ext_vector_type(4))) float f32x4;

__device__ __forceinline__ uint16_t bfhi(float x) {
  return (uint16_t)(__float_as_uint(x) >> 16);           // truncate
}
__device__ __forceinline__ float bf2f(uint16_t h) {
  return __uint_as_float((uint32_t)h << 16);
}
__device__ __forceinline__ void packsplit8(const float4 a, const float4 b,
                                           short8& hi, short8& lo) {
  const float x[8] = {a.x, a.y, a.z, a.w, b.x, b.y, b.z, b.w};
  #pragma unroll
  for (int i = 0; i < 8; ++i) {
    const uint32_t u = __float_as_uint(x[i]);
    const uint16_t h = (uint16_t)(u >> 16);
    const float r = x[i] - bf2f(h);
    hi[i] = (short)h;
    lo[i] = (short)(__float_as_uint(r) >> 16);
  }
}

// ---------------- split-bf16 MFMA GEMM: C[M,N] = A[M,2048] @ B[2048,N] ----------------
// (validated r9; unchanged)
__global__ __launch_bounds__(256) void gemm_mfma(
    const float* __restrict__ A, const float* __restrict__ B,
    float* __restrict__ C, int N) {
  __shared__ uint16_t Ah[8 * 520], Al[8 * 520], Bh[8 * 520], Bl[8 * 520];
  const int tid = threadIdx.x;
  const int row0 = blockIdx.y * 128;
  const int col0 = blockIdx.x * 128;
  const int lane = tid & 63;
  const int wv = tid >> 6;
  const int wr = wv >> 1, wc = wv & 1;

  f32x4 acc[4][4];
  #pragma unroll
  for (int m = 0; m < 4; ++m)
    #pragma unroll
    for (int n = 0; n < 4; ++n) acc[m][n] = (f32x4){0.f, 0.f, 0.f, 0.f};

  const int ar = tid >> 1;
  const int akb = (tid & 1) * 16;
  const int bkk = tid >> 3;
  const int bcg = tid & 7;

  for (int k0 = 0; k0 < 2048; k0 += 32) {
    float4 av[4], bv[4];
    #pragma unroll
    for (int c = 0; c < 4; ++c)
      av[c] = *(const float4*)&A[(size_t)(row0 + ar) * 2048 + k0 + akb + 4 * c];
    #pragma unroll
    for (int c = 0; c < 4; ++c)
      bv[c] = *(const float4*)&B[(size_t)(k0 + bkk) * N + col0 + bcg * 16 + 4 * c];
    __syncthreads();
    #pragma unroll
    for (int c = 0; c < 4; ++c) {
      const int kk = akb + 4 * c;
      const int idx = (ar >> 4) * 520 + (((ar & 15) | ((kk >> 3) << 4)) << 3) + (kk & 7);
      const float x0 = av[c].x, x1 = av[c].y, x2 = av[c].z, x3 = av[c].w;
      const uint16_t h0 = bfhi(x0), h1 = bfhi(x1), h2 = bfhi(x2), h3 = bfhi(x3);
      const uint16_t g0 = bfhi(x0 - bf2f(h0)), g1 = bfhi(x1 - bf2f(h1));
      const uint16_t g2 = bfhi(x2 - bf2f(h2)), g3 = bfhi(x3 - bf2f(h3));
      *(uint2*)&Ah[idx] = make_uint2((uint32_t)h0 | ((uint32_t)h1 << 16),
                                     (uint32_t)h2 | ((uint32_t)h3 << 16));
      *(uint2*)&Al[idx] = make_uint2((uint32_t)g0 | ((uint32_t)g1 << 16),
                                     (uint32_t)g2 | ((uint32_t)g3 << 16));
    }
    #pragma unroll
    for (int c = 0; c < 4; ++c) {
      const float xs4[4] = {bv[c].x, bv[c].y, bv[c].z, bv[c].w};
      #pragma unroll
      for (int i = 0; i < 4; ++i) {
        const int j = bcg * 16 + 4 * c + i;
        const uint16_t h = bfhi(xs4[i]);
        const uint16_t g = bfhi(xs4[i] - bf2f(h));
        const int idx = (j >> 4) * 520 + (((j & 15) | ((bkk >> 3) << 4)) << 3) + (bkk & 7);
        Bh[idx] = h;
        Bl[idx] = g;
      }
    }
    __syncthreads();
    short8 bhf[4], blf[4];
    #pragma unroll
    for (int nf = 0; nf < 4; ++nf) {
      bhf[nf] = *(const short8*)&Bh[(wc * 4 + nf) * 520 + lane * 8];
      blf[nf] = *(const short8*)&Bl[(wc * 4 + nf) * 520 + lane * 8];
    }
    #pragma unroll
    for (int m = 0; m < 4; ++m) {
      const short8 ahf = *(const short8*)&Ah[(wr * 4 + m) * 520 + lane * 8];
      const short8 alf = *(const short8*)&Al[(wr * 4 + m) * 520 + lane * 8];
      #pragma unroll
      for (int nf = 0; nf < 4; ++nf) {
        acc[m][nf] = __builtin_amdgcn_mfma_f32_16x16x32_bf16(ahf, bhf[nf], acc[m][nf], 0, 0, 0);
        acc[m][nf] = __builtin_amdgcn_mfma_f32_16x16x32_bf16(ahf, blf[nf], acc[m][nf], 0, 0, 0);
        acc[m][nf] = __builtin_amdgcn_mfma_f32_16x16x32_bf16(alf, bhf[nf], acc[m][nf], 0, 0, 0);
      }
    }
  }
  #pragma unroll
  for (int m = 0; m < 4; ++m)
    #pragma unroll
    for (int nf = 0; nf < 4; ++nf) {
      const int row = row0 + wr * 64 + m * 16 + ((lane >> 4) << 2);
      const int col = col0 + wc * 64 + nf * 16 + (lane & 15);
      #pragma unroll
      for (int ri = 0; ri < 4; ++ri)
        C[(size_t)(row + ri) * N + col] = acc[m][nf][ri];
    }
}

// --------- gemm_mfma_ext: B_q projection + fused A-projection tile -------------------
// Grid (13, 32). Tiles 0..11: C[:,0:1536] = hs @ WBq (as gemm_mfma). Tile 12 stages
// its B-tile from [WAq | WAk | WAv | 0] (16-col groups align with W boundaries) and
// writes cols<80 of the result to Aout[4096][80] = hs @ [W_A_q|W_A_k|W_A_v].
__global__ __launch_bounds__(256) void gemm_mfma_ext(
    const float* __restrict__ A, const float* __restrict__ B,
    const float* __restrict__ WAq, const float* __restrict__ WAk,
    const float* __restrict__ WAv,
    float* __restrict__ C, float* __restrict__ Aout, int N) {
  __shared__ uint16_t Ah[8 * 520], Al[8 * 520], Bh[8 * 520], Bl[8 * 520];
  const int tid = threadIdx.x;
  const int row0 = blockIdx.y * 128;
  const int col0 = blockIdx.x * 128;
  const bool special = (blockIdx.x == gridDim.x - 1);
  const int lane = tid & 63;
  const int wv = tid >> 6;
  const int wr = wv >> 1, wc = wv & 1;

  f32x4 acc[4][4];
  #pragma unroll
  for (int m = 0; m < 4; ++m)
    #pragma unroll
    for (int n = 0; n < 4; ++n) acc[m][n] = (f32x4){0.f, 0.f, 0.f, 0.f};

  const int ar = tid >> 1;
  const int akb = (tid & 1) * 16;
  const int bkk = tid >> 3;
  const int bcg = tid & 7;

  for (int k0 = 0; k0 < 2048; k0 += 32) {
    float4 av[4], bv[4];
    #pragma unroll
    for (int c = 0; c < 4; ++c)
      av[c] = *(const float4*)&A[(size_t)(row0 + ar) * 2048 + k0 + akb + 4 * c];
    if (!special) {
      #pragma unroll
      for (int c = 0; c < 4; ++c)
        bv[c] = *(const float4*)&B[(size_t)(k0 + bkk) * N + col0 + bcg * 16 + 4 * c];
    } else {
      #pragma unroll
      for (int c = 0; c < 4; ++c) {
        if (bcg < 3)
          bv[c] = *(const float4*)&WAq[(size_t)(k0 + bkk) * 48 + bcg * 16 + 4 * c];
        else if (bcg == 3)
          bv[c] = *(const float4*)&WAk[(size_t)(k0 + bkk) * 16 + 4 * c];
        else if (bcg == 4)
          bv[c] = *(const float4*)&WAv[(size_t)(k0 + bkk) * 16 + 4 * c];
        else
          bv[c] = make_float4(0.f, 0.f, 0.f, 0.f);
      }
    }
    __syncthreads();
    #pragma unroll
    for (int c = 0; c < 4; ++c) {
      const int kk = akb + 4 * c;
      const int idx = (ar >> 4) * 520 + (((ar & 15) | ((kk >> 3) << 4)) << 3) + (kk & 7);
      const float x0 = av[c].x, x1 = av[c].y, x2 = av[c].z, x3 = av[c].w;
      const uint16_t h0 = bfhi(x0), h1 = bfhi(x1), h2 = bfhi(x2), h3 = bfhi(x3);
      const uint16_t g0 = bfhi(x0 - bf2f(h0)), g1 = bfhi(x1 - bf2f(h1));
      const uint16_t g2 = bfhi(x2 - bf2f(h2)), g3 = bfhi(x3 - bf2f(h3));
      *(uint2*)&Ah[idx] = make_uint2((uint32_t)h0 | ((uint32_t)h1 << 16),
                                     (uint32_t)h2 | ((uint32_t)h3 << 16));
      *(uint2*)&Al[idx] = make_uint2((uint32_t)g0 | ((uint32_t)g1 << 16),
                                     (uint32_t)g2 | ((uint32_t)g3 << 16));
    }
    #pragma unroll
    for (int c = 0; c < 4; ++c) {
      const float xs4[4] = {bv[c].x, bv[c].y, bv[c].z, bv[c].w};
      #pragma unroll
      for (int i = 0; i < 4; ++i) {
        const int j = bcg * 16 + 4 * c + i;
        const uint16_t h = bfhi(xs4[i]);
        const uint16_t g = bfhi(xs4[i] - bf2f(h));
        const int idx = (j >> 4) * 520 + (((j & 15) | ((bkk >> 3) << 4)) << 3) + (bkk & 7);
        Bh[idx] = h;
        Bl[idx] = g;
      }
    }
    __syncthreads();
    short8 bhf[4], blf[4];
    #pragma unroll
    for (int nf = 0; nf < 4; ++nf) {
      bhf[nf] = *(const short8*)&Bh[(wc * 4 + nf) * 520 + lane * 8];
      blf[nf] = *(const short8*)&Bl[(wc * 4 + nf) * 520 + lane * 8];
    }
    #pragma unroll
    for (int m = 0; m < 4; ++m) {
      const short8 ahf = *(const short8*)&Ah[(wr * 4 + m) * 520 + lane * 8];
      const short8 alf = *(const short8*)&Al[(wr * 4 + m) * 520 + lane * 8];
      #pragma unroll
      for (int nf = 0; nf < 4; ++nf) {
        acc[m][nf] = __builtin_amdgcn_mfma_f32_16x16x32_bf16(ahf, bhf[nf], acc[m][nf], 0, 0, 0);
        acc[m][nf] = __builtin_amdgcn_mfma_f32_16x16x32_bf16(ahf, blf[nf], acc[m][nf], 0, 0, 0);
        acc[m][nf] = __builtin_amdgcn_mfma_f32_16x16x32_bf16(alf, bhf[nf], acc[m][nf], 0, 0, 0);
      }
    }
  }
  #pragma unroll
  for (int m = 0; m < 4; ++m)
    #pragma unroll
    for (int nf = 0; nf < 4; ++nf) {
      const int row = row0 + wr * 64 + m * 16 + ((lane >> 4) << 2);
      const int col = wc * 64 + nf * 16 + (lane & 15);
      if (!special) {
        #pragma unroll
        for (int ri = 0; ri < 4; ++ri)
          C[(size_t)(row + ri) * N + col0 + col] = acc[m][nf][ri];
      } else if (col < 80) {
        #pragma unroll
        for (int ri = 0; ri < 4; ++ri)
          Aout[(size_t)(row + ri) * 80 + col] = acc[m][nf][ri];
      }
    }
}

// ------------- RoPE + rank contraction v2: pure streaming (A-proj precomputed) --------
__global__ __launch_bounds__(256) void qkv_rope(
    const float* __restrict__ Aall,
    const float* __restrict__ Bq, const float* __restrict__ Bk,
    const float* __restrict__ Bv,
    const float* __restrict__ fc, const float* __restrict__ fs,
    float* __restrict__ q, float* __restrict__ k, float* __restrict__ v) {
  const int m = blockIdx.x;        // 0..4095  (b*SLEN + s)
  const int s = m & (SLEN - 1);
  const int b = m >> 11;
  const int tid = threadIdx.x;
  __shared__ float Al[80];         // A_q[48] | A_k[16] | A_v[16]

  if (tid < 20) *(float4*)&Al[tid * 4] = *(const float4*)&Aall[(size_t)m * 80 + tid * 4];
  __syncthreads();

  const size_t tbase = (size_t)b * NH * SLEN * HD + (size_t)s * HD;
  if (tid < 128) {
    const int j = tid;
    const float cz = fc[s * 128 + j], sz = fs[s * 128 + j];
    float qe[8], qo[8];
    #pragma unroll
    for (int hh = 0; hh < 8; ++hh) { qe[hh] = 0.f; qo[hh] = 0.f; }
    #pragma unroll
    for (int r = 0; r < 6; ++r) {
      const float2 x = *(const float2*)&Bq[(size_t)m * 1536 + r * 256 + 2 * j];
      const float re = x.x * cz - x.y * sz;
      const float ro = x.x * sz + x.y * cz;
      #pragma unroll
      for (int hh = 0; hh < 8; ++hh) {
        const float a = Al[hh * 6 + r];
        qe[hh] = fmaf(a, re, qe[hh]);
        qo[hh] = fmaf(a, ro, qo[hh]);
      }
    }
    const float qs = SCALING / 6.f;
    #pragma unroll
    for (int hh = 0; hh < 8; ++hh) {
      float2 o; o.x = qe[hh] * qs; o.y = qo[hh] * qs;
      *(float2*)&q[tbase + (size_t)hh * SLEN * HD + 2 * j] = o;
    }
  } else {
    const int j = tid - 128;
    const float cz = fc[s * 128 + j], sz = fs[s * 128 + j];
    float ke_[8], ko_[8], ve_[8], vo_[8];
    #pragma unroll
    for (int hh = 0; hh < 8; ++hh) { ke_[hh]=0.f; ko_[hh]=0.f; ve_[hh]=0.f; vo_[hh]=0.f; }
    #pragma unroll
    for (int r = 0; r < 2; ++r) {
      const float2 xk = *(const float2*)&Bk[(size_t)m * 512 + r * 256 + 2 * j];
      const float2 xv = *(const float2*)&Bv[(size_t)m * 512 + r * 256 + 2 * j];
      const float re = xk.x * cz - xk.y * sz;
      const float ro = xk.x * sz + xk.y * cz;
      #pragma unroll
      for (int hh = 0; hh < 8; ++hh) {
        const float ak = Al[48 + hh * 2 + r];
        const float av = Al[64 + hh * 2 + r];
        ke_[hh] = fmaf(ak, re, ke_[hh]);
        ko_[hh] = fmaf(ak, ro, ko_[hh]);
        ve_[hh] = fmaf(av, xv.x, ve_[hh]);
        vo_[hh] = fmaf(av, xv.y, vo_[hh]);
      }
    }
    #pragma unroll
    for (int hh = 0; hh < 8; ++hh) {
      float2 ok; ok.x = ke_[hh] * 0.5f; ok.y = ko_[hh] * 0.5f;
      *(float2*)&k[tbase + (size_t)hh * SLEN * HD + 2 * j] = ok;
      float2 ov; ov.x = ve_[hh] * 0.5f; ov.y = vo_[hh] * 0.5f;
      *(float2*)&v[tbase + (size_t)hh * SLEN * HD + 2 * j] = ov;
    }
  }
}

// ------------- causal softcapped attention v4: MFMA (unchanged from r10) --------------
#define KLD 264
#define VLD 34
#define PLD 36
__global__ __launch_bounds__(256, 2) void attn_mfma(
    const float* __restrict__ q, const float* __restrict__ k,
    const float* __restrict__ v, float* __restrict__ out) {
  __shared__ uint16_t Khs[32 * KLD];
  __shared__ uint16_t Kls[32 * KLD];
  __shared__ uint16_t Vts[256 * VLD];
  __shared__ uint16_t Ps[4 * 16 * PLD];
  const int tid = threadIdx.x;
  const int lane = tid & 63;
  const int w = tid >> 6;
  const int l15 = lane & 15;
  const int l4 = lane >> 4;
  const int bid = blockIdx.x;
  const int qt = 31 - (bid >> 4);
  const int bh = bid & 15;
  const int b = bh >> 3, h = bh & 7;
  const int q0 = qt * 64;
  const size_t base = (size_t)bh * SLEN * HD;

  short8 qh[8], ql[8];
  {
    const float* qp = &q[base + (size_t)(q0 + w * 16 + l15) * HD + 8 * l4];
    #pragma unroll
    for (int f = 0; f < 8; ++f) {
      const float4 a = *(const float4*)&qp[32 * f];
      const float4 bb = *(const float4*)&qp[32 * f + 4];
      packsplit8(a, bb, qh[f], ql[f]);
    }
  }
  f32x4 acc[16];
  #pragma unroll
  for (int df = 0; df < 16; ++df) acc[df] = (f32x4){0.f, 0.f, 0.f, 0.f};
  float den[4] = {0.f, 0.f, 0.f, 0.f};

  const int myrow = q0 + w * 16 + l4 * 4;
  const int rowmax = q0 + w * 16 + 15;
  const int nkt = 2 * qt + 2;
  const int sr = tid & 31;
  const int sc = (tid >> 5) * 32;

  for (int kt = 0; kt < nkt; ++kt) {
    const int k0 = kt * 32;
    __syncthreads();
    {
      const float* kp = &k[base + (size_t)(k0 + sr) * HD + sc];
      #pragma unroll
      for (int j = 0; j < 4; ++j) {
        const float4 a = *(const float4*)&kp[8 * j];
        const float4 bb = *(const float4*)&kp[8 * j + 4];
        short8 hi, lo;
        packsplit8(a, bb, hi, lo);
        *(short8*)&Khs[sr * KLD + sc + 8 * j] = hi;
        *(short8*)&Kls[sr * KLD + sc + 8 * j] = lo;
      }
      const float* vp = &v[base + (size_t)(k0 + sr) * HD + sc];
      #pragma unroll
      for (int j = 0; j < 8; ++j) {
        const float4 a = *(const float4*)&vp[4 * j];
        Vts[(sc + 4 * j + 0) * VLD + sr] = bfhi(a.x);
        Vts[(sc + 4 * j + 1) * VLD + sr] = bfhi(a.y);
        Vts[(sc + 4 * j + 2) * VLD + sr] = bfhi(a.z);
        Vts[(sc + 4 * j + 3) * VLD + sr] = bfhi(a.w);
      }
    }
    __syncthreads();
    if (k0 > rowmax) continue;

    f32x4 sfr[2];
    #pragma unroll
    for (int kf = 0; kf < 2; ++kf) {
      f32x4 c = (f32x4){0.f, 0.f, 0.f, 0.f};
      #pragma unroll
      for (int dc = 0; dc < 8; ++dc) {
        const int off = (16 * kf + l15) * KLD + 32 * dc + 8 * l4;
        const short8 kh = *(const short8*)&Khs[off];
        const short8 kl = *(const short8*)&Kls[off];
        c = __builtin_amdgcn_mfma_f32_16x16x32_bf16(qh[dc], kh, c, 0, 0, 0);
        c = __builtin_amdgcn_mfma_f32_16x16x32_bf16(qh[dc], kl, c, 0, 0, 0);
        c = __builtin_amdgcn_mfma_f32_16x16x32_bf16(ql[dc], kh, c, 0, 0, 0);
      }
      sfr[kf] = c;
    }
    uint16_t* pw = &Ps[w * 16 * PLD];
    #pragma unroll
    for (int kf = 0; kf < 2; ++kf) {
      #pragma unroll
      for (int ri = 0; ri < 4; ++ri) {
        const float pd = sfr[kf][ri];
        const float t1 = exp2f(pd * 0.0577078016f);
        float e = exp2f(-144.26950409f * __builtin_amdgcn_rcpf(t1 + 1.f));
        if (k0 + 16 * kf + l15 > myrow + ri) e = 0.f;
        den[ri] += e;
        pw[(l4 * 4 + ri) * PLD + 16 * kf + l15] = bfhi(e);
      }
    }
    const short8 pa = *(const short8*)&pw[l15 * PLD + 8 * l4];
    #pragma unroll
    for (int df = 0; df < 16; ++df) {
      const short8 vb = *(const short8*)&Vts[(16 * df + l15) * VLD + 8 * l4];
      acc[df] = __builtin_amdgcn_mfma_f32_16x16x32_bf16(pa, vb, acc[df], 0, 0, 0);
    }
  }
  #pragma unroll
  for (int ri = 0; ri < 4; ++ri) {
    den[ri] += __shfl_xor(den[ri], 1);
    den[ri] += __shfl_xor(den[ri], 2);
    den[ri] += __shfl_xor(den[ri], 4);
    den[ri] += __shfl_xor(den[ri], 8);
  }
  float* op = &out[((size_t)(b * SLEN + myrow)) * (NH * HD) + h * HD + l15];
  #pragma unroll
  for (int ri = 0; ri < 4; ++ri) {
    const float inv = 1.f / den[ri];
    #pragma unroll
    for (int df = 0; df < 16; ++df)
      op[(size_t)ri * (NH * HD) + 16 * df] = acc[df][ri] * inv;
  }
}

extern "C" void kernel_launch(void* const* d_in, const int* in_sizes, int n_in,
                              void* d_out, int out_size, void* d_ws, size_t ws_size,
                              hipStream_t stream) {
  const float* hs  = (const float*)d_in[0];
  const float* fc  = (const float*)d_in[1];
  const float* fs  = (const float*)d_in[2];
  // d_in[3] = mask: pure causal, handled analytically.
  const float* WAq = (const float*)d_in[4];
  const float* WAk = (const float*)d_in[5];
  const float* WAv = (const float*)d_in[6];
  const float* WBq = (const float*)d_in[7];
  const float* WBk = (const float*)d_in[8];
  const float* WBv = (const float*)d_in[9];
  const float* Wo  = (const float*)d_in[10];
  float* out = (float*)d_out;

  // Workspace layout (floats). att aliases Bq+Bk (dead after qkv_rope). ~144 MB peak.
  float* ws   = (float*)d_ws;
  float* Bq   = ws;                               // 4096*1536
  float* Bk   = Bq + (size_t)MTOT * 1536;         // 4096*512
  float* Bv   = Bk + (size_t)MTOT * 512;          // 4096*512
  float* qT   = Bv + (size_t)MTOT * 512;          // [2,8,2048,256]
  float* kT   = qT + (size_t)2 * NH * SLEN * HD;
  float* vT   = kT + (size_t)2 * NH * SLEN * HD;
  float* Aall = vT + (size_t)2 * NH * SLEN * HD;  // [4096, 80]
  float* att  = ws;                               // [4096,2048] over Bq+Bk

  gemm_mfma_ext<<<dim3(13, MTOT / 128), 256, 0, stream>>>(hs, WBq, WAq, WAk, WAv,
                                                          Bq, Aall, 1536);
  gemm_mfma<<<dim3(512 / 128, MTOT / 128), 256, 0, stream>>>(hs, WBk, Bk, 512);
  gemm_mfma<<<dim3(512 / 128, MTOT / 128), 256, 0, stream>>>(hs, WBv, Bv, 512);
  qkv_rope<<<MTOT, 256, 0, stream>>>(Aall, Bq, Bk, Bv, fc, fs, qT, kT, vT);
  attn_mfma<<<dim3(32 * 16), 256, 0, stream>>>(qT, kT, vT, att);
  gemm_mfma<<<dim3(HID / 128, MTOT / 128), 256, 0, stream>>>(att, Wo, out, HID);
}

// Round 12
// 748.160 us; speedup vs baseline: 3.8254x; 1.0188x over previous
//
#include <hip/hip_runtime.h>
#include <cstdint>

#define HID 2048
#define SLEN 2048
#define NH 8
#define HD 256
#define MTOT 4096

constexpr float SCALING = 0.0625f;   // 256^-0.5
constexpr float SOFTCAP = 50.0f;

typedef __attribute__((ext_vector_type(8))) short short8;
typedef __attribute__((ext_vector_type(4))) float f32x4;

__device__ __forceinline__ uint16_t bfhi(float x) {
  return (uint16_t)(__float_as_uint(x) >> 16);           // truncate
}
__device__ __forceinline__ float bf2f(uint16_t h) {
  return __uint_as_float((uint32_t)h << 16);
}
__device__ __forceinline__ void packsplit8(const float4 a, const float4 b,
                                           short8& hi, short8& lo) {
  const float x[8] = {a.x, a.y, a.z, a.w, b.x, b.y, b.z, b.w};
  #pragma unroll
  for (int i = 0; i < 8; ++i) {
    const uint32_t u = __float_as_uint(x[i]);
    const uint16_t h = (uint16_t)(u >> 16);
    const float r = x[i] - bf2f(h);
    hi[i] = (short)h;
    lo[i] = (short)(__float_as_uint(r) >> 16);
  }
}

// ---------------- split-bf16 MFMA GEMM: C[M,N] = A[M,2048] @ B[2048,N] ----------------
// (validated r9; unchanged)
__global__ __launch_bounds__(256) void gemm_mfma(
    const float* __restrict__ A, const float* __restrict__ B,
    float* __restrict__ C, int N) {
  __shared__ uint16_t Ah[8 * 520], Al[8 * 520], Bh[8 * 520], Bl[8 * 520];
  const int tid = threadIdx.x;
  const int row0 = blockIdx.y * 128;
  const int col0 = blockIdx.x * 128;
  const int lane = tid & 63;
  const int wv = tid >> 6;
  const int wr = wv >> 1, wc = wv & 1;

  f32x4 acc[4][4];
  #pragma unroll
  for (int m = 0; m < 4; ++m)
    #pragma unroll
    for (int n = 0; n < 4; ++n) acc[m][n] = (f32x4){0.f, 0.f, 0.f, 0.f};

  const int ar = tid >> 1;
  const int akb = (tid & 1) * 16;
  const int bkk = tid >> 3;
  const int bcg = tid & 7;

  for (int k0 = 0; k0 < 2048; k0 += 32) {
    float4 av[4], bv[4];
    #pragma unroll
    for (int c = 0; c < 4; ++c)
      av[c] = *(const float4*)&A[(size_t)(row0 + ar) * 2048 + k0 + akb + 4 * c];
    #pragma unroll
    for (int c = 0; c < 4; ++c)
      bv[c] = *(const float4*)&B[(size_t)(k0 + bkk) * N + col0 + bcg * 16 + 4 * c];
    __syncthreads();
    #pragma unroll
    for (int c = 0; c < 4; ++c) {
      const int kk = akb + 4 * c;
      const int idx = (ar >> 4) * 520 + (((ar & 15) | ((kk >> 3) << 4)) << 3) + (kk & 7);
      const float x0 = av[c].x, x1 = av[c].y, x2 = av[c].z, x3 = av[c].w;
      const uint16_t h0 = bfhi(x0), h1 = bfhi(x1), h2 = bfhi(x2), h3 = bfhi(x3);
      const uint16_t g0 = bfhi(x0 - bf2f(h0)), g1 = bfhi(x1 - bf2f(h1));
      const uint16_t g2 = bfhi(x2 - bf2f(h2)), g3 = bfhi(x3 - bf2f(h3));
      *(uint2*)&Ah[idx] = make_uint2((uint32_t)h0 | ((uint32_t)h1 << 16),
                                     (uint32_t)h2 | ((uint32_t)h3 << 16));
      *(uint2*)&Al[idx] = make_uint2((uint32_t)g0 | ((uint32_t)g1 << 16),
                                     (uint32_t)g2 | ((uint32_t)g3 << 16));
    }
    #pragma unroll
    for (int c = 0; c < 4; ++c) {
      const float xs4[4] = {bv[c].x, bv[c].y, bv[c].z, bv[c].w};
      #pragma unroll
      for (int i = 0; i < 4; ++i) {
        const int j = bcg * 16 + 4 * c + i;
        const uint16_t h = bfhi(xs4[i]);
        const uint16_t g = bfhi(xs4[i] - bf2f(h));
        const int idx = (j >> 4) * 520 + (((j & 15) | ((bkk >> 3) << 4)) << 3) + (bkk & 7);
        Bh[idx] = h;
        Bl[idx] = g;
      }
    }
    __syncthreads();
    short8 bhf[4], blf[4];
    #pragma unroll
    for (int nf = 0; nf < 4; ++nf) {
      bhf[nf] = *(const short8*)&Bh[(wc * 4 + nf) * 520 + lane * 8];
      blf[nf] = *(const short8*)&Bl[(wc * 4 + nf) * 520 + lane * 8];
    }
    #pragma unroll
    for (int m = 0; m < 4; ++m) {
      const short8 ahf = *(const short8*)&Ah[(wr * 4 + m) * 520 + lane * 8];
      const short8 alf = *(const short8*)&Al[(wr * 4 + m) * 520 + lane * 8];
      #pragma unroll
      for (int nf = 0; nf < 4; ++nf) {
        acc[m][nf] = __builtin_amdgcn_mfma_f32_16x16x32_bf16(ahf, bhf[nf], acc[m][nf], 0, 0, 0);
        acc[m][nf] = __builtin_amdgcn_mfma_f32_16x16x32_bf16(ahf, blf[nf], acc[m][nf], 0, 0, 0);
        acc[m][nf] = __builtin_amdgcn_mfma_f32_16x16x32_bf16(alf, bhf[nf], acc[m][nf], 0, 0, 0);
      }
    }
  }
  #pragma unroll
  for (int m = 0; m < 4; ++m)
    #pragma unroll
    for (int nf = 0; nf < 4; ++nf) {
      const int row = row0 + wr * 64 + m * 16 + ((lane >> 4) << 2);
      const int col = col0 + wc * 64 + nf * 16 + (lane & 15);
      #pragma unroll
      for (int ri = 0; ri < 4; ++ri)
        C[(size_t)(row + ri) * N + col] = acc[m][nf][ri];
    }
}

// --------- gemm_mfma_ext: B_q projection + fused A-projection tile (validated r11) ----
__global__ __launch_bounds__(256) void gemm_mfma_ext(
    const float* __restrict__ A, const float* __restrict__ B,
    const float* __restrict__ WAq, const float* __restrict__ WAk,
    const float* __restrict__ WAv,
    float* __restrict__ C, float* __restrict__ Aout, int N) {
  __shared__ uint16_t Ah[8 * 520], Al[8 * 520], Bh[8 * 520], Bl[8 * 520];
  const int tid = threadIdx.x;
  const int row0 = blockIdx.y * 128;
  const int col0 = blockIdx.x * 128;
  const bool special = (blockIdx.x == gridDim.x - 1);
  const int lane = tid & 63;
  const int wv = tid >> 6;
  const int wr = wv >> 1, wc = wv & 1;

  f32x4 acc[4][4];
  #pragma unroll
  for (int m = 0; m < 4; ++m)
    #pragma unroll
    for (int n = 0; n < 4; ++n) acc[m][n] = (f32x4){0.f, 0.f, 0.f, 0.f};

  const int ar = tid >> 1;
  const int akb = (tid & 1) * 16;
  const int bkk = tid >> 3;
  const int bcg = tid & 7;

  for (int k0 = 0; k0 < 2048; k0 += 32) {
    float4 av[4], bv[4];
    #pragma unroll
    for (int c = 0; c < 4; ++c)
      av[c] = *(const float4*)&A[(size_t)(row0 + ar) * 2048 + k0 + akb + 4 * c];
    if (!special) {
      #pragma unroll
      for (int c = 0; c < 4; ++c)
        bv[c] = *(const float4*)&B[(size_t)(k0 + bkk) * N + col0 + bcg * 16 + 4 * c];
    } else {
      #pragma unroll
      for (int c = 0; c < 4; ++c) {
        if (bcg < 3)
          bv[c] = *(const float4*)&WAq[(size_t)(k0 + bkk) * 48 + bcg * 16 + 4 * c];
        else if (bcg == 3)
          bv[c] = *(const float4*)&WAk[(size_t)(k0 + bkk) * 16 + 4 * c];
        else if (bcg == 4)
          bv[c] = *(const float4*)&WAv[(size_t)(k0 + bkk) * 16 + 4 * c];
        else
          bv[c] = make_float4(0.f, 0.f, 0.f, 0.f);
      }
    }
    __syncthreads();
    #pragma unroll
    for (int c = 0; c < 4; ++c) {
      const int kk = akb + 4 * c;
      const int idx = (ar >> 4) * 520 + (((ar & 15) | ((kk >> 3) << 4)) << 3) + (kk & 7);
      const float x0 = av[c].x, x1 = av[c].y, x2 = av[c].z, x3 = av[c].w;
      const uint16_t h0 = bfhi(x0), h1 = bfhi(x1), h2 = bfhi(x2), h3 = bfhi(x3);
      const uint16_t g0 = bfhi(x0 - bf2f(h0)), g1 = bfhi(x1 - bf2f(h1));
      const uint16_t g2 = bfhi(x2 - bf2f(h2)), g3 = bfhi(x3 - bf2f(h3));
      *(uint2*)&Ah[idx] = make_uint2((uint32_t)h0 | ((uint32_t)h1 << 16),
                                     (uint32_t)h2 | ((uint32_t)h3 << 16));
      *(uint2*)&Al[idx] = make_uint2((uint32_t)g0 | ((uint32_t)g1 << 16),
                                     (uint32_t)g2 | ((uint32_t)g3 << 16));
    }
    #pragma unroll
    for (int c = 0; c < 4; ++c) {
      const float xs4[4] = {bv[c].x, bv[c].y, bv[c].z, bv[c].w};
      #pragma unroll
      for (int i = 0; i < 4; ++i) {
        const int j = bcg * 16 + 4 * c + i;
        const uint16_t h = bfhi(xs4[i]);
        const uint16_t g = bfhi(xs4[i] - bf2f(h));
        const int idx = (j >> 4) * 520 + (((j & 15) | ((bkk >> 3) << 4)) << 3) + (bkk & 7);
        Bh[idx] = h;
        Bl[idx] = g;
      }
    }
    __syncthreads();
    short8 bhf[4], blf[4];
    #pragma unroll
    for (int nf = 0; nf < 4; ++nf) {
      bhf[nf] = *(const short8*)&Bh[(wc * 4 + nf) * 520 + lane * 8];
      blf[nf] = *(const short8*)&Bl[(wc * 4 + nf) * 520 + lane * 8];
    }
    #pragma unroll
    for (int m = 0; m < 4; ++m) {
      const short8 ahf = *(const short8*)&Ah[(wr * 4 + m) * 520 + lane * 8];
      const short8 alf = *(const short8*)&Al[(wr * 4 + m) * 520 + lane * 8];
      #pragma unroll
      for (int nf = 0; nf < 4; ++nf) {
        acc[m][nf] = __builtin_amdgcn_mfma_f32_16x16x32_bf16(ahf, bhf[nf], acc[m][nf], 0, 0, 0);
        acc[m][nf] = __builtin_amdgcn_mfma_f32_16x16x32_bf16(ahf, blf[nf], acc[m][nf], 0, 0, 0);
        acc[m][nf] = __builtin_amdgcn_mfma_f32_16x16x32_bf16(alf, bhf[nf], acc[m][nf], 0, 0, 0);
      }
    }
  }
  #pragma unroll
  for (int m = 0; m < 4; ++m)
    #pragma unroll
    for (int nf = 0; nf < 4; ++nf) {
      const int row = row0 + wr * 64 + m * 16 + ((lane >> 4) << 2);
      const int col = wc * 64 + nf * 16 + (lane & 15);
      if (!special) {
        #pragma unroll
        for (int ri = 0; ri < 4; ++ri)
          C[(size_t)(row + ri) * N + col0 + col] = acc[m][nf][ri];
      } else if (col < 80) {
        #pragma unroll
        for (int ri = 0; ri < 4; ++ri)
          Aout[(size_t)(row + ri) * 80 + col] = acc[m][nf][ri];
      }
    }
}

// ------------- RoPE + rank contraction v2 (validated r11, unchanged) ------------------
__global__ __launch_bounds__(256) void qkv_rope(
    const float* __restrict__ Aall,
    const float* __restrict__ Bq, const float* __restrict__ Bk,
    const float* __restrict__ Bv,
    const float* __restrict__ fc, const float* __restrict__ fs,
    float* __restrict__ q, float* __restrict__ k, float* __restrict__ v) {
  const int m = blockIdx.x;        // 0..4095  (b*SLEN + s)
  const int s = m & (SLEN - 1);
  const int b = m >> 11;
  const int tid = threadIdx.x;
  __shared__ float Al[80];         // A_q[48] | A_k[16] | A_v[16]

  if (tid < 20) *(float4*)&Al[tid * 4] = *(const float4*)&Aall[(size_t)m * 80 + tid * 4];
  __syncthreads();

  const size_t tbase = (size_t)b * NH * SLEN * HD + (size_t)s * HD;
  if (tid < 128) {
    const int j = tid;
    const float cz = fc[s * 128 + j], sz = fs[s * 128 + j];
    float qe[8], qo[8];
    #pragma unroll
    for (int hh = 0; hh < 8; ++hh) { qe[hh] = 0.f; qo[hh] = 0.f; }
    #pragma unroll
    for (int r = 0; r < 6; ++r) {
      const float2 x = *(const float2*)&Bq[(size_t)m * 1536 + r * 256 + 2 * j];
      const float re = x.x * cz - x.y * sz;
      const float ro = x.x * sz + x.y * cz;
      #pragma unroll
      for (int hh = 0; hh < 8; ++hh) {
        const float a = Al[hh * 6 + r];
        qe[hh] = fmaf(a, re, qe[hh]);
        qo[hh] = fmaf(a, ro, qo[hh]);
      }
    }
    const float qs = SCALING / 6.f;
    #pragma unroll
    for (int hh = 0; hh < 8; ++hh) {
      float2 o; o.x = qe[hh] * qs; o.y = qo[hh] * qs;
      *(float2*)&q[tbase + (size_t)hh * SLEN * HD + 2 * j] = o;
    }
  } else {
    const int j = tid - 128;
    const float cz = fc[s * 128 + j], sz = fs[s * 128 + j];
    float ke_[8], ko_[8], ve_[8], vo_[8];
    #pragma unroll
    for (int hh = 0; hh < 8; ++hh) { ke_[hh]=0.f; ko_[hh]=0.f; ve_[hh]=0.f; vo_[hh]=0.f; }
    #pragma unroll
    for (int r = 0; r < 2; ++r) {
      const float2 xk = *(const float2*)&Bk[(size_t)m * 512 + r * 256 + 2 * j];
      const float2 xv = *(const float2*)&Bv[(size_t)m * 512 + r * 256 + 2 * j];
      const float re = xk.x * cz - xk.y * sz;
      const float ro = xk.x * sz + xk.y * cz;
      #pragma unroll
      for (int hh = 0; hh < 8; ++hh) {
        const float ak = Al[48 + hh * 2 + r];
        const float av = Al[64 + hh * 2 + r];
        ke_[hh] = fmaf(ak, re, ke_[hh]);
        ko_[hh] = fmaf(ak, ro, ko_[hh]);
        ve_[hh] = fmaf(av, xv.x, ve_[hh]);
        vo_[hh] = fmaf(av, xv.y, vo_[hh]);
      }
    }
    #pragma unroll
    for (int hh = 0; hh < 8; ++hh) {
      float2 ok; ok.x = ke_[hh] * 0.5f; ok.y = ko_[hh] * 0.5f;
      *(float2*)&k[tbase + (size_t)hh * SLEN * HD + 2 * j] = ok;
      float2 ov; ov.x = ve_[hh] * 0.5f; ov.y = vo_[hh] * 0.5f;
      *(float2*)&v[tbase + (size_t)hh * SLEN * HD + 2 * j] = ov;
    }
  }
}

// ------------- causal softcapped attention v5: MFMA + aligned LDS + T14 pipeline ------
// Changes vs v4: (1) VLD/PLD 34/36 -> 40: all b128 LDS reads 16B-aligned and
// bank-conflict-free (group stride 5 coprime 32; KLD=264 was already clean).
// (2) Software pipeline (T14): next k-tile's K/V loaded into REGISTERS before the
// MFMA phase; loads stay in flight across the barrier (reg-destined, not LDS);
// the vmcnt wait lands at next iteration's convert. Costs ~64 VGPR; occupancy is
// LDS-bound at 2 blocks/CU either way.
#define KLD 264
#define VLD 40
#define PLD 40
__global__ __launch_bounds__(256, 2) void attn_mfma(
    const float* __restrict__ q, const float* __restrict__ k,
    const float* __restrict__ v, float* __restrict__ out) {
  __shared__ uint16_t Khs[32 * KLD];   // 16896 B
  __shared__ uint16_t Kls[32 * KLD];   // 16896 B
  __shared__ uint16_t Vts[256 * VLD];  // 20480 B
  __shared__ uint16_t Ps[4 * 16 * PLD];//  5120 B  (total 59392 B -> 2 blocks/CU)
  const int tid = threadIdx.x;
  const int lane = tid & 63;
  const int w = tid >> 6;
  const int l15 = lane & 15;
  const int l4 = lane >> 4;
  const int bid = blockIdx.x;
  const int qt = 31 - (bid >> 4);      // heavy q-tiles first (LPT)
  const int bh = bid & 15;
  const int b = bh >> 3, h = bh & 7;
  const int q0 = qt * 64;
  const size_t base = (size_t)bh * SLEN * HD;

  // Q fragments in registers: rows q0+16w+l15, d = 32f + 8*l4 + e
  short8 qh[8], ql[8];
  {
    const float* qp = &q[base + (size_t)(q0 + w * 16 + l15) * HD + 8 * l4];
    #pragma unroll
    for (int f = 0; f < 8; ++f) {
      const float4 a = *(const float4*)&qp[32 * f];
      const float4 bb = *(const float4*)&qp[32 * f + 4];
      packsplit8(a, bb, qh[f], ql[f]);
    }
  }
  f32x4 acc[16];
  #pragma unroll
  for (int df = 0; df < 16; ++df) acc[df] = (f32x4){0.f, 0.f, 0.f, 0.f};
  float den[4] = {0.f, 0.f, 0.f, 0.f};

  const int myrow = q0 + w * 16 + l4 * 4;
  const int rowmax = q0 + w * 16 + 15;
  const int nkt = 2 * qt + 2;
  const int sr = tid & 31;             // staging row
  const int sc = (tid >> 5) * 32;      // staging col chunk (32 floats)
  const float* kb_ = &k[base];
  const float* vb_ = &v[base];

  // T14 prologue: tile 0 -> registers
  float4 kreg[8], vreg[8];
  {
    const float* kp = &kb_[(size_t)sr * HD + sc];
    const float* vp = &vb_[(size_t)sr * HD + sc];
    #pragma unroll
    for (int j = 0; j < 8; ++j) kreg[j] = *(const float4*)&kp[4 * j];
    #pragma unroll
    for (int j = 0; j < 8; ++j) vreg[j] = *(const float4*)&vp[4 * j];
  }

  for (int kt = 0; kt < nkt; ++kt) {
    const int k0 = kt * 32;
    __syncthreads();   // all waves done reading previous tile's LDS
    // convert current tile regs -> LDS
    #pragma unroll
    for (int j = 0; j < 4; ++j) {
      short8 hi, lo;
      packsplit8(kreg[2 * j], kreg[2 * j + 1], hi, lo);
      *(short8*)&Khs[sr * KLD + sc + 8 * j] = hi;
      *(short8*)&Kls[sr * KLD + sc + 8 * j] = lo;
    }
    #pragma unroll
    for (int j = 0; j < 8; ++j) {
      Vts[(sc + 4 * j + 0) * VLD + sr] = bfhi(vreg[j].x);
      Vts[(sc + 4 * j + 1) * VLD + sr] = bfhi(vreg[j].y);
      Vts[(sc + 4 * j + 2) * VLD + sr] = bfhi(vreg[j].z);
      Vts[(sc + 4 * j + 3) * VLD + sr] = bfhi(vreg[j].w);
    }
    // issue NEXT tile's loads; they fly across the barrier under the MFMA phase
    if (kt + 1 < nkt) {
      const float* kp = &kb_[(size_t)(k0 + 32 + sr) * HD + sc];
      const float* vp = &vb_[(size_t)(k0 + 32 + sr) * HD + sc];
      #pragma unroll
      for (int j = 0; j < 8; ++j) kreg[j] = *(const float4*)&kp[4 * j];
      #pragma unroll
      for (int j = 0; j < 8; ++j) vreg[j] = *(const float4*)&vp[4 * j];
    }
    __syncthreads();   // LDS tile ready
    if (k0 <= rowmax) {
      // QK^T: 2 k-frags x 8 d-chunks x 3 split terms
      f32x4 sfr[2];
      #pragma unroll
      for (int kf = 0; kf < 2; ++kf) {
        f32x4 c = (f32x4){0.f, 0.f, 0.f, 0.f};
        #pragma unroll
        for (int dc = 0; dc < 8; ++dc) {
          const int off = (16 * kf + l15) * KLD + 32 * dc + 8 * l4;
          const short8 kh = *(const short8*)&Khs[off];
          const short8 kl = *(const short8*)&Kls[off];
          c = __builtin_amdgcn_mfma_f32_16x16x32_bf16(qh[dc], kh, c, 0, 0, 0);
          c = __builtin_amdgcn_mfma_f32_16x16x32_bf16(qh[dc], kl, c, 0, 0, 0);
          c = __builtin_amdgcn_mfma_f32_16x16x32_bf16(ql[dc], kh, c, 0, 0, 0);
        }
        sfr[kf] = c;
      }
      // softcap + exp (fixed-max) + causal mask; P -> wave-private LDS (bf16)
      uint16_t* pw = &Ps[w * 16 * PLD];
      #pragma unroll
      for (int kf = 0; kf < 2; ++kf) {
        #pragma unroll
        for (int ri = 0; ri < 4; ++ri) {
          const float pd = sfr[kf][ri];
          const float t1 = exp2f(pd * 0.0577078016f);
          float e = exp2f(-144.26950409f * __builtin_amdgcn_rcpf(t1 + 1.f));
          if (k0 + 16 * kf + l15 > myrow + ri) e = 0.f;
          den[ri] += e;
          pw[(l4 * 4 + ri) * PLD + 16 * kf + l15] = bfhi(e);
        }
      }
      // PV: A = P[16q][32j], B = Vt frags [32j][16d], 16 d-frags
      const short8 pa = *(const short8*)&pw[l15 * PLD + 8 * l4];
      #pragma unroll
      for (int df = 0; df < 16; ++df) {
        const short8 vb = *(const short8*)&Vts[(16 * df + l15) * VLD + 8 * l4];
        acc[df] = __builtin_amdgcn_mfma_f32_16x16x32_bf16(pa, vb, acc[df], 0, 0, 0);
      }
    }
  }
  // den: reduce across the 16 lanes of each row group
  #pragma unroll
  for (int ri = 0; ri < 4; ++ri) {
    den[ri] += __shfl_xor(den[ri], 1);
    den[ri] += __shfl_xor(den[ri], 2);
    den[ri] += __shfl_xor(den[ri], 4);
    den[ri] += __shfl_xor(den[ri], 8);
  }
  float* op = &out[((size_t)(b * SLEN + myrow)) * (NH * HD) + h * HD + l15];
  #pragma unroll
  for (int ri = 0; ri < 4; ++ri) {
    const float inv = 1.f / den[ri];
    #pragma unroll
    for (int df = 0; df < 16; ++df)
      op[(size_t)ri * (NH * HD) + 16 * df] = acc[df][ri] * inv;
  }
}

extern "C" void kernel_launch(void* const* d_in, const int* in_sizes, int n_in,
                              void* d_out, int out_size, void* d_ws, size_t ws_size,
                              hipStream_t stream) {
  const float* hs  = (const float*)d_in[0];
  const float* fc  = (const float*)d_in[1];
  const float* fs  = (const float*)d_in[2];
  // d_in[3] = mask: pure causal, handled analytically.
  const float* WAq = (const float*)d_in[4];
  const float* WAk = (const float*)d_in[5];
  const float* WAv = (const float*)d_in[6];
  const float* WBq = (const float*)d_in[7];
  const float* WBk = (const float*)d_in[8];
  const float* WBv = (const float*)d_in[9];
  const float* Wo  = (const float*)d_in[10];
  float* out = (float*)d_out;

  // Workspace layout (floats). att aliases Bq+Bk (dead after qkv_rope). ~144 MB peak.
  float* ws   = (float*)d_ws;
  float* Bq   = ws;                               // 4096*1536
  float* Bk   = Bq + (size_t)MTOT * 1536;         // 4096*512
  float* Bv   = Bk + (size_t)MTOT * 512;          // 4096*512
  float* qT   = Bv + (size_t)MTOT * 512;          // [2,8,2048,256]
  float* kT   = qT + (size_t)2 * NH * SLEN * HD;
  float* vT   = kT + (size_t)2 * NH * SLEN * HD;
  float* Aall = vT + (size_t)2 * NH * SLEN * HD;  // [4096, 80]
  float* att  = ws;                               // [4096,2048] over Bq+Bk

  gemm_mfma_ext<<<dim3(13, MTOT / 128), 256, 0, stream>>>(hs, WBq, WAq, WAk, WAv,
                                                          Bq, Aall, 1536);
  gemm_mfma<<<dim3(512 / 128, MTOT / 128), 256, 0, stream>>>(hs, WBk, Bk, 512);
  gemm_mfma<<<dim3(512 / 128, MTOT / 128), 256, 0, stream>>>(hs, WBv, Bv, 512);
  qkv_rope<<<MTOT, 256, 0, stream>>>(Aall, Bq, Bk, Bv, fc, fs, qT, kT, vT);
  attn_mfma<<<dim3(32 * 16), 256, 0, stream>>>(qT, kT, vT, att);
  gemm_mfma<<<dim3(HID / 128, MTOT / 128), 256, 0, stream>>>(att, Wo, out, HID);
}

// Round 13
// 747.334 us; speedup vs baseline: 3.8296x; 1.0011x over previous
//
#include <hip/hip_runtime.h>
#include <cstdint>

#define HID 2048
#define SLEN 2048
#define NH 8
#define HD 256
#define MTOT 4096

constexpr float SCALING = 0.0625f;   // 256^-0.5
constexpr float SOFTCAP = 50.0f;

typedef __attribute__((ext_vector_type(8))) short short8;
typedef __attribute__((ext_vector_type(4))) float f32x4;

__device__ __forceinline__ uint16_t bfhi(float x) {
  return (uint16_t)(__float_as_uint(x) >> 16);           // truncate
}
__device__ __forceinline__ float bf2f(uint16_t h) {
  return __uint_as_float((uint32_t)h << 16);
}
__device__ __forceinline__ void packsplit8(const float4 a, const float4 b,
                                           short8& hi, short8& lo) {
  const float x[8] = {a.x, a.y, a.z, a.w, b.x, b.y, b.z, b.w};
  #pragma unroll
  for (int i = 0; i < 8; ++i) {
    const uint32_t u = __float_as_uint(x[i]);
    const uint16_t h = (uint16_t)(u >> 16);
    const float r = x[i] - bf2f(h);
    hi[i] = (short)h;
    lo[i] = (short)(__float_as_uint(r) >> 16);
  }
}

// ---------------- split-bf16 MFMA GEMM: C[M,N] = A[M,2048] @ B[2048,N] ----------------
// (validated r9; unchanged)
__global__ __launch_bounds__(256) void gemm_mfma(
    const float* __restrict__ A, const float* __restrict__ B,
    float* __restrict__ C, int N) {
  __shared__ uint16_t Ah[8 * 520], Al[8 * 520], Bh[8 * 520], Bl[8 * 520];
  const int tid = threadIdx.x;
  const int row0 = blockIdx.y * 128;
  const int col0 = blockIdx.x * 128;
  const int lane = tid & 63;
  const int wv = tid >> 6;
  const int wr = wv >> 1, wc = wv & 1;

  f32x4 acc[4][4];
  #pragma unroll
  for (int m = 0; m < 4; ++m)
    #pragma unroll
    for (int n = 0; n < 4; ++n) acc[m][n] = (f32x4){0.f, 0.f, 0.f, 0.f};

  const int ar = tid >> 1;
  const int akb = (tid & 1) * 16;
  const int bkk = tid >> 3;
  const int bcg = tid & 7;

  for (int k0 = 0; k0 < 2048; k0 += 32) {
    float4 av[4], bv[4];
    #pragma unroll
    for (int c = 0; c < 4; ++c)
      av[c] = *(const float4*)&A[(size_t)(row0 + ar) * 2048 + k0 + akb + 4 * c];
    #pragma unroll
    for (int c = 0; c < 4; ++c)
      bv[c] = *(const float4*)&B[(size_t)(k0 + bkk) * N + col0 + bcg * 16 + 4 * c];
    __syncthreads();
    #pragma unroll
    for (int c = 0; c < 4; ++c) {
      const int kk = akb + 4 * c;
      const int idx = (ar >> 4) * 520 + (((ar & 15) | ((kk >> 3) << 4)) << 3) + (kk & 7);
      const float x0 = av[c].x, x1 = av[c].y, x2 = av[c].z, x3 = av[c].w;
      const uint16_t h0 = bfhi(x0), h1 = bfhi(x1), h2 = bfhi(x2), h3 = bfhi(x3);
      const uint16_t g0 = bfhi(x0 - bf2f(h0)), g1 = bfhi(x1 - bf2f(h1));
      const uint16_t g2 = bfhi(x2 - bf2f(h2)), g3 = bfhi(x3 - bf2f(h3));
      *(uint2*)&Ah[idx] = make_uint2((uint32_t)h0 | ((uint32_t)h1 << 16),
                                     (uint32_t)h2 | ((uint32_t)h3 << 16));
      *(uint2*)&Al[idx] = make_uint2((uint32_t)g0 | ((uint32_t)g1 << 16),
                                     (uint32_t)g2 | ((uint32_t)g3 << 16));
    }
    #pragma unroll
    for (int c = 0; c < 4; ++c) {
      const float xs4[4] = {bv[c].x, bv[c].y, bv[c].z, bv[c].w};
      #pragma unroll
      for (int i = 0; i < 4; ++i) {
        const int j = bcg * 16 + 4 * c + i;
        const uint16_t h = bfhi(xs4[i]);
        const uint16_t g = bfhi(xs4[i] - bf2f(h));
        const int idx = (j >> 4) * 520 + (((j & 15) | ((bkk >> 3) << 4)) << 3) + (bkk & 7);
        Bh[idx] = h;
        Bl[idx] = g;
      }
    }
    __syncthreads();
    short8 bhf[4], blf[4];
    #pragma unroll
    for (int nf = 0; nf < 4; ++nf) {
      bhf[nf] = *(const short8*)&Bh[(wc * 4 + nf) * 520 + lane * 8];
      blf[nf] = *(const short8*)&Bl[(wc * 4 + nf) * 520 + lane * 8];
    }
    #pragma unroll
    for (int m = 0; m < 4; ++m) {
      const short8 ahf = *(const short8*)&Ah[(wr * 4 + m) * 520 + lane * 8];
      const short8 alf = *(const short8*)&Al[(wr * 4 + m) * 520 + lane * 8];
      #pragma unroll
      for (int nf = 0; nf < 4; ++nf) {
        acc[m][nf] = __builtin_amdgcn_mfma_f32_16x16x32_bf16(ahf, bhf[nf], acc[m][nf], 0, 0, 0);
        acc[m][nf] = __builtin_amdgcn_mfma_f32_16x16x32_bf16(ahf, blf[nf], acc[m][nf], 0, 0, 0);
        acc[m][nf] = __builtin_amdgcn_mfma_f32_16x16x32_bf16(alf, bhf[nf], acc[m][nf], 0, 0, 0);
      }
    }
  }
  #pragma unroll
  for (int m = 0; m < 4; ++m)
    #pragma unroll
    for (int nf = 0; nf < 4; ++nf) {
      const int row = row0 + wr * 64 + m * 16 + ((lane >> 4) << 2);
      const int col = col0 + wc * 64 + nf * 16 + (lane & 15);
      #pragma unroll
      for (int ri = 0; ri < 4; ++ri)
        C[(size_t)(row + ri) * N + col] = acc[m][nf][ri];
    }
}

// --------- gemm_mfma_ext: B_q projection + fused A-projection tile (validated r11) ----
__global__ __launch_bounds__(256) void gemm_mfma_ext(
    const float* __restrict__ A, const float* __restrict__ B,
    const float* __restrict__ WAq, const float* __restrict__ WAk,
    const float* __restrict__ WAv,
    float* __restrict__ C, float* __restrict__ Aout, int N) {
  __shared__ uint16_t Ah[8 * 520], Al[8 * 520], Bh[8 * 520], Bl[8 * 520];
  const int tid = threadIdx.x;
  const int row0 = blockIdx.y * 128;
  const int col0 = blockIdx.x * 128;
  const bool special = (blockIdx.x == gridDim.x - 1);
  const int lane = tid & 63;
  const int wv = tid >> 6;
  const int wr = wv >> 1, wc = wv & 1;

  f32x4 acc[4][4];
  #pragma unroll
  for (int m = 0; m < 4; ++m)
    #pragma unroll
    for (int n = 0; n < 4; ++n) acc[m][n] = (f32x4){0.f, 0.f, 0.f, 0.f};

  const int ar = tid >> 1;
  const int akb = (tid & 1) * 16;
  const int bkk = tid >> 3;
  const int bcg = tid & 7;

  for (int k0 = 0; k0 < 2048; k0 += 32) {
    float4 av[4], bv[4];
    #pragma unroll
    for (int c = 0; c < 4; ++c)
      av[c] = *(const float4*)&A[(size_t)(row0 + ar) * 2048 + k0 + akb + 4 * c];
    if (!special) {
      #pragma unroll
      for (int c = 0; c < 4; ++c)
        bv[c] = *(const float4*)&B[(size_t)(k0 + bkk) * N + col0 + bcg * 16 + 4 * c];
    } else {
      #pragma unroll
      for (int c = 0; c < 4; ++c) {
        if (bcg < 3)
          bv[c] = *(const float4*)&WAq[(size_t)(k0 + bkk) * 48 + bcg * 16 + 4 * c];
        else if (bcg == 3)
          bv[c] = *(const float4*)&WAk[(size_t)(k0 + bkk) * 16 + 4 * c];
        else if (bcg == 4)
          bv[c] = *(const float4*)&WAv[(size_t)(k0 + bkk) * 16 + 4 * c];
        else
          bv[c] = make_float4(0.f, 0.f, 0.f, 0.f);
      }
    }
    __syncthreads();
    #pragma unroll
    for (int c = 0; c < 4; ++c) {
      const int kk = akb + 4 * c;
      const int idx = (ar >> 4) * 520 + (((ar & 15) | ((kk >> 3) << 4)) << 3) + (kk & 7);
      const float x0 = av[c].x, x1 = av[c].y, x2 = av[c].z, x3 = av[c].w;
      const uint16_t h0 = bfhi(x0), h1 = bfhi(x1), h2 = bfhi(x2), h3 = bfhi(x3);
      const uint16_t g0 = bfhi(x0 - bf2f(h0)), g1 = bfhi(x1 - bf2f(h1));
      const uint16_t g2 = bfhi(x2 - bf2f(h2)), g3 = bfhi(x3 - bf2f(h3));
      *(uint2*)&Ah[idx] = make_uint2((uint32_t)h0 | ((uint32_t)h1 << 16),
                                     (uint32_t)h2 | ((uint32_t)h3 << 16));
      *(uint2*)&Al[idx] = make_uint2((uint32_t)g0 | ((uint32_t)g1 << 16),
                                     (uint32_t)g2 | ((uint32_t)g3 << 16));
    }
    #pragma unroll
    for (int c = 0; c < 4; ++c) {
      const float xs4[4] = {bv[c].x, bv[c].y, bv[c].z, bv[c].w};
      #pragma unroll
      for (int i = 0; i < 4; ++i) {
        const int j = bcg * 16 + 4 * c + i;
        const uint16_t h = bfhi(xs4[i]);
        const uint16_t g = bfhi(xs4[i] - bf2f(h));
        const int idx = (j >> 4) * 520 + (((j & 15) | ((bkk >> 3) << 4)) << 3) + (bkk & 7);
        Bh[idx] = h;
        Bl[idx] = g;
      }
    }
    __syncthreads();
    short8 bhf[4], blf[4];
    #pragma unroll
    for (int nf = 0; nf < 4; ++nf) {
      bhf[nf] = *(const short8*)&Bh[(wc * 4 + nf) * 520 + lane * 8];
      blf[nf] = *(const short8*)&Bl[(wc * 4 + nf) * 520 + lane * 8];
    }
    #pragma unroll
    for (int m = 0; m < 4; ++m) {
      const short8 ahf = *(const short8*)&Ah[(wr * 4 + m) * 520 + lane * 8];
      const short8 alf = *(const short8*)&Al[(wr * 4 + m) * 520 + lane * 8];
      #pragma unroll
      for (int nf = 0; nf < 4; ++nf) {
        acc[m][nf] = __builtin_amdgcn_mfma_f32_16x16x32_bf16(ahf, bhf[nf], acc[m][nf], 0, 0, 0);
        acc[m][nf] = __builtin_amdgcn_mfma_f32_16x16x32_bf16(ahf, blf[nf], acc[m][nf], 0, 0, 0);
        acc[m][nf] = __builtin_amdgcn_mfma_f32_16x16x32_bf16(alf, bhf[nf], acc[m][nf], 0, 0, 0);
      }
    }
  }
  #pragma unroll
  for (int m = 0; m < 4; ++m)
    #pragma unroll
    for (int nf = 0; nf < 4; ++nf) {
      const int row = row0 + wr * 64 + m * 16 + ((lane >> 4) << 2);
      const int col = wc * 64 + nf * 16 + (lane & 15);
      if (!special) {
        #pragma unroll
        for (int ri = 0; ri < 4; ++ri)
          C[(size_t)(row + ri) * N + col0 + col] = acc[m][nf][ri];
      } else if (col < 80) {
        #pragma unroll
        for (int ri = 0; ri < 4; ++ri)
          Aout[(size_t)(row + ri) * 80 + col] = acc[m][nf][ri];
      }
    }
}

// ------------- RoPE + rank contraction v2 (validated r11, unchanged) ------------------
__global__ __launch_bounds__(256) void qkv_rope(
    const float* __restrict__ Aall,
    const float* __restrict__ Bq, const float* __restrict__ Bk,
    const float* __restrict__ Bv,
    const float* __restrict__ fc, const float* __restrict__ fs,
    float* __restrict__ q, float* __restrict__ k, float* __restrict__ v) {
  const int m = blockIdx.x;        // 0..4095  (b*SLEN + s)
  const int s = m & (SLEN - 1);
  const int b = m >> 11;
  const int tid = threadIdx.x;
  __shared__ float Al[80];         // A_q[48] | A_k[16] | A_v[16]

  if (tid < 20) *(float4*)&Al[tid * 4] = *(const float4*)&Aall[(size_t)m * 80 + tid * 4];
  __syncthreads();

  const size_t tbase = (size_t)b * NH * SLEN * HD + (size_t)s * HD;
  if (tid < 128) {
    const int j = tid;
    const float cz = fc[s * 128 + j], sz = fs[s * 128 + j];
    float qe[8], qo[8];
    #pragma unroll
    for (int hh = 0; hh < 8; ++hh) { qe[hh] = 0.f; qo[hh] = 0.f; }
    #pragma unroll
    for (int r = 0; r < 6; ++r) {
      const float2 x = *(const float2*)&Bq[(size_t)m * 1536 + r * 256 + 2 * j];
      const float re = x.x * cz - x.y * sz;
      const float ro = x.x * sz + x.y * cz;
      #pragma unroll
      for (int hh = 0; hh < 8; ++hh) {
        const float a = Al[hh * 6 + r];
        qe[hh] = fmaf(a, re, qe[hh]);
        qo[hh] = fmaf(a, ro, qo[hh]);
      }
    }
    const float qs = SCALING / 6.f;
    #pragma unroll
    for (int hh = 0; hh < 8; ++hh) {
      float2 o; o.x = qe[hh] * qs; o.y = qo[hh] * qs;
      *(float2*)&q[tbase + (size_t)hh * SLEN * HD + 2 * j] = o;
    }
  } else {
    const int j = tid - 128;
    const float cz = fc[s * 128 + j], sz = fs[s * 128 + j];
    float ke_[8], ko_[8], ve_[8], vo_[8];
    #pragma unroll
    for (int hh = 0; hh < 8; ++hh) { ke_[hh]=0.f; ko_[hh]=0.f; ve_[hh]=0.f; vo_[hh]=0.f; }
    #pragma unroll
    for (int r = 0; r < 2; ++r) {
      const float2 xk = *(const float2*)&Bk[(size_t)m * 512 + r * 256 + 2 * j];
      const float2 xv = *(const float2*)&Bv[(size_t)m * 512 + r * 256 + 2 * j];
      const float re = xk.x * cz - xk.y * sz;
      const float ro = xk.x * sz + xk.y * cz;
      #pragma unroll
      for (int hh = 0; hh < 8; ++hh) {
        const float ak = Al[48 + hh * 2 + r];
        const float av = Al[64 + hh * 2 + r];
        ke_[hh] = fmaf(ak, re, ke_[hh]);
        ko_[hh] = fmaf(ak, ro, ko_[hh]);
        ve_[hh] = fmaf(av, xv.x, ve_[hh]);
        vo_[hh] = fmaf(av, xv.y, vo_[hh]);
      }
    }
    #pragma unroll
    for (int hh = 0; hh < 8; ++hh) {
      float2 ok; ok.x = ke_[hh] * 0.5f; ok.y = ko_[hh] * 0.5f;
      *(float2*)&k[tbase + (size_t)hh * SLEN * HD + 2 * j] = ok;
      float2 ov; ov.x = ve_[hh] * 0.5f; ov.y = vo_[hh] * 0.5f;
      *(float2*)&v[tbase + (size_t)hh * SLEN * HD + 2 * j] = ov;
    }
  }
}

// ------------- causal softcapped attention v6: raw barriers + split QK chains ---------
// vs v5: (1) __syncthreads -> {s_waitcnt lgkmcnt(0); s_barrier} via inline asm/builtin.
// Raw s_barrier does NOT drain vmcnt, so next-tile global loads genuinely stay in
// flight under the MFMA phase (the compiler's counted vmcnt wait lands at the next
// convert's first kreg use). (2) QK^T uses 3 independent accumulator chains (one per
// split term, depth 8) instead of one 24-deep serial chain.
#define KLD 264
#define VLD 40
#define PLD 40
__global__ __launch_bounds__(256, 2) void attn_mfma(
    const float* __restrict__ q, const float* __restrict__ k,
    const float* __restrict__ v, float* __restrict__ out) {
  __shared__ uint16_t Khs[32 * KLD];
  __shared__ uint16_t Kls[32 * KLD];
  __shared__ uint16_t Vts[256 * VLD];
  __shared__ uint16_t Ps[4 * 16 * PLD];
  const int tid = threadIdx.x;
  const int lane = tid & 63;
  const int w = tid >> 6;
  const int l15 = lane & 15;
  const int l4 = lane >> 4;
  const int bid = blockIdx.x;
  const int qt = 31 - (bid >> 4);      // heavy q-tiles first (LPT)
  const int bh = bid & 15;
  const int b = bh >> 3, h = bh & 7;
  const int q0 = qt * 64;
  const size_t base = (size_t)bh * SLEN * HD;

  short8 qh[8], ql[8];
  {
    const float* qp = &q[base + (size_t)(q0 + w * 16 + l15) * HD + 8 * l4];
    #pragma unroll
    for (int f = 0; f < 8; ++f) {
      const float4 a = *(const float4*)&qp[32 * f];
      const float4 bb = *(const float4*)&qp[32 * f + 4];
      packsplit8(a, bb, qh[f], ql[f]);
    }
  }
  f32x4 acc[16];
  #pragma unroll
  for (int df = 0; df < 16; ++df) acc[df] = (f32x4){0.f, 0.f, 0.f, 0.f};
  float den[4] = {0.f, 0.f, 0.f, 0.f};

  const int myrow = q0 + w * 16 + l4 * 4;
  const int rowmax = q0 + w * 16 + 15;
  const int nkt = 2 * qt + 2;
  const int sr = tid & 31;
  const int sc = (tid >> 5) * 32;
  const float* kb_ = &k[base];
  const float* vb_ = &v[base];

  // prologue: tile 0 -> registers
  float4 kreg[8], vreg[8];
  {
    const float* kp = &kb_[(size_t)sr * HD + sc];
    const float* vp = &vb_[(size_t)sr * HD + sc];
    #pragma unroll
    for (int j = 0; j < 8; ++j) kreg[j] = *(const float4*)&kp[4 * j];
    #pragma unroll
    for (int j = 0; j < 8; ++j) vreg[j] = *(const float4*)&vp[4 * j];
  }

  for (int kt = 0; kt < nkt; ++kt) {
    const int k0 = kt * 32;
    // convert current tile regs -> LDS (compiler inserts counted vmcnt wait for kreg)
    #pragma unroll
    for (int j = 0; j < 4; ++j) {
      short8 hi, lo;
      packsplit8(kreg[2 * j], kreg[2 * j + 1], hi, lo);
      *(short8*)&Khs[sr * KLD + sc + 8 * j] = hi;
      *(short8*)&Kls[sr * KLD + sc + 8 * j] = lo;
    }
    #pragma unroll
    for (int j = 0; j < 8; ++j) {
      Vts[(sc + 4 * j + 0) * VLD + sr] = bfhi(vreg[j].x);
      Vts[(sc + 4 * j + 1) * VLD + sr] = bfhi(vreg[j].y);
      Vts[(sc + 4 * j + 2) * VLD + sr] = bfhi(vreg[j].z);
      Vts[(sc + 4 * j + 3) * VLD + sr] = bfhi(vreg[j].w);
    }
    // issue NEXT tile's loads; raw barrier below does NOT drain vmcnt
    if (kt + 1 < nkt) {
      const float* kp = &kb_[(size_t)(k0 + 32 + sr) * HD + sc];
      const float* vp = &vb_[(size_t)(k0 + 32 + sr) * HD + sc];
      #pragma unroll
      for (int j = 0; j < 8; ++j) kreg[j] = *(const float4*)&kp[4 * j];
      #pragma unroll
      for (int j = 0; j < 8; ++j) vreg[j] = *(const float4*)&vp[4 * j];
    }
    asm volatile("s_waitcnt lgkmcnt(0)" ::: "memory");
    __builtin_amdgcn_sched_barrier(0);
    __builtin_amdgcn_s_barrier();          // LDS tile visible; global loads in flight
    __builtin_amdgcn_sched_barrier(0);
    if (k0 <= rowmax) {
      // QK^T: 2 k-frags x 8 d-chunks x 3 split terms, 3 independent chains
      f32x4 sfr[2];
      #pragma unroll
      for (int kf = 0; kf < 2; ++kf) {
        f32x4 c0 = (f32x4){0.f, 0.f, 0.f, 0.f};
        f32x4 c1 = c0, c2 = c0;
        #pragma unroll
        for (int dc = 0; dc < 8; ++dc) {
          const int off = (16 * kf + l15) * KLD + 32 * dc + 8 * l4;
          const short8 kh = *(const short8*)&Khs[off];
          const short8 kl = *(const short8*)&Kls[off];
          c0 = __builtin_amdgcn_mfma_f32_16x16x32_bf16(qh[dc], kh, c0, 0, 0, 0);
          c1 = __builtin_amdgcn_mfma_f32_16x16x32_bf16(qh[dc], kl, c1, 0, 0, 0);
          c2 = __builtin_amdgcn_mfma_f32_16x16x32_bf16(ql[dc], kh, c2, 0, 0, 0);
        }
        sfr[kf] = (c0 + c1) + c2;
      }
      // softcap + exp (fixed-max) + causal mask; P -> wave-private LDS (bf16)
      uint16_t* pw = &Ps[w * 16 * PLD];
      #pragma unroll
      for (int kf = 0; kf < 2; ++kf) {
        #pragma unroll
        for (int ri = 0; ri < 4; ++ri) {
          const float pd = sfr[kf][ri];
          const float t1 = exp2f(pd * 0.0577078016f);
          float e = exp2f(-144.26950409f * __builtin_amdgcn_rcpf(t1 + 1.f));
          if (k0 + 16 * kf + l15 > myrow + ri) e = 0.f;
          den[ri] += e;
          pw[(l4 * 4 + ri) * PLD + 16 * kf + l15] = bfhi(e);
        }
      }
      // PV: A = P[16q][32j], B = Vt frags [32j][16d], 16 independent d-frags
      const short8 pa = *(const short8*)&pw[l15 * PLD + 8 * l4];
      #pragma unroll
      for (int df = 0; df < 16; ++df) {
        const short8 vb = *(const short8*)&Vts[(16 * df + l15) * VLD + 8 * l4];
        acc[df] = __builtin_amdgcn_mfma_f32_16x16x32_bf16(pa, vb, acc[df], 0, 0, 0);
      }
    }
    __builtin_amdgcn_sched_barrier(0);
    __builtin_amdgcn_s_barrier();          // all waves done reading this tile's LDS
    __builtin_amdgcn_sched_barrier(0);
  }
  #pragma unroll
  for (int ri = 0; ri < 4; ++ri) {
    den[ri] += __shfl_xor(den[ri], 1);
    den[ri] += __shfl_xor(den[ri], 2);
    den[ri] += __shfl_xor(den[ri], 4);
    den[ri] += __shfl_xor(den[ri], 8);
  }
  float* op = &out[((size_t)(b * SLEN + myrow)) * (NH * HD) + h * HD + l15];
  #pragma unroll
  for (int ri = 0; ri < 4; ++ri) {
    const float inv = 1.f / den[ri];
    #pragma unroll
    for (int df = 0; df < 16; ++df)
      op[(size_t)ri * (NH * HD) + 16 * df] = acc[df][ri] * inv;
  }
}

extern "C" void kernel_launch(void* const* d_in, const int* in_sizes, int n_in,
                              void* d_out, int out_size, void* d_ws, size_t ws_size,
                              hipStream_t stream) {
  const float* hs  = (const float*)d_in[0];
  const float* fc  = (const float*)d_in[1];
  const float* fs  = (const float*)d_in[2];
  // d_in[3] = mask: pure causal, handled analytically.
  const float* WAq = (const float*)d_in[4];
  const float* WAk = (const float*)d_in[5];
  const float* WAv = (const float*)d_in[6];
  const float* WBq = (const float*)d_in[7];
  const float* WBk = (const float*)d_in[8];
  const float* WBv = (const float*)d_in[9];
  const float* Wo  = (const float*)d_in[10];
  float* out = (float*)d_out;

  // Workspace layout (floats). att aliases Bq+Bk (dead after qkv_rope). ~144 MB peak.
  float* ws   = (float*)d_ws;
  float* Bq   = ws;                               // 4096*1536
  float* Bk   = Bq + (size_t)MTOT * 1536;         // 4096*512
  float* Bv   = Bk + (size_t)MTOT * 512;          // 4096*512
  float* qT   = Bv + (size_t)MTOT * 512;          // [2,8,2048,256]
  float* kT   = qT + (size_t)2 * NH * SLEN * HD;
  float* vT   = kT + (size_t)2 * NH * SLEN * HD;
  float* Aall = vT + (size_t)2 * NH * SLEN * HD;  // [4096, 80]
  float* att  = ws;                               // [4096,2048] over Bq+Bk

  gemm_mfma_ext<<<dim3(13, MTOT / 128), 256, 0, stream>>>(hs, WBq, WAq, WAk, WAv,
                                                          Bq, Aall, 1536);
  gemm_mfma<<<dim3(512 / 128, MTOT / 128), 256, 0, stream>>>(hs, WBk, Bk, 512);
  gemm_mfma<<<dim3(512 / 128, MTOT / 128), 256, 0, stream>>>(hs, WBv, Bv, 512);
  qkv_rope<<<MTOT, 256, 0, stream>>>(Aall, Bq, Bk, Bv, fc, fs, qT, kT, vT);
  attn_mfma<<<dim3(32 * 16), 256, 0, stream>>>(qT, kT, vT, att);
  gemm_mfma<<<dim3(HID / 128, MTOT / 128), 256, 0, stream>>>(att, Wo, out, HID);
}

// Round 15
// 715.106 us; speedup vs baseline: 4.0022x; 1.0451x over previous
//
#include <hip/hip_runtime.h>
#include <cstdint>

#define HID 2048
#define SLEN 2048
#define NH 8
#define HD 256
#define MTOT 4096

constexpr float SCALING = 0.0625f;   // 256^-0.5
constexpr float SOFTCAP = 50.0f;

typedef __attribute__((ext_vector_type(8))) short short8;
typedef __attribute__((ext_vector_type(4))) float f32x4;

__device__ __forceinline__ uint16_t bfhi(float x) {
  return (uint16_t)(__float_as_uint(x) >> 16);           // truncate
}
__device__ __forceinline__ float bf2f(uint16_t h) {
  return __uint_as_float((uint32_t)h << 16);
}
__device__ __forceinline__ void packsplit8(const float4 a, const float4 b,
                                           short8& hi, short8& lo) {
  const float x[8] = {a.x, a.y, a.z, a.w, b.x, b.y, b.z, b.w};
  #pragma unroll
  for (int i = 0; i < 8; ++i) {
    const uint32_t u = __float_as_uint(x[i]);
    const uint16_t h = (uint16_t)(u >> 16);
    const float r = x[i] - bf2f(h);
    hi[i] = (short)h;
    lo[i] = (short)(__float_as_uint(r) >> 16);
  }
}
__device__ __forceinline__ void atomAddF(float* p, float v) {
  __hip_atomic_fetch_add(p, v, __ATOMIC_RELAXED, __HIP_MEMORY_SCOPE_AGENT);
}

// ---------------- split-bf16 MFMA GEMM: C[M,N] = A[M,2048] @ B[2048,N] ----------------
// (validated r9; unchanged)
__global__ __launch_bounds__(256) void gemm_mfma(
    const float* __restrict__ A, const float* __restrict__ B,
    float* __restrict__ C, int N) {
  __shared__ uint16_t Ah[8 * 520], Al[8 * 520], Bh[8 * 520], Bl[8 * 520];
  const int tid = threadIdx.x;
  const int row0 = blockIdx.y * 128;
  const int col0 = blockIdx.x * 128;
  const int lane = tid & 63;
  const int wv = tid >> 6;
  const int wr = wv >> 1, wc = wv & 1;

  f32x4 acc[4][4];
  #pragma unroll
  for (int m = 0; m < 4; ++m)
    #pragma unroll
    for (int n = 0; n < 4; ++n) acc[m][n] = (f32x4){0.f, 0.f, 0.f, 0.f};

  const int ar = tid >> 1;
  const int akb = (tid & 1) * 16;
  const int bkk = tid >> 3;
  const int bcg = tid & 7;

  for (int k0 = 0; k0 < 2048; k0 += 32) {
    float4 av[4], bv[4];
    #pragma unroll
    for (int c = 0; c < 4; ++c)
      av[c] = *(const float4*)&A[(size_t)(row0 + ar) * 2048 + k0 + akb + 4 * c];
    #pragma unroll
    for (int c = 0; c < 4; ++c)
      bv[c] = *(const float4*)&B[(size_t)(k0 + bkk) * N + col0 + bcg * 16 + 4 * c];
    __syncthreads();
    #pragma unroll
    for (int c = 0; c < 4; ++c) {
      const int kk = akb + 4 * c;
      const int idx = (ar >> 4) * 520 + (((ar & 15) | ((kk >> 3) << 4)) << 3) + (kk & 7);
      const float x0 = av[c].x, x1 = av[c].y, x2 = av[c].z, x3 = av[c].w;
      const uint16_t h0 = bfhi(x0), h1 = bfhi(x1), h2 = bfhi(x2), h3 = bfhi(x3);
      const uint16_t g0 = bfhi(x0 - bf2f(h0)), g1 = bfhi(x1 - bf2f(h1));
      const uint16_t g2 = bfhi(x2 - bf2f(h2)), g3 = bfhi(x3 - bf2f(h3));
      *(uint2*)&Ah[idx] = make_uint2((uint32_t)h0 | ((uint32_t)h1 << 16),
                                     (uint32_t)h2 | ((uint32_t)h3 << 16));
      *(uint2*)&Al[idx] = make_uint2((uint32_t)g0 | ((uint32_t)g1 << 16),
                                     (uint32_t)g2 | ((uint32_t)g3 << 16));
    }
    #pragma unroll
    for (int c = 0; c < 4; ++c) {
      const float xs4[4] = {bv[c].x, bv[c].y, bv[c].z, bv[c].w};
      #pragma unroll
      for (int i = 0; i < 4; ++i) {
        const int j = bcg * 16 + 4 * c + i;
        const uint16_t h = bfhi(xs4[i]);
        const uint16_t g = bfhi(xs4[i] - bf2f(h));
        const int idx = (j >> 4) * 520 + (((j & 15) | ((bkk >> 3) << 4)) << 3) + (bkk & 7);
        Bh[idx] = h;
        Bl[idx] = g;
      }
    }
    __syncthreads();
    short8 bhf[4], blf[4];
    #pragma unroll
    for (int nf = 0; nf < 4; ++nf) {
      bhf[nf] = *(const short8*)&Bh[(wc * 4 + nf) * 520 + lane * 8];
      blf[nf] = *(const short8*)&Bl[(wc * 4 + nf) * 520 + lane * 8];
    }
    #pragma unroll
    for (int m = 0; m < 4; ++m) {
      const short8 ahf = *(const short8*)&Ah[(wr * 4 + m) * 520 + lane * 8];
      const short8 alf = *(const short8*)&Al[(wr * 4 + m) * 520 + lane * 8];
      #pragma unroll
      for (int nf = 0; nf < 4; ++nf) {
        acc[m][nf] = __builtin_amdgcn_mfma_f32_16x16x32_bf16(ahf, bhf[nf], acc[m][nf], 0, 0, 0);
        acc[m][nf] = __builtin_amdgcn_mfma_f32_16x16x32_bf16(ahf, blf[nf], acc[m][nf], 0, 0, 0);
        acc[m][nf] = __builtin_amdgcn_mfma_f32_16x16x32_bf16(alf, bhf[nf], acc[m][nf], 0, 0, 0);
      }
    }
  }
  #pragma unroll
  for (int m = 0; m < 4; ++m)
    #pragma unroll
    for (int nf = 0; nf < 4; ++nf) {
      const int row = row0 + wr * 64 + m * 16 + ((lane >> 4) << 2);
      const int col = col0 + wc * 64 + nf * 16 + (lane & 15);
      #pragma unroll
      for (int ri = 0; ri < 4; ++ri)
        C[(size_t)(row + ri) * N + col] = acc[m][nf][ri];
    }
}

// --------- gemm_mfma_ext: B_q projection + fused A-projection tile (validated r11) ----
__global__ __launch_bounds__(256) void gemm_mfma_ext(
    const float* __restrict__ A, const float* __restrict__ B,
    const float* __restrict__ WAq, const float* __restrict__ WAk,
    const float* __restrict__ WAv,
    float* __restrict__ C, float* __restrict__ Aout, int N) {
  __shared__ uint16_t Ah[8 * 520], Al[8 * 520], Bh[8 * 520], Bl[8 * 520];
  const int tid = threadIdx.x;
  const int row0 = blockIdx.y * 128;
  const int col0 = blockIdx.x * 128;
  const bool special = (blockIdx.x == gridDim.x - 1);
  const int lane = tid & 63;
  const int wv = tid >> 6;
  const int wr = wv >> 1, wc = wv & 1;

  f32x4 acc[4][4];
  #pragma unroll
  for (int m = 0; m < 4; ++m)
    #pragma unroll
    for (int n = 0; n < 4; ++n) acc[m][n] = (f32x4){0.f, 0.f, 0.f, 0.f};

  const int ar = tid >> 1;
  const int akb = (tid & 1) * 16;
  const int bkk = tid >> 3;
  const int bcg = tid & 7;

  for (int k0 = 0; k0 < 2048; k0 += 32) {
    float4 av[4], bv[4];
    #pragma unroll
    for (int c = 0; c < 4; ++c)
      av[c] = *(const float4*)&A[(size_t)(row0 + ar) * 2048 + k0 + akb + 4 * c];
    if (!special) {
      #pragma unroll
      for (int c = 0; c < 4; ++c)
        bv[c] = *(const float4*)&B[(size_t)(k0 + bkk) * N + col0 + bcg * 16 + 4 * c];
    } else {
      #pragma unroll
      for (int c = 0; c < 4; ++c) {
        if (bcg < 3)
          bv[c] = *(const float4*)&WAq[(size_t)(k0 + bkk) * 48 + bcg * 16 + 4 * c];
        else if (bcg == 3)
          bv[c] = *(const float4*)&WAk[(size_t)(k0 + bkk) * 16 + 4 * c];
        else if (bcg == 4)
          bv[c] = *(const float4*)&WAv[(size_t)(k0 + bkk) * 16 + 4 * c];
        else
          bv[c] = make_float4(0.f, 0.f, 0.f, 0.f);
      }
    }
    __syncthreads();
    #pragma unroll
    for (int c = 0; c < 4; ++c) {
      const int kk = akb + 4 * c;
      const int idx = (ar >> 4) * 520 + (((ar & 15) | ((kk >> 3) << 4)) << 3) + (kk & 7);
      const float x0 = av[c].x, x1 = av[c].y, x2 = av[c].z, x3 = av[c].w;
      const uint16_t h0 = bfhi(x0), h1 = bfhi(x1), h2 = bfhi(x2), h3 = bfhi(x3);
      const uint16_t g0 = bfhi(x0 - bf2f(h0)), g1 = bfhi(x1 - bf2f(h1));
      const uint16_t g2 = bfhi(x2 - bf2f(h2)), g3 = bfhi(x3 - bf2f(h3));
      *(uint2*)&Ah[idx] = make_uint2((uint32_t)h0 | ((uint32_t)h1 << 16),
                                     (uint32_t)h2 | ((uint32_t)h3 << 16));
      *(uint2*)&Al[idx] = make_uint2((uint32_t)g0 | ((uint32_t)g1 << 16),
                                     (uint32_t)g2 | ((uint32_t)g3 << 16));
    }
    #pragma unroll
    for (int c = 0; c < 4; ++c) {
      const float xs4[4] = {bv[c].x, bv[c].y, bv[c].z, bv[c].w};
      #pragma unroll
      for (int i = 0; i < 4; ++i) {
        const int j = bcg * 16 + 4 * c + i;
        const uint16_t h = bfhi(xs4[i]);
        const uint16_t g = bfhi(xs4[i] - bf2f(h));
        const int idx = (j >> 4) * 520 + (((j & 15) | ((bkk >> 3) << 4)) << 3) + (bkk & 7);
        Bh[idx] = h;
        Bl[idx] = g;
      }
    }
    __syncthreads();
    short8 bhf[4], blf[4];
    #pragma unroll
    for (int nf = 0; nf < 4; ++nf) {
      bhf[nf] = *(const short8*)&Bh[(wc * 4 + nf) * 520 + lane * 8];
      blf[nf] = *(const short8*)&Bl[(wc * 4 + nf) * 520 + lane * 8];
    }
    #pragma unroll
    for (int m = 0; m < 4; ++m) {
      const short8 ahf = *(const short8*)&Ah[(wr * 4 + m) * 520 + lane * 8];
      const short8 alf = *(const short8*)&Al[(wr * 4 + m) * 520 + lane * 8];
      #pragma unroll
      for (int nf = 0; nf < 4; ++nf) {
        acc[m][nf] = __builtin_amdgcn_mfma_f32_16x16x32_bf16(ahf, bhf[nf], acc[m][nf], 0, 0, 0);
        acc[m][nf] = __builtin_amdgcn_mfma_f32_16x16x32_bf16(ahf, blf[nf], acc[m][nf], 0, 0, 0);
        acc[m][nf] = __builtin_amdgcn_mfma_f32_16x16x32_bf16(alf, bhf[nf], acc[m][nf], 0, 0, 0);
      }
    }
  }
  #pragma unroll
  for (int m = 0; m < 4; ++m)
    #pragma unroll
    for (int nf = 0; nf < 4; ++nf) {
      const int row = row0 + wr * 64 + m * 16 + ((lane >> 4) << 2);
      const int col = wc * 64 + nf * 16 + (lane & 15);
      if (!special) {
        #pragma unroll
        for (int ri = 0; ri < 4; ++ri)
          C[(size_t)(row + ri) * N + col0 + col] = acc[m][nf][ri];
      } else if (col < 80) {
        #pragma unroll
        for (int ri = 0; ri < 4; ++ri)
          Aout[(size_t)(row + ri) * 80 + col] = acc[m][nf][ri];
      }
    }
}

// ------------- RoPE + rank contraction v2 (validated r11, unchanged) ------------------
__global__ __launch_bounds__(256) void qkv_rope(
    const float* __restrict__ Aall,
    const float* __restrict__ Bq, const float* __restrict__ Bk,
    const float* __restrict__ Bv,
    const float* __restrict__ fc, const float* __restrict__ fs,
    float* __restrict__ q, float* __restrict__ k, float* __restrict__ v) {
  const int m = blockIdx.x;        // 0..4095  (b*SLEN + s)
  const int s = m & (SLEN - 1);
  const int b = m >> 11;
  const int tid = threadIdx.x;
  __shared__ float Al[80];         // A_q[48] | A_k[16] | A_v[16]

  if (tid < 20) *(float4*)&Al[tid * 4] = *(const float4*)&Aall[(size_t)m * 80 + tid * 4];
  __syncthreads();

  const size_t tbase = (size_t)b * NH * SLEN * HD + (size_t)s * HD;
  if (tid < 128) {
    const int j = tid;
    const float cz = fc[s * 128 + j], sz = fs[s * 128 + j];
    float qe[8], qo[8];
    #pragma unroll
    for (int hh = 0; hh < 8; ++hh) { qe[hh] = 0.f; qo[hh] = 0.f; }
    #pragma unroll
    for (int r = 0; r < 6; ++r) {
      const float2 x = *(const float2*)&Bq[(size_t)m * 1536 + r * 256 + 2 * j];
      const float re = x.x * cz - x.y * sz;
      const float ro = x.x * sz + x.y * cz;
      #pragma unroll
      for (int hh = 0; hh < 8; ++hh) {
        const float a = Al[hh * 6 + r];
        qe[hh] = fmaf(a, re, qe[hh]);
        qo[hh] = fmaf(a, ro, qo[hh]);
      }
    }
    const float qs = SCALING / 6.f;
    #pragma unroll
    for (int hh = 0; hh < 8; ++hh) {
      float2 o; o.x = qe[hh] * qs; o.y = qo[hh] * qs;
      *(float2*)&q[tbase + (size_t)hh * SLEN * HD + 2 * j] = o;
    }
  } else {
    const int j = tid - 128;
    const float cz = fc[s * 128 + j], sz = fs[s * 128 + j];
    float ke_[8], ko_[8], ve_[8], vo_[8];
    #pragma unroll
    for (int hh = 0; hh < 8; ++hh) { ke_[hh]=0.f; ko_[hh]=0.f; ve_[hh]=0.f; vo_[hh]=0.f; }
    #pragma unroll
    for (int r = 0; r < 2; ++r) {
      const float2 xk = *(const float2*)&Bk[(size_t)m * 512 + r * 256 + 2 * j];
      const float2 xv = *(const float2*)&Bv[(size_t)m * 512 + r * 256 + 2 * j];
      const float re = xk.x * cz - xk.y * sz;
      const float ro = xk.x * sz + xk.y * cz;
      #pragma unroll
      for (int hh = 0; hh < 8; ++hh) {
        const float ak = Al[48 + hh * 2 + r];
        const float av = Al[64 + hh * 2 + r];
        ke_[hh] = fmaf(ak, re, ke_[hh]);
        ko_[hh] = fmaf(ak, ro, ko_[hh]);
        ve_[hh] = fmaf(av, xv.x, ve_[hh]);
        vo_[hh] = fmaf(av, xv.y, vo_[hh]);
      }
    }
    #pragma unroll
    for (int hh = 0; hh < 8; ++hh) {
      float2 ok; ok.x = ke_[hh] * 0.5f; ok.y = ko_[hh] * 0.5f;
      *(float2*)&k[tbase + (size_t)hh * SLEN * HD + 2 * j] = ok;
      float2 ov; ov.x = ve_[hh] * 0.5f; ov.y = vo_[hh] * 0.5f;
      *(float2*)&v[tbase + (size_t)hh * SLEN * HD + 2 * j] = ov;
    }
  }
}

// ------------- zero att + den (harness poisons ws; atomics need zeros) ----------------
__global__ __launch_bounds__(256) void zero_acc(float* __restrict__ att,
                                                float* __restrict__ den) {
  const int idx = blockIdx.x * 256 + threadIdx.x;   // float4 index
  const float4 z = {0.f, 0.f, 0.f, 0.f};
  *(float4*)&att[(size_t)idx * 4] = z;              // grid covers 8,388,608 floats
  if (idx < 8192) *(float4*)&den[(size_t)idx * 4] = z;   // 32768 floats
}

// ------------- normalize: att /= den (den completed by attn atomics) ------------------
__global__ __launch_bounds__(256) void normalize_att(
    float* __restrict__ att, const float* __restrict__ den) {
  const int m = blockIdx.x;              // row 0..4095 = b*2048+s
  const int t = threadIdx.x;
  const int h = t >> 5;                  // col chunk [t*8, t*8+8) -> head
  const float inv = 1.f / den[((size_t)(m >> 11) * 8 + h) * SLEN + (m & 2047)];
  float* p = &att[(size_t)m * 2048 + t * 8];
  float4 a = *(float4*)&p[0], b = *(float4*)&p[4];
  a.x *= inv; a.y *= inv; a.z *= inv; a.w *= inv;
  b.x *= inv; b.y *= inv; b.z *= inv; b.w *= inv;
  *(float4*)&p[0] = a; *(float4*)&p[4] = b;
}

// ------------- causal softcapped attention v7b: balanced fold+halve -------------------
// Same as v7 (r13) — the r13 failure was a WORKSPACE ALIASING bug (den was placed
// inside att's range), not an algorithm bug. den now lives in the Bv region, which
// att does not overlap and which is dead after qkv_rope.
// Fixed-max softmax partials are LINEAR -> k-range splits sum. Block (bh, p, hf):
// q-tile 31-p then q-tile p, k-tiles kt ≡ hf (mod 2). Every block does exactly
// (32-p)+(p+1) = 33 k-iters -> 512 perfectly balanced blocks. Each att/den element
// gets exactly 2 atomic adds -> order-invariant -> deterministic.
#define KLD 264
#define VLD 40
#define PLD 40
__global__ __launch_bounds__(256, 2) void attn_mfma(
    const float* __restrict__ q, const float* __restrict__ k,
    const float* __restrict__ v, float* __restrict__ att,
    float* __restrict__ den_g) {
  __shared__ uint16_t Khs[32 * KLD];
  __shared__ uint16_t Kls[32 * KLD];
  __shared__ uint16_t Vts[256 * VLD];
  __shared__ uint16_t Ps[4 * 16 * PLD];
  const int tid = threadIdx.x;
  const int lane = tid & 63;
  const int w = tid >> 6;
  const int l15 = lane & 15;
  const int l4 = lane >> 4;
  const int bid = blockIdx.x;
  const int bh = bid & 15;             // low bits -> per-bh K/V pins to one XCD L2
  const int p = (bid >> 4) & 15;
  const int hf = bid >> 8;             // k-parity half
  const int b = bh >> 3, h = bh & 7;
  const size_t base = (size_t)bh * SLEN * HD;
  const float* kb_ = &k[base];
  const float* vb_ = &v[base];
  const int sr = tid & 31;
  const int sc = (tid >> 5) * 32;

  #pragma unroll
  for (int sub = 0; sub < 2; ++sub) {
    const int qt = (sub == 0) ? (31 - p) : p;
    const int q0 = qt * 64;
    // Q fragments in registers: rows q0+16w+l15, d = 32f + 8*l4 + e
    short8 qh[8], ql[8];
    {
      const float* qp = &q[base + (size_t)(q0 + w * 16 + l15) * HD + 8 * l4];
      #pragma unroll
      for (int f = 0; f < 8; ++f) {
        const float4 a = *(const float4*)&qp[32 * f];
        const float4 bb = *(const float4*)&qp[32 * f + 4];
        packsplit8(a, bb, qh[f], ql[f]);
      }
    }
    f32x4 acc[16];
    #pragma unroll
    for (int df = 0; df < 16; ++df) acc[df] = (f32x4){0.f, 0.f, 0.f, 0.f};
    float den[4] = {0.f, 0.f, 0.f, 0.f};

    const int myrow = q0 + w * 16 + l4 * 4;
    const int rowmax = q0 + w * 16 + 15;
    const int nkt = 2 * qt + 2;

    float4 kreg[8], vreg[8];
    {
      const float* kp = &kb_[(size_t)(hf * 32 + sr) * HD + sc];
      const float* vp = &vb_[(size_t)(hf * 32 + sr) * HD + sc];
      #pragma unroll
      for (int j = 0; j < 8; ++j) kreg[j] = *(const float4*)&kp[4 * j];
      #pragma unroll
      for (int j = 0; j < 8; ++j) vreg[j] = *(const float4*)&vp[4 * j];
    }

    for (int kt = hf; kt < nkt; kt += 2) {
      const int k0 = kt * 32;
      #pragma unroll
      for (int j = 0; j < 4; ++j) {
        short8 hi, lo;
        packsplit8(kreg[2 * j], kreg[2 * j + 1], hi, lo);
        *(short8*)&Khs[sr * KLD + sc + 8 * j] = hi;
        *(short8*)&Kls[sr * KLD + sc + 8 * j] = lo;
      }
      #pragma unroll
      for (int j = 0; j < 8; ++j) {
        Vts[(sc + 4 * j + 0) * VLD + sr] = bfhi(vreg[j].x);
        Vts[(sc + 4 * j + 1) * VLD + sr] = bfhi(vreg[j].y);
        Vts[(sc + 4 * j + 2) * VLD + sr] = bfhi(vreg[j].z);
        Vts[(sc + 4 * j + 3) * VLD + sr] = bfhi(vreg[j].w);
      }
      if (kt + 2 < nkt) {
        const float* kp = &kb_[(size_t)(k0 + 64 + sr) * HD + sc];
        const float* vp = &vb_[(size_t)(k0 + 64 + sr) * HD + sc];
        #pragma unroll
        for (int j = 0; j < 8; ++j) kreg[j] = *(const float4*)&kp[4 * j];
        #pragma unroll
        for (int j = 0; j < 8; ++j) vreg[j] = *(const float4*)&vp[4 * j];
      }
      asm volatile("s_waitcnt lgkmcnt(0)" ::: "memory");
      __builtin_amdgcn_sched_barrier(0);
      __builtin_amdgcn_s_barrier();
      __builtin_amdgcn_sched_barrier(0);
      if (k0 <= rowmax) {
        f32x4 sfr[2];
        #pragma unroll
        for (int kf = 0; kf < 2; ++kf) {
          f32x4 c0 = (f32x4){0.f, 0.f, 0.f, 0.f};
          f32x4 c1 = c0, c2 = c0;
          #pragma unroll
          for (int dc = 0; dc < 8; ++dc) {
            const int off = (16 * kf + l15) * KLD + 32 * dc + 8 * l4;
            const short8 kh = *(const short8*)&Khs[off];
            const short8 kl = *(const short8*)&Kls[off];
            c0 = __builtin_amdgcn_mfma_f32_16x16x32_bf16(qh[dc], kh, c0, 0, 0, 0);
            c1 = __builtin_amdgcn_mfma_f32_16x16x32_bf16(qh[dc], kl, c1, 0, 0, 0);
            c2 = __builtin_amdgcn_mfma_f32_16x16x32_bf16(ql[dc], kh, c2, 0, 0, 0);
          }
          sfr[kf] = (c0 + c1) + c2;
        }
        uint16_t* pw = &Ps[w * 16 * PLD];
        #pragma unroll
        for (int kf = 0; kf < 2; ++kf) {
          #pragma unroll
          for (int ri = 0; ri < 4; ++ri) {
            const float pd = sfr[kf][ri];
            const float t1 = exp2f(pd * 0.0577078016f);
            float e = exp2f(-144.26950409f * __builtin_amdgcn_rcpf(t1 + 1.f));
            if (k0 + 16 * kf + l15 > myrow + ri) e = 0.f;
            den[ri] += e;
            pw[(l4 * 4 + ri) * PLD + 16 * kf + l15] = bfhi(e);
          }
        }
        const short8 pa = *(const short8*)&pw[l15 * PLD + 8 * l4];
        #pragma unroll
        for (int df = 0; df < 16; ++df) {
          const short8 vb = *(const short8*)&Vts[(16 * df + l15) * VLD + 8 * l4];
          acc[df] = __builtin_amdgcn_mfma_f32_16x16x32_bf16(pa, vb, acc[df], 0, 0, 0);
        }
      }
      __builtin_amdgcn_sched_barrier(0);
      __builtin_amdgcn_s_barrier();
      __builtin_amdgcn_sched_barrier(0);
    }
    // partial den reduce (16 lanes) + atomic merge (2 addends/address -> deterministic)
    #pragma unroll
    for (int ri = 0; ri < 4; ++ri) {
      den[ri] += __shfl_xor(den[ri], 1);
      den[ri] += __shfl_xor(den[ri], 2);
      den[ri] += __shfl_xor(den[ri], 4);
      den[ri] += __shfl_xor(den[ri], 8);
    }
    if (l15 == 0) {
      #pragma unroll
      for (int ri = 0; ri < 4; ++ri)
        atomAddF(&den_g[(size_t)bh * SLEN + myrow + ri], den[ri]);
    }
    float* op = &att[((size_t)(b * SLEN + myrow)) * (NH * HD) + h * HD + l15];
    #pragma unroll
    for (int ri = 0; ri < 4; ++ri)
      #pragma unroll
      for (int df = 0; df < 16; ++df)
        atomAddF(&op[(size_t)ri * (NH * HD) + 16 * df], acc[df][ri]);
  }
}

extern "C" void kernel_launch(void* const* d_in, const int* in_sizes, int n_in,
                              void* d_out, int out_size, void* d_ws, size_t ws_size,
                              hipStream_t stream) {
  const float* hs  = (const float*)d_in[0];
  const float* fc  = (const float*)d_in[1];
  const float* fs  = (const float*)d_in[2];
  // d_in[3] = mask: pure causal, handled analytically.
  const float* WAq = (const float*)d_in[4];
  const float* WAk = (const float*)d_in[5];
  const float* WAv = (const float*)d_in[6];
  const float* WBq = (const float*)d_in[7];
  const float* WBk = (const float*)d_in[8];
  const float* WBv = (const float*)d_in[9];
  const float* Wo  = (const float*)d_in[10];
  float* out = (float*)d_out;

  // Workspace (floats). att = [4096,2048] aliases Bq+Bk EXACTLY (both dead after
  // rope). den lives at the START of the Bv region (dead after rope; att does NOT
  // reach Bv — att ends exactly where Bv begins). No live overlap at any point.
  float* ws   = (float*)d_ws;
  float* Bq   = ws;                               // 4096*1536 = 6,291,456
  float* Bk   = Bq + (size_t)MTOT * 1536;         // 4096*512  = 2,097,152
  float* Bv   = Bk + (size_t)MTOT * 512;          // 4096*512  = 2,097,152
  float* qT   = Bv + (size_t)MTOT * 512;          // [2,8,2048,256]
  float* kT   = qT + (size_t)2 * NH * SLEN * HD;
  float* vT   = kT + (size_t)2 * NH * SLEN * HD;
  float* Aall = vT + (size_t)2 * NH * SLEN * HD;  // [4096, 80]
  float* att  = ws;                               // 8,388,608 floats = Bq+Bk exactly
  float* den  = Bv;                               // 32,768 floats at Bv start

  gemm_mfma_ext<<<dim3(13, MTOT / 128), 256, 0, stream>>>(hs, WBq, WAq, WAk, WAv,
                                                          Bq, Aall, 1536);
  gemm_mfma<<<dim3(512 / 128, MTOT / 128), 256, 0, stream>>>(hs, WBk, Bk, 512);
  gemm_mfma<<<dim3(512 / 128, MTOT / 128), 256, 0, stream>>>(hs, WBv, Bv, 512);
  qkv_rope<<<MTOT, 256, 0, stream>>>(Aall, Bq, Bk, Bv, fc, fs, qT, kT, vT);
  zero_acc<<<8192, 256, 0, stream>>>(att, den);   // 8192*256*4 = 8,388,608 floats
  attn_mfma<<<dim3(512), 256, 0, stream>>>(qT, kT, vT, att, den);
  normalize_att<<<MTOT, 256, 0, stream>>>(att, den);
  gemm_mfma<<<dim3(HID / 128, MTOT / 128), 256, 0, stream>>>(att, Wo, out, HID);
}

// Round 17
// 672.626 us; speedup vs baseline: 4.2550x; 1.0632x over previous
//
#include <hip/hip_runtime.h>
#include <cstdint>

#define HID 2048
#define SLEN 2048
#define NH 8
#define HD 256
#define MTOT 4096

constexpr float SCALING = 0.0625f;   // 256^-0.5
constexpr float SOFTCAP = 50.0f;

typedef __attribute__((ext_vector_type(8))) short short8;
typedef __attribute__((ext_vector_type(4))) float f32x4;

__device__ __forceinline__ uint16_t bfhi(float x) {
  return (uint16_t)(__float_as_uint(x) >> 16);           // truncate
}
__device__ __forceinline__ float bf2f(uint16_t h) {
  return __uint_as_float((uint32_t)h << 16);
}
__device__ __forceinline__ void packsplit8(const float4 a, const float4 b,
                                           short8& hi, short8& lo) {
  const float x[8] = {a.x, a.y, a.z, a.w, b.x, b.y, b.z, b.w};
  #pragma unroll
  for (int i = 0; i < 8; ++i) {
    const uint32_t u = __float_as_uint(x[i]);
    const uint16_t h = (uint16_t)(u >> 16);
    const float r = x[i] - bf2f(h);
    hi[i] = (short)h;
    lo[i] = (short)(__float_as_uint(r) >> 16);
  }
}
__device__ __forceinline__ void atomAddF(float* p, float v) {
  __hip_atomic_fetch_add(p, v, __ATOMIC_RELAXED, __HIP_MEMORY_SCOPE_AGENT);
}
__device__ __forceinline__ uint32_t packbf2(float x0, float x1) {
  return (uint32_t)bfhi(x0) | ((uint32_t)bfhi(x1) << 16);
}

// ---------------- split-bf16 MFMA GEMM: C[M,N] = A[M,2048] @ B[2048,N] ----------------
// (validated r9; unchanged)
__global__ __launch_bounds__(256) void gemm_mfma(
    const float* __restrict__ A, const float* __restrict__ B,
    float* __restrict__ C, int N) {
  __shared__ uint16_t Ah[8 * 520], Al[8 * 520], Bh[8 * 520], Bl[8 * 520];
  const int tid = threadIdx.x;
  const int row0 = blockIdx.y * 128;
  const int col0 = blockIdx.x * 128;
  const int lane = tid & 63;
  const int wv = tid >> 6;
  const int wr = wv >> 1, wc = wv & 1;

  f32x4 acc[4][4];
  #pragma unroll
  for (int m = 0; m < 4; ++m)
    #pragma unroll
    for (int n = 0; n < 4; ++n) acc[m][n] = (f32x4){0.f, 0.f, 0.f, 0.f};

  const int ar = tid >> 1;
  const int akb = (tid & 1) * 16;
  const int bkk = tid >> 3;
  const int bcg = tid & 7;

  for (int k0 = 0; k0 < 2048; k0 += 32) {
    float4 av[4], bv[4];
    #pragma unroll
    for (int c = 0; c < 4; ++c)
      av[c] = *(const float4*)&A[(size_t)(row0 + ar) * 2048 + k0 + akb + 4 * c];
    #pragma unroll
    for (int c = 0; c < 4; ++c)
      bv[c] = *(const float4*)&B[(size_t)(k0 + bkk) * N + col0 + bcg * 16 + 4 * c];
    __syncthreads();
    #pragma unroll
    for (int c = 0; c < 4; ++c) {
      const int kk = akb + 4 * c;
      const int idx = (ar >> 4) * 520 + (((ar & 15) | ((kk >> 3) << 4)) << 3) + (kk & 7);
      const float x0 = av[c].x, x1 = av[c].y, x2 = av[c].z, x3 = av[c].w;
      const uint16_t h0 = bfhi(x0), h1 = bfhi(x1), h2 = bfhi(x2), h3 = bfhi(x3);
      const uint16_t g0 = bfhi(x0 - bf2f(h0)), g1 = bfhi(x1 - bf2f(h1));
      const uint16_t g2 = bfhi(x2 - bf2f(h2)), g3 = bfhi(x3 - bf2f(h3));
      *(uint2*)&Ah[idx] = make_uint2((uint32_t)h0 | ((uint32_t)h1 << 16),
                                     (uint32_t)h2 | ((uint32_t)h3 << 16));
      *(uint2*)&Al[idx] = make_uint2((uint32_t)g0 | ((uint32_t)g1 << 16),
                                     (uint32_t)g2 | ((uint32_t)g3 << 16));
    }
    #pragma unroll
    for (int c = 0; c < 4; ++c) {
      const float xs4[4] = {bv[c].x, bv[c].y, bv[c].z, bv[c].w};
      #pragma unroll
      for (int i = 0; i < 4; ++i) {
        const int j = bcg * 16 + 4 * c + i;
        const uint16_t h = bfhi(xs4[i]);
        const uint16_t g = bfhi(xs4[i] - bf2f(h));
        const int idx = (j >> 4) * 520 + (((j & 15) | ((bkk >> 3) << 4)) << 3) + (bkk & 7);
        Bh[idx] = h;
        Bl[idx] = g;
      }
    }
    __syncthreads();
    short8 bhf[4], blf[4];
    #pragma unroll
    for (int nf = 0; nf < 4; ++nf) {
      bhf[nf] = *(const short8*)&Bh[(wc * 4 + nf) * 520 + lane * 8];
      blf[nf] = *(const short8*)&Bl[(wc * 4 + nf) * 520 + lane * 8];
    }
    #pragma unroll
    for (int m = 0; m < 4; ++m) {
      const short8 ahf = *(const short8*)&Ah[(wr * 4 + m) * 520 + lane * 8];
      const short8 alf = *(const short8*)&Al[(wr * 4 + m) * 520 + lane * 8];
      #pragma unroll
      for (int nf = 0; nf < 4; ++nf) {
        acc[m][nf] = __builtin_amdgcn_mfma_f32_16x16x32_bf16(ahf, bhf[nf], acc[m][nf], 0, 0, 0);
        acc[m][nf] = __builtin_amdgcn_mfma_f32_16x16x32_bf16(ahf, blf[nf], acc[m][nf], 0, 0, 0);
        acc[m][nf] = __builtin_amdgcn_mfma_f32_16x16x32_bf16(alf, bhf[nf], acc[m][nf], 0, 0, 0);
      }
    }
  }
  #pragma unroll
  for (int m = 0; m < 4; ++m)
    #pragma unroll
    for (int nf = 0; nf < 4; ++nf) {
      const int row = row0 + wr * 64 + m * 16 + ((lane >> 4) << 2);
      const int col = col0 + wc * 64 + nf * 16 + (lane & 15);
      #pragma unroll
      for (int ri = 0; ri < 4; ++ri)
        C[(size_t)(row + ri) * N + col] = acc[m][nf][ri];
    }
}

// --------- gemm_mfma_ext: B_q projection + fused A-projection tile (validated r11) ----
__global__ __launch_bounds__(256) void gemm_mfma_ext(
    const float* __restrict__ A, const float* __restrict__ B,
    const float* __restrict__ WAq, const float* __restrict__ WAk,
    const float* __restrict__ WAv,
    float* __restrict__ C, float* __restrict__ Aout, int N) {
  __shared__ uint16_t Ah[8 * 520], Al[8 * 520], Bh[8 * 520], Bl[8 * 520];
  const int tid = threadIdx.x;
  const int row0 = blockIdx.y * 128;
  const int col0 = blockIdx.x * 128;
  const bool special = (blockIdx.x == gridDim.x - 1);
  const int lane = tid & 63;
  const int wv = tid >> 6;
  const int wr = wv >> 1, wc = wv & 1;

  f32x4 acc[4][4];
  #pragma unroll
  for (int m = 0; m < 4; ++m)
    #pragma unroll
    for (int n = 0; n < 4; ++n) acc[m][n] = (f32x4){0.f, 0.f, 0.f, 0.f};

  const int ar = tid >> 1;
  const int akb = (tid & 1) * 16;
  const int bkk = tid >> 3;
  const int bcg = tid & 7;

  for (int k0 = 0; k0 < 2048; k0 += 32) {
    float4 av[4], bv[4];
    #pragma unroll
    for (int c = 0; c < 4; ++c)
      av[c] = *(const float4*)&A[(size_t)(row0 + ar) * 2048 + k0 + akb + 4 * c];
    if (!special) {
      #pragma unroll
      for (int c = 0; c < 4; ++c)
        bv[c] = *(const float4*)&B[(size_t)(k0 + bkk) * N + col0 + bcg * 16 + 4 * c];
    } else {
      #pragma unroll
      for (int c = 0; c < 4; ++c) {
        if (bcg < 3)
          bv[c] = *(const float4*)&WAq[(size_t)(k0 + bkk) * 48 + bcg * 16 + 4 * c];
        else if (bcg == 3)
          bv[c] = *(const float4*)&WAk[(size_t)(k0 + bkk) * 16 + 4 * c];
        else if (bcg == 4)
          bv[c] = *(const float4*)&WAv[(size_t)(k0 + bkk) * 16 + 4 * c];
        else
          bv[c] = make_float4(0.f, 0.f, 0.f, 0.f);
      }
    }
    __syncthreads();
    #pragma unroll
    for (int c = 0; c < 4; ++c) {
      const int kk = akb + 4 * c;
      const int idx = (ar >> 4) * 520 + (((ar & 15) | ((kk >> 3) << 4)) << 3) + (kk & 7);
      const float x0 = av[c].x, x1 = av[c].y, x2 = av[c].z, x3 = av[c].w;
      const uint16_t h0 = bfhi(x0), h1 = bfhi(x1), h2 = bfhi(x2), h3 = bfhi(x3);
      const uint16_t g0 = bfhi(x0 - bf2f(h0)), g1 = bfhi(x1 - bf2f(h1));
      const uint16_t g2 = bfhi(x2 - bf2f(h2)), g3 = bfhi(x3 - bf2f(h3));
      *(uint2*)&Ah[idx] = make_uint2((uint32_t)h0 | ((uint32_t)h1 << 16),
                                     (uint32_t)h2 | ((uint32_t)h3 << 16));
      *(uint2*)&Al[idx] = make_uint2((uint32_t)g0 | ((uint32_t)g1 << 16),
                                     (uint32_t)g2 | ((uint32_t)g3 << 16));
    }
    #pragma unroll
    for (int c = 0; c < 4; ++c) {
      const float xs4[4] = {bv[c].x, bv[c].y, bv[c].z, bv[c].w};
      #pragma unroll
      for (int i = 0; i < 4; ++i) {
        const int j = bcg * 16 + 4 * c + i;
        const uint16_t h = bfhi(xs4[i]);
        const uint16_t g = bfhi(xs4[i] - bf2f(h));
        const int idx = (j >> 4) * 520 + (((j & 15) | ((bkk >> 3) << 4)) << 3) + (bkk & 7);
        Bh[idx] = h;
        Bl[idx] = g;
      }
    }
    __syncthreads();
    short8 bhf[4], blf[4];
    #pragma unroll
    for (int nf = 0; nf < 4; ++nf) {
      bhf[nf] = *(const short8*)&Bh[(wc * 4 + nf) * 520 + lane * 8];
      blf[nf] = *(const short8*)&Bl[(wc * 4 + nf) * 520 + lane * 8];
    }
    #pragma unroll
    for (int m = 0; m < 4; ++m) {
      const short8 ahf = *(const short8*)&Ah[(wr * 4 + m) * 520 + lane * 8];
      const short8 alf = *(const short8*)&Al[(wr * 4 + m) * 520 + lane * 8];
      #pragma unroll
      for (int nf = 0; nf < 4; ++nf) {
        acc[m][nf] = __builtin_amdgcn_mfma_f32_16x16x32_bf16(ahf, bhf[nf], acc[m][nf], 0, 0, 0);
        acc[m][nf] = __builtin_amdgcn_mfma_f32_16x16x32_bf16(ahf, blf[nf], acc[m][nf], 0, 0, 0);
        acc[m][nf] = __builtin_amdgcn_mfma_f32_16x16x32_bf16(alf, bhf[nf], acc[m][nf], 0, 0, 0);
      }
    }
  }
  #pragma unroll
  for (int m = 0; m < 4; ++m)
    #pragma unroll
    for (int nf = 0; nf < 4; ++nf) {
      const int row = row0 + wr * 64 + m * 16 + ((lane >> 4) << 2);
      const int col = wc * 64 + nf * 16 + (lane & 15);
      if (!special) {
        #pragma unroll
        for (int ri = 0; ri < 4; ++ri)
          C[(size_t)(row + ri) * N + col0 + col] = acc[m][nf][ri];
      } else if (col < 80) {
        #pragma unroll
        for (int ri = 0; ri < 4; ++ri)
          Aout[(size_t)(row + ri) * 80 + col] = acc[m][nf][ri];
      }
    }
}

// ------------- RoPE + rank contraction v3: emits split-bf16 q/k and bf16 v ------------
// Byte-identical values to what attn v7b's packsplit produced internally (trunc split),
// so attn's LDS images and all downstream math are unchanged.
__global__ __launch_bounds__(256) void qkv_rope(
    const float* __restrict__ Aall,
    const float* __restrict__ Bq, const float* __restrict__ Bk,
    const float* __restrict__ Bv,
    const float* __restrict__ fc, const float* __restrict__ fs,
    uint16_t* __restrict__ qhg, uint16_t* __restrict__ qlg,
    uint16_t* __restrict__ khg, uint16_t* __restrict__ klg,
    uint16_t* __restrict__ vvg) {
  const int m = blockIdx.x;        // 0..4095  (b*SLEN + s)
  const int s = m & (SLEN - 1);
  const int b = m >> 11;
  const int tid = threadIdx.x;
  __shared__ float Al[80];         // A_q[48] | A_k[16] | A_v[16]

  if (tid < 20) *(float4*)&Al[tid * 4] = *(const float4*)&Aall[(size_t)m * 80 + tid * 4];
  __syncthreads();

  const size_t tbase = (size_t)b * NH * SLEN * HD + (size_t)s * HD;
  if (tid < 128) {
    const int j = tid;
    const float cz = fc[s * 128 + j], sz = fs[s * 128 + j];
    float qe[8], qo[8];
    #pragma unroll
    for (int hh = 0; hh < 8; ++hh) { qe[hh] = 0.f; qo[hh] = 0.f; }
    #pragma unroll
    for (int r = 0; r < 6; ++r) {
      const float2 x = *(const float2*)&Bq[(size_t)m * 1536 + r * 256 + 2 * j];
      const float re = x.x * cz - x.y * sz;
      const float ro = x.x * sz + x.y * cz;
      #pragma unroll
      for (int hh = 0; hh < 8; ++hh) {
        const float a = Al[hh * 6 + r];
        qe[hh] = fmaf(a, re, qe[hh]);
        qo[hh] = fmaf(a, ro, qo[hh]);
      }
    }
    const float qs = SCALING / 6.f;
    #pragma unroll
    for (int hh = 0; hh < 8; ++hh) {
      const float x0 = qe[hh] * qs, x1 = qo[hh] * qs;
      const uint16_t h0 = bfhi(x0), h1 = bfhi(x1);
      const size_t eb = (tbase + (size_t)hh * SLEN * HD + 2 * j) >> 1;
      ((uint32_t*)qhg)[eb] = (uint32_t)h0 | ((uint32_t)h1 << 16);
      ((uint32_t*)qlg)[eb] = packbf2(x0 - bf2f(h0), x1 - bf2f(h1));
    }
  } else {
    const int j = tid - 128;
    const float cz = fc[s * 128 + j], sz = fs[s * 128 + j];
    float ke_[8], ko_[8], ve_[8], vo_[8];
    #pragma unroll
    for (int hh = 0; hh < 8; ++hh) { ke_[hh]=0.f; ko_[hh]=0.f; ve_[hh]=0.f; vo_[hh]=0.f; }
    #pragma unroll
    for (int r = 0; r < 2; ++r) {
      const float2 xk = *(const float2*)&Bk[(size_t)m * 512 + r * 256 + 2 * j];
      const float2 xv = *(const float2*)&Bv[(size_t)m * 512 + r * 256 + 2 * j];
      const float re = xk.x * cz - xk.y * sz;
      const float ro = xk.x * sz + xk.y * cz;
      #pragma unroll
      for (int hh = 0; hh < 8; ++hh) {
        const float ak = Al[48 + hh * 2 + r];
        const float av = Al[64 + hh * 2 + r];
        ke_[hh] = fmaf(ak, re, ke_[hh]);
        ko_[hh] = fmaf(ak, ro, ko_[hh]);
        ve_[hh] = fmaf(av, xv.x, ve_[hh]);
        vo_[hh] = fmaf(av, xv.y, vo_[hh]);
      }
    }
    #pragma unroll
    for (int hh = 0; hh < 8; ++hh) {
      const float x0 = ke_[hh] * 0.5f, x1 = ko_[hh] * 0.5f;
      const uint16_t h0 = bfhi(x0), h1 = bfhi(x1);
      const size_t eb = (tbase + (size_t)hh * SLEN * HD + 2 * j) >> 1;
      ((uint32_t*)khg)[eb] = (uint32_t)h0 | ((uint32_t)h1 << 16);
      ((uint32_t*)klg)[eb] = packbf2(x0 - bf2f(h0), x1 - bf2f(h1));
      ((uint32_t*)vvg)[eb] = packbf2(ve_[hh] * 0.5f, vo_[hh] * 0.5f);
    }
  }
}

// ------------- zero att + den (harness poisons ws; atomics need zeros) ----------------
__global__ __launch_bounds__(256) void zero_acc(float* __restrict__ att,
                                                float* __restrict__ den) {
  const int idx = blockIdx.x * 256 + threadIdx.x;   // float4 index
  const float4 z = {0.f, 0.f, 0.f, 0.f};
  *(float4*)&att[(size_t)idx * 4] = z;              // grid covers 8,388,608 floats
  if (idx < 8192) *(float4*)&den[(size_t)idx * 4] = z;   // 32768 floats
}

// ------------- normalize: att /= den (den completed by attn atomics) ------------------
__global__ __launch_bounds__(256) void normalize_att(
    float* __restrict__ att, const float* __restrict__ den) {
  const int m = blockIdx.x;              // row 0..4095 = b*2048+s
  const int t = threadIdx.x;
  const int h = t >> 5;                  // col chunk [t*8, t*8+8) -> head
  const float inv = 1.f / den[((size_t)(m >> 11) * 8 + h) * SLEN + (m & 2047)];
  float* p = &att[(size_t)m * 2048 + t * 8];
  float4 a = *(float4*)&p[0], b = *(float4*)&p[4];
  a.x *= inv; a.y *= inv; a.z *= inv; a.w *= inv;
  b.x *= inv; b.y *= inv; b.z *= inv; b.w *= inv;
  *(float4*)&p[0] = a; *(float4*)&p[4] = b;
}

// ------------- causal softcapped attention v8: pre-converted bf16 inputs + setprio ----
// vs v7b: (1) q/k arrive as split-bf16, v as bf16 (rope emits them) -> staging is pure
// 16B loads + the SAME LDS writes; the ~160 VALU/iter packsplit chain is gone.
// (2) T5 setprio(1) around the QK and PV MFMA clusters (phase-split schedule: waves at
// different phases across the 2 blocks/CU -> scheduler can prefer MFMA-phase waves).
// Balanced fold+halve decomposition + 2-addend atomic merge unchanged (validated r15).
#define KLD 264
#define VLD 40
#define PLD 40
__global__ __launch_bounds__(256, 2) void attn_mfma(
    const uint16_t* __restrict__ qhg, const uint16_t* __restrict__ qlg,
    const uint16_t* __restrict__ khg, const uint16_t* __restrict__ klg,
    const uint16_t* __restrict__ vvg, float* __restrict__ att,
    float* __restrict__ den_g) {
  __shared__ uint16_t Khs[32 * KLD];
  __shared__ uint16_t Kls[32 * KLD];
  __shared__ uint16_t Vts[256 * VLD];
  __shared__ uint16_t Ps[4 * 16 * PLD];
  const int tid = threadIdx.x;
  const int lane = tid & 63;
  const int w = tid >> 6;
  const int l15 = lane & 15;
  const int l4 = lane >> 4;
  const int bid = blockIdx.x;
  const int bh = bid & 15;             // low bits -> per-bh K/V pins to one XCD L2
  const int p = (bid >> 4) & 15;
  const int hf = bid >> 8;             // k-parity half
  const int b = bh >> 3, h = bh & 7;
  const size_t base = (size_t)bh * SLEN * HD;
  const uint16_t* khb = &khg[base];
  const uint16_t* klb = &klg[base];
  const uint16_t* vvb = &vvg[base];
  const int sr = tid & 31;
  const int sc = (tid >> 5) * 32;

  #pragma unroll
  for (int sub = 0; sub < 2; ++sub) {
    const int qt = (sub == 0) ? (31 - p) : p;
    const int q0 = qt * 64;
    // Q fragments: direct 16B loads of pre-split bf16 (rows q0+16w+l15, d=32f+8*l4+e)
    short8 qh[8], ql[8];
    {
      const uint16_t* qhp = &qhg[base + (size_t)(q0 + w * 16 + l15) * HD + 8 * l4];
      const uint16_t* qlp = &qlg[base + (size_t)(q0 + w * 16 + l15) * HD + 8 * l4];
      #pragma unroll
      for (int f = 0; f < 8; ++f) {
        qh[f] = *(const short8*)&qhp[32 * f];
        ql[f] = *(const short8*)&qlp[32 * f];
      }
    }
    f32x4 acc[16];
    #pragma unroll
    for (int df = 0; df < 16; ++df) acc[df] = (f32x4){0.f, 0.f, 0.f, 0.f};
    float den[4] = {0.f, 0.f, 0.f, 0.f};

    const int myrow = q0 + w * 16 + l4 * 4;
    const int rowmax = q0 + w * 16 + 15;
    const int nkt = 2 * qt + 2;

    short8 kh8[4], kl8[4], vv8[4];
    {
      const uint16_t* kp = &khb[(size_t)(hf * 32 + sr) * HD + sc];
      const uint16_t* lp = &klb[(size_t)(hf * 32 + sr) * HD + sc];
      const uint16_t* vp = &vvb[(size_t)(hf * 32 + sr) * HD + sc];
      #pragma unroll
      for (int j = 0; j < 4; ++j) {
        kh8[j] = *(const short8*)&kp[8 * j];
        kl8[j] = *(const short8*)&lp[8 * j];
        vv8[j] = *(const short8*)&vp[8 * j];
      }
    }

    for (int kt = hf; kt < nkt; kt += 2) {
      const int k0 = kt * 32;
      // stage current tile regs -> LDS (pure copies; no conversion)
      #pragma unroll
      for (int j = 0; j < 4; ++j) {
        *(short8*)&Khs[sr * KLD + sc + 8 * j] = kh8[j];
        *(short8*)&Kls[sr * KLD + sc + 8 * j] = kl8[j];
      }
      #pragma unroll
      for (int j = 0; j < 4; ++j) {
        const short8 s8 = vv8[j];
        #pragma unroll
        for (int i = 0; i < 8; ++i)
          Vts[(sc + 8 * j + i) * VLD + sr] = (uint16_t)s8[i];
      }
      // issue NEXT tile's loads; raw barrier below does NOT drain vmcnt
      if (kt + 2 < nkt) {
        const uint16_t* kp = &khb[(size_t)(k0 + 64 + sr) * HD + sc];
        const uint16_t* lp = &klb[(size_t)(k0 + 64 + sr) * HD + sc];
        const uint16_t* vp = &vvb[(size_t)(k0 + 64 + sr) * HD + sc];
        #pragma unroll
        for (int j = 0; j < 4; ++j) {
          kh8[j] = *(const short8*)&kp[8 * j];
          kl8[j] = *(const short8*)&lp[8 * j];
          vv8[j] = *(const short8*)&vp[8 * j];
        }
      }
      asm volatile("s_waitcnt lgkmcnt(0)" ::: "memory");
      __builtin_amdgcn_sched_barrier(0);
      __builtin_amdgcn_s_barrier();
      __builtin_amdgcn_sched_barrier(0);
      if (k0 <= rowmax) {
        // QK^T: 2 k-frags x 8 d-chunks x 3 split terms, 3 independent chains
        f32x4 sfr[2];
        __builtin_amdgcn_s_setprio(1);
        #pragma unroll
        for (int kf = 0; kf < 2; ++kf) {
          f32x4 c0 = (f32x4){0.f, 0.f, 0.f, 0.f};
          f32x4 c1 = c0, c2 = c0;
          #pragma unroll
          for (int dc = 0; dc < 8; ++dc) {
            const int off = (16 * kf + l15) * KLD + 32 * dc + 8 * l4;
            const short8 kh = *(const short8*)&Khs[off];
            const short8 kl = *(const short8*)&Kls[off];
            c0 = __builtin_amdgcn_mfma_f32_16x16x32_bf16(qh[dc], kh, c0, 0, 0, 0);
            c1 = __builtin_amdgcn_mfma_f32_16x16x32_bf16(qh[dc], kl, c1, 0, 0, 0);
            c2 = __builtin_amdgcn_mfma_f32_16x16x32_bf16(ql[dc], kh, c2, 0, 0, 0);
          }
          sfr[kf] = (c0 + c1) + c2;
        }
        __builtin_amdgcn_s_setprio(0);
        // softcap + exp (fixed-max) + causal mask; P -> wave-private LDS (bf16)
        uint16_t* pw = &Ps[w * 16 * PLD];
        #pragma unroll
        for (int kf = 0; kf < 2; ++kf) {
          #pragma unroll
          for (int ri = 0; ri < 4; ++ri) {
            const float pd = sfr[kf][ri];
            const float t1 = exp2f(pd * 0.0577078016f);
            float e = exp2f(-144.26950409f * __builtin_amdgcn_rcpf(t1 + 1.f));
            if (k0 + 16 * kf + l15 > myrow + ri) e = 0.f;
            den[ri] += e;
            pw[(l4 * 4 + ri) * PLD + 16 * kf + l15] = bfhi(e);
          }
        }
        // PV: A = P[16q][32j], B = Vt frags [32j][16d], 16 independent d-frags
        const short8 pa = *(const short8*)&pw[l15 * PLD + 8 * l4];
        __builtin_amdgcn_s_setprio(1);
        #pragma unroll
        for (int df = 0; df < 16; ++df) {
          const short8 vb = *(const short8*)&Vts[(16 * df + l15) * VLD + 8 * l4];
          acc[df] = __builtin_amdgcn_mfma_f32_16x16x32_bf16(pa, vb, acc[df], 0, 0, 0);
        }
        __builtin_amdgcn_s_setprio(0);
      }
      __builtin_amdgcn_sched_barrier(0);
      __builtin_amdgcn_s_barrier();
      __builtin_amdgcn_sched_barrier(0);
    }
    // partial den reduce (16 lanes) + atomic merge (2 addends/address -> deterministic)
    #pragma unroll
    for (int ri = 0; ri < 4; ++ri) {
      den[ri] += __shfl_xor(den[ri], 1);
      den[ri] += __shfl_xor(den[ri], 2);
      den[ri] += __shfl_xor(den[ri], 4);
      den[ri] += __shfl_xor(den[ri], 8);
    }
    if (l15 == 0) {
      #pragma unroll
      for (int ri = 0; ri < 4; ++ri)
        atomAddF(&den_g[(size_t)bh * SLEN + myrow + ri], den[ri]);
    }
    float* op = &att[((size_t)(b * SLEN + myrow)) * (NH * HD) + h * HD + l15];
    #pragma unroll
    for (int ri = 0; ri < 4; ++ri)
      #pragma unroll
      for (int df = 0; df < 16; ++df)
        atomAddF(&op[(size_t)ri * (NH * HD) + 16 * df], acc[df][ri]);
  }
}

extern "C" void kernel_launch(void* const* d_in, const int* in_sizes, int n_in,
                              void* d_out, int out_size, void* d_ws, size_t ws_size,
                              hipStream_t stream) {
  const float* hs  = (const float*)d_in[0];
  const float* fc  = (const float*)d_in[1];
  const float* fs  = (const float*)d_in[2];
  // d_in[3] = mask: pure causal, handled analytically.
  const float* WAq = (const float*)d_in[4];
  const float* WAk = (const float*)d_in[5];
  const float* WAv = (const float*)d_in[6];
  const float* WBq = (const float*)d_in[7];
  const float* WBk = (const float*)d_in[8];
  const float* WBv = (const float*)d_in[9];
  const float* Wo  = (const float*)d_in[10];
  float* out = (float*)d_out;

  // Workspace (floats). att [0,8.39M) = Bq+Bk exactly (dead after rope).
  // den at Bv start (dead after rope). bf16 q/k/v buffers live in the old qT/kT/vT
  // region [10.49M, 31.46M): written by rope, read by attn, no overlap with att/den.
  // Total footprint ~127 MB (was 144, proven fits).
  float* ws   = (float*)d_ws;
  float* Bq   = ws;                               // 6,291,456 floats
  float* Bk   = Bq + (size_t)MTOT * 1536;         // 2,097,152
  float* Bv   = Bk + (size_t)MTOT * 512;          // 2,097,152
  uint16_t* qh = (uint16_t*)(Bv + (size_t)MTOT * 512);   // 8,388,608 shorts each
  uint16_t* ql = qh + (size_t)8388608;
  uint16_t* kh = ql + (size_t)8388608;
  uint16_t* kl = kh + (size_t)8388608;
  uint16_t* vv = kl + (size_t)8388608;            // ends at float-offset 31,457,280
  float* Aall = ws + (size_t)31457280;            // [4096, 80] = 327,680 floats
  float* att  = ws;                               // 8,388,608 floats (= Bq+Bk)
  float* den  = Bv;                               // 32,768 floats at Bv start

  gemm_mfma_ext<<<dim3(13, MTOT / 128), 256, 0, stream>>>(hs, WBq, WAq, WAk, WAv,
                                                          Bq, Aall, 1536);
  gemm_mfma<<<dim3(512 / 128, MTOT / 128), 256, 0, stream>>>(hs, WBk, Bk, 512);
  gemm_mfma<<<dim3(512 / 128, MTOT / 128), 256, 0, stream>>>(hs, WBv, Bv, 512);
  qkv_rope<<<MTOT, 256, 0, stream>>>(Aall, Bq, Bk, Bv, fc, fs, qh, ql, kh, kl, vv);
  zero_acc<<<8192, 256, 0, stream>>>(att, den);
  attn_mfma<<<dim3(512), 256, 0, stream>>>(qh, ql, kh, kl, vv, att, den);
  normalize_att<<<MTOT, 256, 0, stream>>>(att, den);
  gemm_mfma<<<dim3(HID / 128, MTOT / 128), 256, 0, stream>>>(att, Wo, out, HID);
}

// Round 20
// 472.258 us; speedup vs baseline: 6.0603x; 1.4243x over previous
//
#include <hip/hip_runtime.h>
#include <cstdint>

#define HID 2048
#define SLEN 2048
#define NH 8
#define HD 256
#define MTOT 4096

constexpr float SCALING = 0.0625f;   // 256^-0.5
constexpr float SOFTCAP = 50.0f;

typedef __attribute__((ext_vector_type(8))) short short8;
typedef __attribute__((ext_vector_type(4))) float f32x4;

__device__ __forceinline__ uint16_t bfhi(float x) {
  return (uint16_t)(__float_as_uint(x) >> 16);           // truncate
}
__device__ __forceinline__ float bf2f(uint16_t h) {
  return __uint_as_float((uint32_t)h << 16);
}
__device__ __forceinline__ void atomAddF(float* p, float v) {
  __hip_atomic_fetch_add(p, v, __ATOMIC_RELAXED, __HIP_MEMORY_SCOPE_AGENT);
}
__device__ __forceinline__ uint32_t packbf2(float x0, float x1) {
  return (uint32_t)bfhi(x0) | ((uint32_t)bfhi(x1) << 16);
}

// ---------- gemm_proj: ALL projections in one dispatch (672 blocks = 2.6 rounds) ------
// Col-tiles: 0..11 -> hs@WBq -> Bq[4096,1536]; 12 -> fused A-proj -> Aall[4096,80]
// (validated r11 ext logic); 13..16 -> hs@WBk -> Bk[4096,512]; 17..20 -> hs@WBv -> Bv.
// Inner loop byte-identical to the r9-validated split-bf16 MFMA GEMM.
__global__ __launch_bounds__(256) void gemm_proj(
    const float* __restrict__ A,
    const float* __restrict__ WBq, const float* __restrict__ WBk,
    const float* __restrict__ WBv,
    const float* __restrict__ WAq, const float* __restrict__ WAk,
    const float* __restrict__ WAv,
    float* __restrict__ Cq, float* __restrict__ Ck, float* __restrict__ Cv,
    float* __restrict__ Aout) {
  __shared__ uint16_t Ah[8 * 520], Al[8 * 520], Bh[8 * 520], Bl[8 * 520];
  const int tid = threadIdx.x;
  const int ct = blockIdx.x;           // col tile 0..20
  const int row0 = blockIdx.y * 128;
  const bool special = (ct == 12);
  const float* Bmat = WBq; float* Cmat = Cq; int Nseg = 1536; int col0 = ct * 128;
  if (ct >= 17)      { Bmat = WBv; Cmat = Cv; Nseg = 512; col0 = (ct - 17) * 128; }
  else if (ct >= 13) { Bmat = WBk; Cmat = Ck; Nseg = 512; col0 = (ct - 13) * 128; }
  const int lane = tid & 63;
  const int wv = tid >> 6;
  const int wr = wv >> 1, wc = wv & 1;

  f32x4 acc[4][4];
  #pragma unroll
  for (int m = 0; m < 4; ++m)
    #pragma unroll
    for (int n = 0; n < 4; ++n) acc[m][n] = (f32x4){0.f, 0.f, 0.f, 0.f};

  const int ar = tid >> 1;
  const int akb = (tid & 1) * 16;
  const int bkk = tid >> 3;
  const int bcg = tid & 7;

  for (int k0 = 0; k0 < 2048; k0 += 32) {
    float4 av[4], bv[4];
    #pragma unroll
    for (int c = 0; c < 4; ++c)
      av[c] = *(const float4*)&A[(size_t)(row0 + ar) * 2048 + k0 + akb + 4 * c];
    if (!special) {
      #pragma unroll
      for (int c = 0; c < 4; ++c)
        bv[c] = *(const float4*)&Bmat[(size_t)(k0 + bkk) * Nseg + col0 + bcg * 16 + 4 * c];
    } else {
      #pragma unroll
      for (int c = 0; c < 4; ++c) {
        if (bcg < 3)
          bv[c] = *(const float4*)&WAq[(size_t)(k0 + bkk) * 48 + bcg * 16 + 4 * c];
        else if (bcg == 3)
          bv[c] = *(const float4*)&WAk[(size_t)(k0 + bkk) * 16 + 4 * c];
        else if (bcg == 4)
          bv[c] = *(const float4*)&WAv[(size_t)(k0 + bkk) * 16 + 4 * c];
        else
          bv[c] = make_float4(0.f, 0.f, 0.f, 0.f);
      }
    }
    __syncthreads();
    #pragma unroll
    for (int c = 0; c < 4; ++c) {
      const int kk = akb + 4 * c;
      const int idx = (ar >> 4) * 520 + (((ar & 15) | ((kk >> 3) << 4)) << 3) + (kk & 7);
      const float x0 = av[c].x, x1 = av[c].y, x2 = av[c].z, x3 = av[c].w;
      const uint16_t h0 = bfhi(x0), h1 = bfhi(x1), h2 = bfhi(x2), h3 = bfhi(x3);
      const uint16_t g0 = bfhi(x0 - bf2f(h0)), g1 = bfhi(x1 - bf2f(h1));
      const uint16_t g2 = bfhi(x2 - bf2f(h2)), g3 = bfhi(x3 - bf2f(h3));
      *(uint2*)&Ah[idx] = make_uint2((uint32_t)h0 | ((uint32_t)h1 << 16),
                                     (uint32_t)h2 | ((uint32_t)h3 << 16));
      *(uint2*)&Al[idx] = make_uint2((uint32_t)g0 | ((uint32_t)g1 << 16),
                                     (uint32_t)g2 | ((uint32_t)g3 << 16));
    }
    #pragma unroll
    for (int c = 0; c < 4; ++c) {
      const float xs4[4] = {bv[c].x, bv[c].y, bv[c].z, bv[c].w};
      #pragma unroll
      for (int i = 0; i < 4; ++i) {
        const int j = bcg * 16 + 4 * c + i;
        const uint16_t h = bfhi(xs4[i]);
        const uint16_t g = bfhi(xs4[i] - bf2f(h));
        const int idx = (j >> 4) * 520 + (((j & 15) | ((bkk >> 3) << 4)) << 3) + (bkk & 7);
        Bh[idx] = h;
        Bl[idx] = g;
      }
    }
    __syncthreads();
    short8 bhf[4], blf[4];
    #pragma unroll
    for (int nf = 0; nf < 4; ++nf) {
      bhf[nf] = *(const short8*)&Bh[(wc * 4 + nf) * 520 + lane * 8];
      blf[nf] = *(const short8*)&Bl[(wc * 4 + nf) * 520 + lane * 8];
    }
    #pragma unroll
    for (int m = 0; m < 4; ++m) {
      const short8 ahf = *(const short8*)&Ah[(wr * 4 + m) * 520 + lane * 8];
      const short8 alf = *(const short8*)&Al[(wr * 4 + m) * 520 + lane * 8];
      #pragma unroll
      for (int nf = 0; nf < 4; ++nf) {
        acc[m][nf] = __builtin_amdgcn_mfma_f32_16x16x32_bf16(ahf, bhf[nf], acc[m][nf], 0, 0, 0);
        acc[m][nf] = __builtin_amdgcn_mfma_f32_16x16x32_bf16(ahf, blf[nf], acc[m][nf], 0, 0, 0);
        acc[m][nf] = __builtin_amdgcn_mfma_f32_16x16x32_bf16(alf, bhf[nf], acc[m][nf], 0, 0, 0);
      }
    }
  }
  #pragma unroll
  for (int m = 0; m < 4; ++m)
    #pragma unroll
    for (int nf = 0; nf < 4; ++nf) {
      const int row = row0 + wr * 64 + m * 16 + ((lane >> 4) << 2);
      const int col = wc * 64 + nf * 16 + (lane & 15);
      if (!special) {
        #pragma unroll
        for (int ri = 0; ri < 4; ++ri)
          Cmat[(size_t)(row + ri) * Nseg + col0 + col] = acc[m][nf][ri];
      } else if (col < 80) {
        #pragma unroll
        for (int ri = 0; ri < 4; ++ri)
          Aout[(size_t)(row + ri) * 80 + col] = acc[m][nf][ri];
      }
    }
}

// ---------- gemm_norm: out = (att / den) @ Wo — normalization fused into A-staging ----
// The 16-float A-window [k0+akb, k0+akb+16) never crosses a 256-col head boundary,
// so one den scalar per stage-read. Replaces the normalize_att kernel.
__global__ __launch_bounds__(256) void gemm_norm(
    const float* __restrict__ A, const float* __restrict__ B,
    const float* __restrict__ den, float* __restrict__ C) {
  __shared__ uint16_t Ah[8 * 520], Al[8 * 520], Bh[8 * 520], Bl[8 * 520];
  const int tid = threadIdx.x;
  const int row0 = blockIdx.y * 128;
  const int col0 = blockIdx.x * 128;
  const int lane = tid & 63;
  const int wv = tid >> 6;
  const int wr = wv >> 1, wc = wv & 1;

  f32x4 acc[4][4];
  #pragma unroll
  for (int m = 0; m < 4; ++m)
    #pragma unroll
    for (int n = 0; n < 4; ++n) acc[m][n] = (f32x4){0.f, 0.f, 0.f, 0.f};

  const int ar = tid >> 1;
  const int akb = (tid & 1) * 16;
  const int bkk = tid >> 3;
  const int bcg = tid & 7;
  const int arow = row0 + ar;                       // att row: b*2048+s
  const size_t denrow = (size_t)(arow >> 11) * 8 * SLEN + (arow & 2047);

  for (int k0 = 0; k0 < 2048; k0 += 32) {
    float4 av[4], bv[4];
    const float inv = 1.f / den[denrow + (size_t)((k0 + akb) >> 8) * SLEN];
    #pragma unroll
    for (int c = 0; c < 4; ++c) {
      float4 t = *(const float4*)&A[(size_t)arow * 2048 + k0 + akb + 4 * c];
      t.x *= inv; t.y *= inv; t.z *= inv; t.w *= inv;
      av[c] = t;
    }
    #pragma unroll
    for (int c = 0; c < 4; ++c)
      bv[c] = *(const float4*)&B[(size_t)(k0 + bkk) * HID + col0 + bcg * 16 + 4 * c];
    __syncthreads();
    #pragma unroll
    for (int c = 0; c < 4; ++c) {
      const int kk = akb + 4 * c;
      const int idx = (ar >> 4) * 520 + (((ar & 15) | ((kk >> 3) << 4)) << 3) + (kk & 7);
      const float x0 = av[c].x, x1 = av[c].y, x2 = av[c].z, x3 = av[c].w;
      const uint16_t h0 = bfhi(x0), h1 = bfhi(x1), h2 = bfhi(x2), h3 = bfhi(x3);
      const uint16_t g0 = bfhi(x0 - bf2f(h0)), g1 = bfhi(x1 - bf2f(h1));
      const uint16_t g2 = bfhi(x2 - bf2f(h2)), g3 = bfhi(x3 - bf2f(h3));
      *(uint2*)&Ah[idx] = make_uint2((uint32_t)h0 | ((uint32_t)h1 << 16),
                                     (uint32_t)h2 | ((uint32_t)h3 << 16));
      *(uint2*)&Al[idx] = make_uint2((uint32_t)g0 | ((uint32_t)g1 << 16),
                                     (uint32_t)g2 | ((uint32_t)g3 << 16));
    }
    #pragma unroll
    for (int c = 0; c < 4; ++c) {
      const float xs4[4] = {bv[c].x, bv[c].y, bv[c].z, bv[c].w};
      #pragma unroll
      for (int i = 0; i < 4; ++i) {
        const int j = bcg * 16 + 4 * c + i;
        const uint16_t h = bfhi(xs4[i]);
        const uint16_t g = bfhi(xs4[i] - bf2f(h));
        const int idx = (j >> 4) * 520 + (((j & 15) | ((bkk >> 3) << 4)) << 3) + (bkk & 7);
        Bh[idx] = h;
        Bl[idx] = g;
      }
    }
    __syncthreads();
    short8 bhf[4], blf[4];
    #pragma unroll
    for (int nf = 0; nf < 4; ++nf) {
      bhf[nf] = *(const short8*)&Bh[(wc * 4 + nf) * 520 + lane * 8];
      blf[nf] = *(const short8*)&Bl[(wc * 4 + nf) * 520 + lane * 8];
    }
    #pragma unroll
    for (int m = 0; m < 4; ++m) {
      const short8 ahf = *(const short8*)&Ah[(wr * 4 + m) * 520 + lane * 8];
      const short8 alf = *(const short8*)&Al[(wr * 4 + m) * 520 + lane * 8];
      #pragma unroll
      for (int nf = 0; nf < 4; ++nf) {
        acc[m][nf] = __builtin_amdgcn_mfma_f32_16x16x32_bf16(ahf, bhf[nf], acc[m][nf], 0, 0, 0);
        acc[m][nf] = __builtin_amdgcn_mfma_f32_16x16x32_bf16(ahf, blf[nf], acc[m][nf], 0, 0, 0);
        acc[m][nf] = __builtin_amdgcn_mfma_f32_16x16x32_bf16(alf, bhf[nf], acc[m][nf], 0, 0, 0);
      }
    }
  }
  #pragma unroll
  for (int m = 0; m < 4; ++m)
    #pragma unroll
    for (int nf = 0; nf < 4; ++nf) {
      const int row = row0 + wr * 64 + m * 16 + ((lane >> 4) << 2);
      const int col = col0 + wc * 64 + nf * 16 + (lane & 15);
      #pragma unroll
      for (int ri = 0; ri < 4; ++ri)
        C[(size_t)(row + ri) * HID + col] = acc[m][nf][ri];
    }
}

// ------------- RoPE + rank contraction v3 (validated r17, unchanged) ------------------
__global__ __launch_bounds__(256) void qkv_rope(
    const float* __restrict__ Aall,
    const float* __restrict__ Bq, const float* __restrict__ Bk,
    const float* __restrict__ Bv,
    const float* __restrict__ fc, const float* __restrict__ fs,
    uint16_t* __restrict__ qhg, uint16_t* __restrict__ qlg,
    uint16_t* __restrict__ khg, uint16_t* __restrict__ klg,
    uint16_t* __restrict__ vvg) {
  const int m = blockIdx.x;        // 0..4095  (b*SLEN + s)
  const int s = m & (SLEN - 1);
  const int b = m >> 11;
  const int tid = threadIdx.x;
  __shared__ float Al[80];         // A_q[48] | A_k[16] | A_v[16]

  if (tid < 20) *(float4*)&Al[tid * 4] = *(const float4*)&Aall[(size_t)m * 80 + tid * 4];
  __syncthreads();

  const size_t tbase = (size_t)b * NH * SLEN * HD + (size_t)s * HD;
  if (tid < 128) {
    const int j = tid;
    const float cz = fc[s * 128 + j], sz = fs[s * 128 + j];
    float qe[8], qo[8];
    #pragma unroll
    for (int hh = 0; hh < 8; ++hh) { qe[hh] = 0.f; qo[hh] = 0.f; }
    #pragma unroll
    for (int r = 0; r < 6; ++r) {
      const float2 x = *(const float2*)&Bq[(size_t)m * 1536 + r * 256 + 2 * j];
      const float re = x.x * cz - x.y * sz;
      const float ro = x.x * sz + x.y * cz;
      #pragma unroll
      for (int hh = 0; hh < 8; ++hh) {
        const float a = Al[hh * 6 + r];
        qe[hh] = fmaf(a, re, qe[hh]);
        qo[hh] = fmaf(a, ro, qo[hh]);
      }
    }
    const float qs = SCALING / 6.f;
    #pragma unroll
    for (int hh = 0; hh < 8; ++hh) {
      const float x0 = qe[hh] * qs, x1 = qo[hh] * qs;
      const uint16_t h0 = bfhi(x0), h1 = bfhi(x1);
      const size_t eb = (tbase + (size_t)hh * SLEN * HD + 2 * j) >> 1;
      ((uint32_t*)qhg)[eb] = (uint32_t)h0 | ((uint32_t)h1 << 16);
      ((uint32_t*)qlg)[eb] = packbf2(x0 - bf2f(h0), x1 - bf2f(h1));
    }
  } else {
    const int j = tid - 128;
    const float cz = fc[s * 128 + j], sz = fs[s * 128 + j];
    float ke_[8], ko_[8], ve_[8], vo_[8];
    #pragma unroll
    for (int hh = 0; hh < 8; ++hh) { ke_[hh]=0.f; ko_[hh]=0.f; ve_[hh]=0.f; vo_[hh]=0.f; }
    #pragma unroll
    for (int r = 0; r < 2; ++r) {
      const float2 xk = *(const float2*)&Bk[(size_t)m * 512 + r * 256 + 2 * j];
      const float2 xv = *(const float2*)&Bv[(size_t)m * 512 + r * 256 + 2 * j];
      const float re = xk.x * cz - xk.y * sz;
      const float ro = xk.x * sz + xk.y * cz;
      #pragma unroll
      for (int hh = 0; hh < 8; ++hh) {
        const float ak = Al[48 + hh * 2 + r];
        const float av = Al[64 + hh * 2 + r];
        ke_[hh] = fmaf(ak, re, ke_[hh]);
        ko_[hh] = fmaf(ak, ro, ko_[hh]);
        ve_[hh] = fmaf(av, xv.x, ve_[hh]);
        vo_[hh] = fmaf(av, xv.y, vo_[hh]);
      }
    }
    #pragma unroll
    for (int hh = 0; hh < 8; ++hh) {
      const float x0 = ke_[hh] * 0.5f, x1 = ko_[hh] * 0.5f;
      const uint16_t h0 = bfhi(x0), h1 = bfhi(x1);
      const size_t eb = (tbase + (size_t)hh * SLEN * HD + 2 * j) >> 1;
      ((uint32_t*)khg)[eb] = (uint32_t)h0 | ((uint32_t)h1 << 16);
      ((uint32_t*)klg)[eb] = packbf2(x0 - bf2f(h0), x1 - bf2f(h1));
      ((uint32_t*)vvg)[eb] = packbf2(ve_[hh] * 0.5f, vo_[hh] * 0.5f);
    }
  }
}

// ------------- zero att + den (harness poisons ws; atomics need zeros) ----------------
__global__ __launch_bounds__(256) void zero_acc(float* __restrict__ att,
                                                float* __restrict__ den) {
  const int idx = blockIdx.x * 256 + threadIdx.x;   // float4 index
  const float4 z = {0.f, 0.f, 0.f, 0.f};
  *(float4*)&att[(size_t)idx * 4] = z;              // grid covers 8,388,608 floats
  if (idx < 8192) *(float4*)&den[(size_t)idx * 4] = z;   // 32768 floats
}

// ------------- causal softcapped attention v8 (validated r17, unchanged) --------------
#define KLD 264
#define VLD 40
#define PLD 40
__global__ __launch_bounds__(256, 2) void attn_mfma(
    const uint16_t* __restrict__ qhg, const uint16_t* __restrict__ qlg,
    const uint16_t* __restrict__ khg, const uint16_t* __restrict__ klg,
    const uint16_t* __restrict__ vvg, float* __restrict__ att,
    float* __restrict__ den_g) {
  __shared__ uint16_t Khs[32 * KLD];
  __shared__ uint16_t Kls[32 * KLD];
  __shared__ uint16_t Vts[256 * VLD];
  __shared__ uint16_t Ps[4 * 16 * PLD];
  const int tid = threadIdx.x;
  const int lane = tid & 63;
  const int w = tid >> 6;
  const int l15 = lane & 15;
  const int l4 = lane >> 4;
  const int bid = blockIdx.x;
  const int bh = bid & 15;             // low bits -> per-bh K/V pins to one XCD L2
  const int p = (bid >> 4) & 15;
  const int hf = bid >> 8;             // k-parity half
  const int b = bh >> 3, h = bh & 7;
  const size_t base = (size_t)bh * SLEN * HD;
  const uint16_t* khb = &khg[base];
  const uint16_t* klb = &klg[base];
  const uint16_t* vvb = &vvg[base];
  const int sr = tid & 31;
  const int sc = (tid >> 5) * 32;

  #pragma unroll
  for (int sub = 0; sub < 2; ++sub) {
    const int qt = (sub == 0) ? (31 - p) : p;
    const int q0 = qt * 64;
    short8 qh[8], ql[8];
    {
      const uint16_t* qhp = &qhg[base + (size_t)(q0 + w * 16 + l15) * HD + 8 * l4];
      const uint16_t* qlp = &qlg[base + (size_t)(q0 + w * 16 + l15) * HD + 8 * l4];
      #pragma unroll
      for (int f = 0; f < 8; ++f) {
        qh[f] = *(const short8*)&qhp[32 * f];
        ql[f] = *(const short8*)&qlp[32 * f];
      }
    }
    f32x4 acc[16];
    #pragma unroll
    for (int df = 0; df < 16; ++df) acc[df] = (f32x4){0.f, 0.f, 0.f, 0.f};
    float den[4] = {0.f, 0.f, 0.f, 0.f};

    const int myrow = q0 + w * 16 + l4 * 4;
    const int rowmax = q0 + w * 16 + 15;
    const int nkt = 2 * qt + 2;

    short8 kh8[4], kl8[4], vv8[4];
    {
      const uint16_t* kp = &khb[(size_t)(hf * 32 + sr) * HD + sc];
      const uint16_t* lp = &klb[(size_t)(hf * 32 + sr) * HD + sc];
      const uint16_t* vp = &vvb[(size_t)(hf * 32 + sr) * HD + sc];
      #pragma unroll
      for (int j = 0; j < 4; ++j) {
        kh8[j] = *(const short8*)&kp[8 * j];
        kl8[j] = *(const short8*)&lp[8 * j];
        vv8[j] = *(const short8*)&vp[8 * j];
      }
    }

    for (int kt = hf; kt < nkt; kt += 2) {
      const int k0 = kt * 32;
      #pragma unroll
      for (int j = 0; j < 4; ++j) {
        *(short8*)&Khs[sr * KLD + sc + 8 * j] = kh8[j];
        *(short8*)&Kls[sr * KLD + sc + 8 * j] = kl8[j];
      }
      #pragma unroll
      for (int j = 0; j < 4; ++j) {
        const short8 s8 = vv8[j];
        #pragma unroll
        for (int i = 0; i < 8; ++i)
          Vts[(sc + 8 * j + i) * VLD + sr] = (uint16_t)s8[i];
      }
      if (kt + 2 < nkt) {
        const uint16_t* kp = &khb[(size_t)(k0 + 64 + sr) * HD + sc];
        const uint16_t* lp = &klb[(size_t)(k0 + 64 + sr) * HD + sc];
        const uint16_t* vp = &vvb[(size_t)(k0 + 64 + sr) * HD + sc];
        #pragma unroll
        for (int j = 0; j < 4; ++j) {
          kh8[j] = *(const short8*)&kp[8 * j];
          kl8[j] = *(const short8*)&lp[8 * j];
          vv8[j] = *(const short8*)&vp[8 * j];
        }
      }
      asm volatile("s_waitcnt lgkmcnt(0)" ::: "memory");
      __builtin_amdgcn_sched_barrier(0);
      __builtin_amdgcn_s_barrier();
      __builtin_amdgcn_sched_barrier(0);
      if (k0 <= rowmax) {
        f32x4 sfr[2];
        __builtin_amdgcn_s_setprio(1);
        #pragma unroll
        for (int kf = 0; kf < 2; ++kf) {
          f32x4 c0 = (f32x4){0.f, 0.f, 0.f, 0.f};
          f32x4 c1 = c0, c2 = c0;
          #pragma unroll
          for (int dc = 0; dc < 8; ++dc) {
            const int off = (16 * kf + l15) * KLD + 32 * dc + 8 * l4;
            const short8 kh = *(const short8*)&Khs[off];
            const short8 kl = *(const short8*)&Kls[off];
            c0 = __builtin_amdgcn_mfma_f32_16x16x32_bf16(qh[dc], kh, c0, 0, 0, 0);
            c1 = __builtin_amdgcn_mfma_f32_16x16x32_bf16(qh[dc], kl, c1, 0, 0, 0);
            c2 = __builtin_amdgcn_mfma_f32_16x16x32_bf16(ql[dc], kh, c2, 0, 0, 0);
          }
          sfr[kf] = (c0 + c1) + c2;
        }
        __builtin_amdgcn_s_setprio(0);
        uint16_t* pw = &Ps[w * 16 * PLD];
        #pragma unroll
        for (int kf = 0; kf < 2; ++kf) {
          #pragma unroll
          for (int ri = 0; ri < 4; ++ri) {
            const float pd = sfr[kf][ri];
            const float t1 = exp2f(pd * 0.0577078016f);
            float e = exp2f(-144.26950409f * __builtin_amdgcn_rcpf(t1 + 1.f));
            if (k0 + 16 * kf + l15 > myrow + ri) e = 0.f;
            den[ri] += e;
            pw[(l4 * 4 + ri) * PLD + 16 * kf + l15] = bfhi(e);
          }
        }
        const short8 pa = *(const short8*)&pw[l15 * PLD + 8 * l4];
        __builtin_amdgcn_s_setprio(1);
        #pragma unroll
        for (int df = 0; df < 16; ++df) {
          const short8 vb = *(const short8*)&Vts[(16 * df + l15) * VLD + 8 * l4];
          acc[df] = __builtin_amdgcn_mfma_f32_16x16x32_bf16(pa, vb, acc[df], 0, 0, 0);
        }
        __builtin_amdgcn_s_setprio(0);
      }
      __builtin_amdgcn_sched_barrier(0);
      __builtin_amdgcn_s_barrier();
      __builtin_amdgcn_sched_barrier(0);
    }
    #pragma unroll
    for (int ri = 0; ri < 4; ++ri) {
      den[ri] += __shfl_xor(den[ri], 1);
      den[ri] += __shfl_xor(den[ri], 2);
      den[ri] += __shfl_xor(den[ri], 4);
      den[ri] += __shfl_xor(den[ri], 8);
    }
    if (l15 == 0) {
      #pragma unroll
      for (int ri = 0; ri < 4; ++ri)
        atomAddF(&den_g[(size_t)bh * SLEN + myrow + ri], den[ri]);
    }
    float* op = &att[((size_t)(b * SLEN + myrow)) * (NH * HD) + h * HD + l15];
    #pragma unroll
    for (int ri = 0; ri < 4; ++ri)
      #pragma unroll
      for (int df = 0; df < 16; ++df)
        atomAddF(&op[(size_t)ri * (NH * HD) + 16 * df], acc[df][ri]);
  }
}

extern "C" void kernel_launch(void* const* d_in, const int* in_sizes, int n_in,
                              void* d_out, int out_size, void* d_ws, size_t ws_size,
                              hipStream_t stream) {
  const float* hs  = (const float*)d_in[0];
  const float* fc  = (const float*)d_in[1];
  const float* fs  = (const float*)d_in[2];
  // d_in[3] = mask: pure causal, handled analytically.
  const float* WAq = (const float*)d_in[4];
  const float* WAk = (const float*)d_in[5];
  const float* WAv = (const float*)d_in[6];
  const float* WBq = (const float*)d_in[7];
  const float* WBk = (const float*)d_in[8];
  const float* WBv = (const float*)d_in[9];
  const float* Wo  = (const float*)d_in[10];
  float* out = (float*)d_out;

  // Workspace (floats). att [0,8.39M) = Bq+Bk exactly (dead after rope).
  // den at Bv start (dead after rope). bf16 q/k/v buffers in [10.49M, 31.46M).
  float* ws   = (float*)d_ws;
  float* Bq   = ws;                               // 6,291,456 floats
  float* Bk   = Bq + (size_t)MTOT * 1536;         // 2,097,152
  float* Bv   = Bk + (size_t)MTOT * 512;          // 2,097,152
  uint16_t* qh = (uint16_t*)(Bv + (size_t)MTOT * 512);   // 8,388,608 shorts each
  uint16_t* ql = qh + (size_t)8388608;
  uint16_t* kh = ql + (size_t)8388608;
  uint16_t* kl = kh + (size_t)8388608;
  uint16_t* vv = kl + (size_t)8388608;            // ends at float-offset 31,457,280
  float* Aall = ws + (size_t)31457280;            // [4096, 80] = 327,680 floats
  float* att  = ws;                               // 8,388,608 floats (= Bq+Bk)
  float* den  = Bv;                               // 32,768 floats at Bv start

  gemm_proj<<<dim3(21, MTOT / 128), 256, 0, stream>>>(hs, WBq, WBk, WBv,
                                                      WAq, WAk, WAv,
                                                      Bq, Bk, Bv, Aall);
  qkv_rope<<<MTOT, 256, 0, stream>>>(Aall, Bq, Bk, Bv, fc, fs, qh, ql, kh, kl, vv);
  zero_acc<<<8192, 256, 0, stream>>>(att, den);
  attn_mfma<<<dim3(512), 256, 0, stream>>>(qh, ql, kh, kl, vv, att, den);
  gemm_norm<<<dim3(HID / 128, MTOT / 128), 256, 0, stream>>>(att, Wo, den, out);
}

// Round 21
// 463.696 us; speedup vs baseline: 6.1722x; 1.0185x over previous
//
#include <hip/hip_runtime.h>
#include <cstdint>

#define HID 2048
#define SLEN 2048
#define NH 8
#define HD 256
#define MTOT 4096

constexpr float SCALING = 0.0625f;   // 256^-0.5
constexpr float SOFTCAP = 50.0f;

typedef __attribute__((ext_vector_type(8))) short short8;
typedef __attribute__((ext_vector_type(4))) float f32x4;

__device__ __forceinline__ uint16_t bfhi(float x) {
  return (uint16_t)(__float_as_uint(x) >> 16);           // truncate
}
__device__ __forceinline__ float bf2f(uint16_t h) {
  return __uint_as_float((uint32_t)h << 16);
}
__device__ __forceinline__ void atomAddF(float* p, float v) {
  __hip_atomic_fetch_add(p, v, __ATOMIC_RELAXED, __HIP_MEMORY_SCOPE_AGENT);
}
__device__ __forceinline__ uint32_t packbf2(float x0, float x1) {
  return (uint32_t)bfhi(x0) | ((uint32_t)bfhi(x1) << 16);
}

// ---------- gemm_proj: ALL projections, one dispatch, T1 XCD-swizzled ------------------
// 1D grid 672 = 21 col-tiles x 32 row-tiles. work = (bid%8)*84 + bid/8 (bijective,
// 672%8==0): XCD k owns row-tiles [4k,4k+4) x all 21 col-tiles -> its L2 holds a 4MB
// A-panel with full reuse (was: every XCD pulled ~all of A; FETCH 360MB, HBM-bound).
// Col-tiles: 0..11 -> hs@WBq; 12 -> fused A-proj; 13..16 -> hs@WBk; 17..20 -> hs@WBv.
__global__ __launch_bounds__(256) void gemm_proj(
    const float* __restrict__ A,
    const float* __restrict__ WBq, const float* __restrict__ WBk,
    const float* __restrict__ WBv,
    const float* __restrict__ WAq, const float* __restrict__ WAk,
    const float* __restrict__ WAv,
    float* __restrict__ Cq, float* __restrict__ Ck, float* __restrict__ Cv,
    float* __restrict__ Aout) {
  __shared__ uint16_t Ah[8 * 520], Al[8 * 520], Bh[8 * 520], Bl[8 * 520];
  const int tid = threadIdx.x;
  const int bid = blockIdx.x;          // 0..671
  const int work = (bid & 7) * 84 + (bid >> 3);
  const int ct = work % 21;            // col tile 0..20
  const int row0 = (work / 21) * 128;  // row tile, contiguous per XCD
  const bool special = (ct == 12);
  const float* Bmat = WBq; float* Cmat = Cq; int Nseg = 1536; int col0 = ct * 128;
  if (ct >= 17)      { Bmat = WBv; Cmat = Cv; Nseg = 512; col0 = (ct - 17) * 128; }
  else if (ct >= 13) { Bmat = WBk; Cmat = Ck; Nseg = 512; col0 = (ct - 13) * 128; }
  const int lane = tid & 63;
  const int wv = tid >> 6;
  const int wr = wv >> 1, wc = wv & 1;

  f32x4 acc[4][4];
  #pragma unroll
  for (int m = 0; m < 4; ++m)
    #pragma unroll
    for (int n = 0; n < 4; ++n) acc[m][n] = (f32x4){0.f, 0.f, 0.f, 0.f};

  const int ar = tid >> 1;
  const int akb = (tid & 1) * 16;
  const int bkk = tid >> 3;
  const int bcg = tid & 7;

  for (int k0 = 0; k0 < 2048; k0 += 32) {
    float4 av[4], bv[4];
    #pragma unroll
    for (int c = 0; c < 4; ++c)
      av[c] = *(const float4*)&A[(size_t)(row0 + ar) * 2048 + k0 + akb + 4 * c];
    if (!special) {
      #pragma unroll
      for (int c = 0; c < 4; ++c)
        bv[c] = *(const float4*)&Bmat[(size_t)(k0 + bkk) * Nseg + col0 + bcg * 16 + 4 * c];
    } else {
      #pragma unroll
      for (int c = 0; c < 4; ++c) {
        if (bcg < 3)
          bv[c] = *(const float4*)&WAq[(size_t)(k0 + bkk) * 48 + bcg * 16 + 4 * c];
        else if (bcg == 3)
          bv[c] = *(const float4*)&WAk[(size_t)(k0 + bkk) * 16 + 4 * c];
        else if (bcg == 4)
          bv[c] = *(const float4*)&WAv[(size_t)(k0 + bkk) * 16 + 4 * c];
        else
          bv[c] = make_float4(0.f, 0.f, 0.f, 0.f);
      }
    }
    __syncthreads();
    #pragma unroll
    for (int c = 0; c < 4; ++c) {
      const int kk = akb + 4 * c;
      const int idx = (ar >> 4) * 520 + (((ar & 15) | ((kk >> 3) << 4)) << 3) + (kk & 7);
      const float x0 = av[c].x, x1 = av[c].y, x2 = av[c].z, x3 = av[c].w;
      const uint16_t h0 = bfhi(x0), h1 = bfhi(x1), h2 = bfhi(x2), h3 = bfhi(x3);
      const uint16_t g0 = bfhi(x0 - bf2f(h0)), g1 = bfhi(x1 - bf2f(h1));
      const uint16_t g2 = bfhi(x2 - bf2f(h2)), g3 = bfhi(x3 - bf2f(h3));
      *(uint2*)&Ah[idx] = make_uint2((uint32_t)h0 | ((uint32_t)h1 << 16),
                                     (uint32_t)h2 | ((uint32_t)h3 << 16));
      *(uint2*)&Al[idx] = make_uint2((uint32_t)g0 | ((uint32_t)g1 << 16),
                                     (uint32_t)g2 | ((uint32_t)g3 << 16));
    }
    #pragma unroll
    for (int c = 0; c < 4; ++c) {
      const float xs4[4] = {bv[c].x, bv[c].y, bv[c].z, bv[c].w};
      #pragma unroll
      for (int i = 0; i < 4; ++i) {
        const int j = bcg * 16 + 4 * c + i;
        const uint16_t h = bfhi(xs4[i]);
        const uint16_t g = bfhi(xs4[i] - bf2f(h));
        const int idx = (j >> 4) * 520 + (((j & 15) | ((bkk >> 3) << 4)) << 3) + (bkk & 7);
        Bh[idx] = h;
        Bl[idx] = g;
      }
    }
    __syncthreads();
    short8 bhf[4], blf[4];
    #pragma unroll
    for (int nf = 0; nf < 4; ++nf) {
      bhf[nf] = *(const short8*)&Bh[(wc * 4 + nf) * 520 + lane * 8];
      blf[nf] = *(const short8*)&Bl[(wc * 4 + nf) * 520 + lane * 8];
    }
    #pragma unroll
    for (int m = 0; m < 4; ++m) {
      const short8 ahf = *(const short8*)&Ah[(wr * 4 + m) * 520 + lane * 8];
      const short8 alf = *(const short8*)&Al[(wr * 4 + m) * 520 + lane * 8];
      #pragma unroll
      for (int nf = 0; nf < 4; ++nf) {
        acc[m][nf] = __builtin_amdgcn_mfma_f32_16x16x32_bf16(ahf, bhf[nf], acc[m][nf], 0, 0, 0);
        acc[m][nf] = __builtin_amdgcn_mfma_f32_16x16x32_bf16(ahf, blf[nf], acc[m][nf], 0, 0, 0);
        acc[m][nf] = __builtin_amdgcn_mfma_f32_16x16x32_bf16(alf, bhf[nf], acc[m][nf], 0, 0, 0);
      }
    }
  }
  #pragma unroll
  for (int m = 0; m < 4; ++m)
    #pragma unroll
    for (int nf = 0; nf < 4; ++nf) {
      const int row = row0 + wr * 64 + m * 16 + ((lane >> 4) << 2);
      const int col = wc * 64 + nf * 16 + (lane & 15);
      if (!special) {
        #pragma unroll
        for (int ri = 0; ri < 4; ++ri)
          Cmat[(size_t)(row + ri) * Nseg + col0 + col] = acc[m][nf][ri];
      } else if (col < 80) {
        #pragma unroll
        for (int ri = 0; ri < 4; ++ri)
          Aout[(size_t)(row + ri) * 80 + col] = acc[m][nf][ri];
      }
    }
}

// ---------- gemm_norm: out = (att / den) @ Wo, T1 XCD-swizzled -------------------------
// 1D grid 512 = 16 col-tiles x 32 row-tiles. work = (bid%8)*64 + bid/8: XCD k owns
// row-tiles [4k,4k+4) -> att-panel reuse in its L2. Normalization fused in A-staging
// (16-float A-window never crosses a 256-col head boundary -> one den scalar each).
__global__ __launch_bounds__(256) void gemm_norm(
    const float* __restrict__ A, const float* __restrict__ B,
    const float* __restrict__ den, float* __restrict__ C) {
  __shared__ uint16_t Ah[8 * 520], Al[8 * 520], Bh[8 * 520], Bl[8 * 520];
  const int tid = threadIdx.x;
  const int bid = blockIdx.x;          // 0..511
  const int work = (bid & 7) * 64 + (bid >> 3);
  const int col0 = (work & 15) * 128;
  const int row0 = (work >> 4) * 128;
  const int lane = tid & 63;
  const int wv = tid >> 6;
  const int wr = wv >> 1, wc = wv & 1;

  f32x4 acc[4][4];
  #pragma unroll
  for (int m = 0; m < 4; ++m)
    #pragma unroll
    for (int n = 0; n < 4; ++n) acc[m][n] = (f32x4){0.f, 0.f, 0.f, 0.f};

  const int ar = tid >> 1;
  const int akb = (tid & 1) * 16;
  const int bkk = tid >> 3;
  const int bcg = tid & 7;
  const int arow = row0 + ar;                       // att row: b*2048+s
  const size_t denrow = (size_t)(arow >> 11) * 8 * SLEN + (arow & 2047);

  for (int k0 = 0; k0 < 2048; k0 += 32) {
    float4 av[4], bv[4];
    const float inv = 1.f / den[denrow + (size_t)((k0 + akb) >> 8) * SLEN];
    #pragma unroll
    for (int c = 0; c < 4; ++c) {
      float4 t = *(const float4*)&A[(size_t)arow * 2048 + k0 + akb + 4 * c];
      t.x *= inv; t.y *= inv; t.z *= inv; t.w *= inv;
      av[c] = t;
    }
    #pragma unroll
    for (int c = 0; c < 4; ++c)
      bv[c] = *(const float4*)&B[(size_t)(k0 + bkk) * HID + col0 + bcg * 16 + 4 * c];
    __syncthreads();
    #pragma unroll
    for (int c = 0; c < 4; ++c) {
      const int kk = akb + 4 * c;
      const int idx = (ar >> 4) * 520 + (((ar & 15) | ((kk >> 3) << 4)) << 3) + (kk & 7);
      const float x0 = av[c].x, x1 = av[c].y, x2 = av[c].z, x3 = av[c].w;
      const uint16_t h0 = bfhi(x0), h1 = bfhi(x1), h2 = bfhi(x2), h3 = bfhi(x3);
      const uint16_t g0 = bfhi(x0 - bf2f(h0)), g1 = bfhi(x1 - bf2f(h1));
      const uint16_t g2 = bfhi(x2 - bf2f(h2)), g3 = bfhi(x3 - bf2f(h3));
      *(uint2*)&Ah[idx] = make_uint2((uint32_t)h0 | ((uint32_t)h1 << 16),
                                     (uint32_t)h2 | ((uint32_t)h3 << 16));
      *(uint2*)&Al[idx] = make_uint2((uint32_t)g0 | ((uint32_t)g1 << 16),
                                     (uint32_t)g2 | ((uint32_t)g3 << 16));
    }
    #pragma unroll
    for (int c = 0; c < 4; ++c) {
      const float xs4[4] = {bv[c].x, bv[c].y, bv[c].z, bv[c].w};
      #pragma unroll
      for (int i = 0; i < 4; ++i) {
        const int j = bcg * 16 + 4 * c + i;
        const uint16_t h = bfhi(xs4[i]);
        const uint16_t g = bfhi(xs4[i] - bf2f(h));
        const int idx = (j >> 4) * 520 + (((j & 15) | ((bkk >> 3) << 4)) << 3) + (bkk & 7);
        Bh[idx] = h;
        Bl[idx] = g;
      }
    }
    __syncthreads();
    short8 bhf[4], blf[4];
    #pragma unroll
    for (int nf = 0; nf < 4; ++nf) {
      bhf[nf] = *(const short8*)&Bh[(wc * 4 + nf) * 520 + lane * 8];
      blf[nf] = *(const short8*)&Bl[(wc * 4 + nf) * 520 + lane * 8];
    }
    #pragma unroll
    for (int m = 0; m < 4; ++m) {
      const short8 ahf = *(const short8*)&Ah[(wr * 4 + m) * 520 + lane * 8];
      const short8 alf = *(const short8*)&Al[(wr * 4 + m) * 520 + lane * 8];
      #pragma unroll
      for (int nf = 0; nf < 4; ++nf) {
        acc[m][nf] = __builtin_amdgcn_mfma_f32_16x16x32_bf16(ahf, bhf[nf], acc[m][nf], 0, 0, 0);
        acc[m][nf] = __builtin_amdgcn_mfma_f32_16x16x32_bf16(ahf, blf[nf], acc[m][nf], 0, 0, 0);
        acc[m][nf] = __builtin_amdgcn_mfma_f32_16x16x32_bf16(alf, bhf[nf], acc[m][nf], 0, 0, 0);
      }
    }
  }
  #pragma unroll
  for (int m = 0; m < 4; ++m)
    #pragma unroll
    for (int nf = 0; nf < 4; ++nf) {
      const int row = row0 + wr * 64 + m * 16 + ((lane >> 4) << 2);
      const int col = col0 + wc * 64 + nf * 16 + (lane & 15);
      #pragma unroll
      for (int ri = 0; ri < 4; ++ri)
        C[(size_t)(row + ri) * HID + col] = acc[m][nf][ri];
    }
}

// ------------- RoPE + rank contraction v3 (validated r17, unchanged) ------------------
__global__ __launch_bounds__(256) void qkv_rope(
    const float* __restrict__ Aall,
    const float* __restrict__ Bq, const float* __restrict__ Bk,
    const float* __restrict__ Bv,
    const float* __restrict__ fc, const float* __restrict__ fs,
    uint16_t* __restrict__ qhg, uint16_t* __restrict__ qlg,
    uint16_t* __restrict__ khg, uint16_t* __restrict__ klg,
    uint16_t* __restrict__ vvg) {
  const int m = blockIdx.x;        // 0..4095  (b*SLEN + s)
  const int s = m & (SLEN - 1);
  const int b = m >> 11;
  const int tid = threadIdx.x;
  __shared__ float Al[80];         // A_q[48] | A_k[16] | A_v[16]

  if (tid < 20) *(float4*)&Al[tid * 4] = *(const float4*)&Aall[(size_t)m * 80 + tid * 4];
  __syncthreads();

  const size_t tbase = (size_t)b * NH * SLEN * HD + (size_t)s * HD;
  if (tid < 128) {
    const int j = tid;
    const float cz = fc[s * 128 + j], sz = fs[s * 128 + j];
    float qe[8], qo[8];
    #pragma unroll
    for (int hh = 0; hh < 8; ++hh) { qe[hh] = 0.f; qo[hh] = 0.f; }
    #pragma unroll
    for (int r = 0; r < 6; ++r) {
      const float2 x = *(const float2*)&Bq[(size_t)m * 1536 + r * 256 + 2 * j];
      const float re = x.x * cz - x.y * sz;
      const float ro = x.x * sz + x.y * cz;
      #pragma unroll
      for (int hh = 0; hh < 8; ++hh) {
        const float a = Al[hh * 6 + r];
        qe[hh] = fmaf(a, re, qe[hh]);
        qo[hh] = fmaf(a, ro, qo[hh]);
      }
    }
    const float qs = SCALING / 6.f;
    #pragma unroll
    for (int hh = 0; hh < 8; ++hh) {
      const float x0 = qe[hh] * qs, x1 = qo[hh] * qs;
      const uint16_t h0 = bfhi(x0), h1 = bfhi(x1);
      const size_t eb = (tbase + (size_t)hh * SLEN * HD + 2 * j) >> 1;
      ((uint32_t*)qhg)[eb] = (uint32_t)h0 | ((uint32_t)h1 << 16);
      ((uint32_t*)qlg)[eb] = packbf2(x0 - bf2f(h0), x1 - bf2f(h1));
    }
  } else {
    const int j = tid - 128;
    const float cz = fc[s * 128 + j], sz = fs[s * 128 + j];
    float ke_[8], ko_[8], ve_[8], vo_[8];
    #pragma unroll
    for (int hh = 0; hh < 8; ++hh) { ke_[hh]=0.f; ko_[hh]=0.f; ve_[hh]=0.f; vo_[hh]=0.f; }
    #pragma unroll
    for (int r = 0; r < 2; ++r) {
      const float2 xk = *(const float2*)&Bk[(size_t)m * 512 + r * 256 + 2 * j];
      const float2 xv = *(const float2*)&Bv[(size_t)m * 512 + r * 256 + 2 * j];
      const float re = xk.x * cz - xk.y * sz;
      const float ro = xk.x * sz + xk.y * cz;
      #pragma unroll
      for (int hh = 0; hh < 8; ++hh) {
        const float ak = Al[48 + hh * 2 + r];
        const float av = Al[64 + hh * 2 + r];
        ke_[hh] = fmaf(ak, re, ke_[hh]);
        ko_[hh] = fmaf(ak, ro, ko_[hh]);
        ve_[hh] = fmaf(av, xv.x, ve_[hh]);
        vo_[hh] = fmaf(av, xv.y, vo_[hh]);
      }
    }
    #pragma unroll
    for (int hh = 0; hh < 8; ++hh) {
      const float x0 = ke_[hh] * 0.5f, x1 = ko_[hh] * 0.5f;
      const uint16_t h0 = bfhi(x0), h1 = bfhi(x1);
      const size_t eb = (tbase + (size_t)hh * SLEN * HD + 2 * j) >> 1;
      ((uint32_t*)khg)[eb] = (uint32_t)h0 | ((uint32_t)h1 << 16);
      ((uint32_t*)klg)[eb] = packbf2(x0 - bf2f(h0), x1 - bf2f(h1));
      ((uint32_t*)vvg)[eb] = packbf2(ve_[hh] * 0.5f, vo_[hh] * 0.5f);
    }
  }
}

// ------------- zero att + den (harness poisons ws; atomics need zeros) ----------------
__global__ __launch_bounds__(256) void zero_acc(float* __restrict__ att,
                                                float* __restrict__ den) {
  const int idx = blockIdx.x * 256 + threadIdx.x;   // float4 index
  const float4 z = {0.f, 0.f, 0.f, 0.f};
  *(float4*)&att[(size_t)idx * 4] = z;              // grid covers 8,388,608 floats
  if (idx < 8192) *(float4*)&den[(size_t)idx * 4] = z;   // 32768 floats
}

// ------------- causal softcapped attention v8 (validated r17, unchanged) --------------
#define KLD 264
#define VLD 40
#define PLD 40
__global__ __launch_bounds__(256, 2) void attn_mfma(
    const uint16_t* __restrict__ qhg, const uint16_t* __restrict__ qlg,
    const uint16_t* __restrict__ khg, const uint16_t* __restrict__ klg,
    const uint16_t* __restrict__ vvg, float* __restrict__ att,
    float* __restrict__ den_g) {
  __shared__ uint16_t Khs[32 * KLD];
  __shared__ uint16_t Kls[32 * KLD];
  __shared__ uint16_t Vts[256 * VLD];
  __shared__ uint16_t Ps[4 * 16 * PLD];
  const int tid = threadIdx.x;
  const int lane = tid & 63;
  const int w = tid >> 6;
  const int l15 = lane & 15;
  const int l4 = lane >> 4;
  const int bid = blockIdx.x;
  const int bh = bid & 15;             // low bits -> per-bh K/V pins to one XCD L2
  const int p = (bid >> 4) & 15;
  const int hf = bid >> 8;             // k-parity half
  const int b = bh >> 3, h = bh & 7;
  const size_t base = (size_t)bh * SLEN * HD;
  const uint16_t* khb = &khg[base];
  const uint16_t* klb = &klg[base];
  const uint16_t* vvb = &vvg[base];
  const int sr = tid & 31;
  const int sc = (tid >> 5) * 32;

  #pragma unroll
  for (int sub = 0; sub < 2; ++sub) {
    const int qt = (sub == 0) ? (31 - p) : p;
    const int q0 = qt * 64;
    short8 qh[8], ql[8];
    {
      const uint16_t* qhp = &qhg[base + (size_t)(q0 + w * 16 + l15) * HD + 8 * l4];
      const uint16_t* qlp = &qlg[base + (size_t)(q0 + w * 16 + l15) * HD + 8 * l4];
      #pragma unroll
      for (int f = 0; f < 8; ++f) {
        qh[f] = *(const short8*)&qhp[32 * f];
        ql[f] = *(const short8*)&qlp[32 * f];
      }
    }
    f32x4 acc[16];
    #pragma unroll
    for (int df = 0; df < 16; ++df) acc[df] = (f32x4){0.f, 0.f, 0.f, 0.f};
    float den[4] = {0.f, 0.f, 0.f, 0.f};

    const int myrow = q0 + w * 16 + l4 * 4;
    const int rowmax = q0 + w * 16 + 15;
    const int nkt = 2 * qt + 2;

    short8 kh8[4], kl8[4], vv8[4];
    {
      const uint16_t* kp = &khb[(size_t)(hf * 32 + sr) * HD + sc];
      const uint16_t* lp = &klb[(size_t)(hf * 32 + sr) * HD + sc];
      const uint16_t* vp = &vvb[(size_t)(hf * 32 + sr) * HD + sc];
      #pragma unroll
      for (int j = 0; j < 4; ++j) {
        kh8[j] = *(const short8*)&kp[8 * j];
        kl8[j] = *(const short8*)&lp[8 * j];
        vv8[j] = *(const short8*)&vp[8 * j];
      }
    }

    for (int kt = hf; kt < nkt; kt += 2) {
      const int k0 = kt * 32;
      #pragma unroll
      for (int j = 0; j < 4; ++j) {
        *(short8*)&Khs[sr * KLD + sc + 8 * j] = kh8[j];
        *(short8*)&Kls[sr * KLD + sc + 8 * j] = kl8[j];
      }
      #pragma unroll
      for (int j = 0; j < 4; ++j) {
        const short8 s8 = vv8[j];
        #pragma unroll
        for (int i = 0; i < 8; ++i)
          Vts[(sc + 8 * j + i) * VLD + sr] = (uint16_t)s8[i];
      }
      if (kt + 2 < nkt) {
        const uint16_t* kp = &khb[(size_t)(k0 + 64 + sr) * HD + sc];
        const uint16_t* lp = &klb[(size_t)(k0 + 64 + sr) * HD + sc];
        const uint16_t* vp = &vvb[(size_t)(k0 + 64 + sr) * HD + sc];
        #pragma unroll
        for (int j = 0; j < 4; ++j) {
          kh8[j] = *(const short8*)&kp[8 * j];
          kl8[j] = *(const short8*)&lp[8 * j];
          vv8[j] = *(const short8*)&vp[8 * j];
        }
      }
      asm volatile("s_waitcnt lgkmcnt(0)" ::: "memory");
      __builtin_amdgcn_sched_barrier(0);
      __builtin_amdgcn_s_barrier();
      __builtin_amdgcn_sched_barrier(0);
      if (k0 <= rowmax) {
        f32x4 sfr[2];
        __builtin_amdgcn_s_setprio(1);
        #pragma unroll
        for (int kf = 0; kf < 2; ++kf) {
          f32x4 c0 = (f32x4){0.f, 0.f, 0.f, 0.f};
          f32x4 c1 = c0, c2 = c0;
          #pragma unroll
          for (int dc = 0; dc < 8; ++dc) {
            const int off = (16 * kf + l15) * KLD + 32 * dc + 8 * l4;
            const short8 kh = *(const short8*)&Khs[off];
            const short8 kl = *(const short8*)&Kls[off];
            c0 = __builtin_amdgcn_mfma_f32_16x16x32_bf16(qh[dc], kh, c0, 0, 0, 0);
            c1 = __builtin_amdgcn_mfma_f32_16x16x32_bf16(qh[dc], kl, c1, 0, 0, 0);
            c2 = __builtin_amdgcn_mfma_f32_16x16x32_bf16(ql[dc], kh, c2, 0, 0, 0);
          }
          sfr[kf] = (c0 + c1) + c2;
        }
        __builtin_amdgcn_s_setprio(0);
        uint16_t* pw = &Ps[w * 16 * PLD];
        #pragma unroll
        for (int kf = 0; kf < 2; ++kf) {
          #pragma unroll
          for (int ri = 0; ri < 4; ++ri) {
            const float pd = sfr[kf][ri];
            const float t1 = exp2f(pd * 0.0577078016f);
            float e = exp2f(-144.26950409f * __builtin_amdgcn_rcpf(t1 + 1.f));
            if (k0 + 16 * kf + l15 > myrow + ri) e = 0.f;
            den[ri] += e;
            pw[(l4 * 4 + ri) * PLD + 16 * kf + l15] = bfhi(e);
          }
        }
        const short8 pa = *(const short8*)&pw[l15 * PLD + 8 * l4];
        __builtin_amdgcn_s_setprio(1);
        #pragma unroll
        for (int df = 0; df < 16; ++df) {
          const short8 vb = *(const short8*)&Vts[(16 * df + l15) * VLD + 8 * l4];
          acc[df] = __builtin_amdgcn_mfma_f32_16x16x32_bf16(pa, vb, acc[df], 0, 0, 0);
        }
        __builtin_amdgcn_s_setprio(0);
      }
      __builtin_amdgcn_sched_barrier(0);
      __builtin_amdgcn_s_barrier();
      __builtin_amdgcn_sched_barrier(0);
    }
    #pragma unroll
    for (int ri = 0; ri < 4; ++ri) {
      den[ri] += __shfl_xor(den[ri], 1);
      den[ri] += __shfl_xor(den[ri], 2);
      den[ri] += __shfl_xor(den[ri], 4);
      den[ri] += __shfl_xor(den[ri], 8);
    }
    if (l15 == 0) {
      #pragma unroll
      for (int ri = 0; ri < 4; ++ri)
        atomAddF(&den_g[(size_t)bh * SLEN + myrow + ri], den[ri]);
    }
    float* op = &att[((size_t)(b * SLEN + myrow)) * (NH * HD) + h * HD + l15];
    #pragma unroll
    for (int ri = 0; ri < 4; ++ri)
      #pragma unroll
      for (int df = 0; df < 16; ++df)
        atomAddF(&op[(size_t)ri * (NH * HD) + 16 * df], acc[df][ri]);
  }
}

extern "C" void kernel_launch(void* const* d_in, const int* in_sizes, int n_in,
                              void* d_out, int out_size, void* d_ws, size_t ws_size,
                              hipStream_t stream) {
  const float* hs  = (const float*)d_in[0];
  const float* fc  = (const float*)d_in[1];
  const float* fs  = (const float*)d_in[2];
  // d_in[3] = mask: pure causal, handled analytically.
  const float* WAq = (const float*)d_in[4];
  const float* WAk = (const float*)d_in[5];
  const float* WAv = (const float*)d_in[6];
  const float* WBq = (const float*)d_in[7];
  const float* WBk = (const float*)d_in[8];
  const float* WBv = (const float*)d_in[9];
  const float* Wo  = (const float*)d_in[10];
  float* out = (float*)d_out;

  // Workspace (floats). att [0,8.39M) = Bq+Bk exactly (dead after rope).
  // den at Bv start (dead after rope). bf16 q/k/v buffers in [10.49M, 31.46M).
  float* ws   = (float*)d_ws;
  float* Bq   = ws;                               // 6,291,456 floats
  float* Bk   = Bq + (size_t)MTOT * 1536;         // 2,097,152
  float* Bv   = Bk + (size_t)MTOT * 512;          // 2,097,152
  uint16_t* qh = (uint16_t*)(Bv + (size_t)MTOT * 512);   // 8,388,608 shorts each
  uint16_t* ql = qh + (size_t)8388608;
  uint16_t* kh = ql + (size_t)8388608;
  uint16_t* kl = kh + (size_t)8388608;
  uint16_t* vv = kl + (size_t)8388608;            // ends at float-offset 31,457,280
  float* Aall = ws + (size_t)31457280;            // [4096, 80] = 327,680 floats
  float* att  = ws;                               // 8,388,608 floats (= Bq+Bk)
  float* den  = Bv;                               // 32,768 floats at Bv start

  gemm_proj<<<dim3(672), 256, 0, stream>>>(hs, WBq, WBk, WBv,
                                           WAq, WAk, WAv,
                                           Bq, Bk, Bv, Aall);
  qkv_rope<<<MTOT, 256, 0, stream>>>(Aall, Bq, Bk, Bv, fc, fs, qh, ql, kh, kl, vv);
  zero_acc<<<8192, 256, 0, stream>>>(att, den);
  attn_mfma<<<dim3(512), 256, 0, stream>>>(qh, ql, kh, kl, vv, att, den);
  gemm_norm<<<dim3(512), 256, 0, stream>>>(att, Wo, den, out);
}

// Round 22
// 448.559 us; speedup vs baseline: 6.3805x; 1.0337x over previous
//
#include <hip/hip_runtime.h>
#include <cstdint>

#define HID 2048
#define SLEN 2048
#define NH 8
#define HD 256
#define MTOT 4096

constexpr float SCALING = 0.0625f;   // 256^-0.5
constexpr float SOFTCAP = 50.0f;

typedef __attribute__((ext_vector_type(8))) short short8;
typedef __attribute__((ext_vector_type(4))) float f32x4;

__device__ __forceinline__ uint16_t bfhi(float x) {
  return (uint16_t)(__float_as_uint(x) >> 16);           // truncate
}
__device__ __forceinline__ float bf2f(uint16_t h) {
  return __uint_as_float((uint32_t)h << 16);
}
__device__ __forceinline__ void packsplit8(const float4 a, const float4 b,
                                           short8& hi, short8& lo) {
  const float x[8] = {a.x, a.y, a.z, a.w, b.x, b.y, b.z, b.w};
  #pragma unroll
  for (int i = 0; i < 8; ++i) {
    const uint32_t u = __float_as_uint(x[i]);
    const uint16_t h = (uint16_t)(u >> 16);
    const float r = x[i] - bf2f(h);
    hi[i] = (short)h;
    lo[i] = (short)(__float_as_uint(r) >> 16);
  }
}
__device__ __forceinline__ void atomAddF(float* p, float v) {
  __hip_atomic_fetch_add(p, v, __ATOMIC_RELAXED, __HIP_MEMORY_SCOPE_AGENT);
}
__device__ __forceinline__ uint32_t packbf2(float x0, float x1) {
  return (uint32_t)bfhi(x0) | ((uint32_t)bfhi(x1) << 16);
}

// ---------- conv_pre: hs -> split-bf16 (row-major) + proj weights -> frag-native ------
// Frag-native: element (ct,kc,cf,lane,e) = Wcat[kc*32+8*(lane>>4)+e][ctcols(cf*16+(lane&15))]
// stored at linear short offset g*8+e with g=((ct*64+kc)*8+cf)*64+lane -> each lane's 8
// shorts (16B) are contiguous, so GEMM staging is pure 16B copies.
__global__ __launch_bounds__(256) void conv_pre(
    const float* __restrict__ hs,
    const float* __restrict__ WBq, const float* __restrict__ WBk,
    const float* __restrict__ WBv,
    const float* __restrict__ WAq, const float* __restrict__ WAk,
    const float* __restrict__ WAv,
    uint16_t* __restrict__ hsh, uint16_t* __restrict__ hsl,
    uint16_t* __restrict__ wfh, uint16_t* __restrict__ wfl) {
  const int bid = blockIdx.x;
  const int tid = threadIdx.x;
  if (bid < 4096) {
    const size_t off = (size_t)bid * 2048 + tid * 8;
    const float4 a = *(const float4*)&hs[off];
    const float4 b = *(const float4*)&hs[off + 4];
    short8 hi, lo;
    packsplit8(a, b, hi, lo);
    *(short8*)&hsh[off] = hi;
    *(short8*)&hsl[off] = lo;
  } else {
    const int g = (bid - 4096) * 256 + tid;   // 0..688127
    const int lane_ = g & 63;
    const int cf = (g >> 6) & 7;
    const int kc = (g >> 9) & 63;
    const int ct = g >> 15;                   // 0..20
    const int col = cf * 16 + (lane_ & 15);
    const int kb = kc * 32 + 8 * (lane_ >> 4);
    float x[8];
    #pragma unroll
    for (int e = 0; e < 8; ++e) {
      const int k = kb + e;
      float v;
      if (ct == 12) {
        if (col < 48)      v = WAq[(size_t)k * 48 + col];
        else if (col < 64) v = WAk[(size_t)k * 16 + (col - 48)];
        else if (col < 80) v = WAv[(size_t)k * 16 + (col - 64)];
        else               v = 0.f;
      } else if (ct < 12) {
        v = WBq[(size_t)k * 1536 + ct * 128 + col];
      } else if (ct < 17) {
        v = WBk[(size_t)k * 512 + (ct - 13) * 128 + col];
      } else {
        v = WBv[(size_t)k * 512 + (ct - 17) * 128 + col];
      }
      x[e] = v;
    }
    short8 hi, lo;
    packsplit8(make_float4(x[0], x[1], x[2], x[3]),
               make_float4(x[4], x[5], x[6], x[7]), hi, lo);
    *(short8*)&wfh[(size_t)g * 8] = hi;
    *(short8*)&wfl[(size_t)g * 8] = lo;
  }
}

// ---------- gemm_proj v3: pre-converted operands, pure-copy staging, XCD-swizzled -----
// Staging: 8x16B global loads + 8x16B aligned LDS writes per thread; ZERO convert VALU,
// zero scalar ds_writes (was ~100 VALU + 16 ds_write_u16 per iter -> MfmaUtil 29%).
// ds_read/MFMA core and C-write byte-identical to the r9-validated GEMM.
__global__ __launch_bounds__(256) void gemm_proj(
    const uint16_t* __restrict__ hsh, const uint16_t* __restrict__ hsl,
    const uint16_t* __restrict__ wfh, const uint16_t* __restrict__ wfl,
    float* __restrict__ Cq, float* __restrict__ Ck, float* __restrict__ Cv,
    float* __restrict__ Aout) {
  __shared__ uint16_t Ah[8 * 520], Al[8 * 520], Bh[8 * 520], Bl[8 * 520];
  const int tid = threadIdx.x;
  const int bid = blockIdx.x;          // 0..671
  const int work = (bid & 7) * 84 + (bid >> 3);
  const int ct = work % 21;
  const int row0 = (work / 21) * 128;
  const bool special = (ct == 12);
  float* Cmat = Cq; int Nseg = 1536; int col0 = ct * 128;
  if (ct >= 17)      { Cmat = Cv; Nseg = 512; col0 = (ct - 17) * 128; }
  else if (ct >= 13) { Cmat = Ck; Nseg = 512; col0 = (ct - 13) * 128; }
  const int lane = tid & 63;
  const int wv = tid >> 6;
  const int wr = wv >> 1, wc = wv & 1;

  f32x4 acc[4][4];
  #pragma unroll
  for (int m = 0; m < 4; ++m)
    #pragma unroll
    for (int n = 0; n < 4; ++n) acc[m][n] = (f32x4){0.f, 0.f, 0.f, 0.f};

  const int ar = tid >> 1;             // A row 0..127
  const int akb = (tid & 1) * 16;      // k half
  const int ia0 = (ar >> 4) * 520 + (ar & 15) * 8 + (akb >> 3) * 128;
  const int bf_ = tid >> 5;            // B copy frag 0..7
  const int boff = (tid & 31) * 16;    // 0..496
  const int ib = bf_ * 520 + boff;

  for (int kc = 0; kc < 64; ++kc) {
    const int k0 = kc * 32;
    const size_t aoff = (size_t)(row0 + ar) * 2048 + k0 + akb;
    const short8 a0h = *(const short8*)&hsh[aoff];
    const short8 a1h = *(const short8*)&hsh[aoff + 8];
    const short8 a0l = *(const short8*)&hsl[aoff];
    const short8 a1l = *(const short8*)&hsl[aoff + 8];
    const size_t boffg = ((size_t)(ct * 64 + kc) * 8 + bf_) * 512 + boff;
    const short8 b0h = *(const short8*)&wfh[boffg];
    const short8 b1h = *(const short8*)&wfh[boffg + 8];
    const short8 b0l = *(const short8*)&wfl[boffg];
    const short8 b1l = *(const short8*)&wfl[boffg + 8];
    __syncthreads();   // previous tile fully consumed
    *(short8*)&Ah[ia0] = a0h;       *(short8*)&Ah[ia0 + 128] = a1h;
    *(short8*)&Al[ia0] = a0l;       *(short8*)&Al[ia0 + 128] = a1l;
    *(short8*)&Bh[ib] = b0h;        *(short8*)&Bh[ib + 8] = b1h;
    *(short8*)&Bl[ib] = b0l;        *(short8*)&Bl[ib + 8] = b1l;
    __syncthreads();
    short8 bhf[4], blf[4];
    #pragma unroll
    for (int nf = 0; nf < 4; ++nf) {
      bhf[nf] = *(const short8*)&Bh[(wc * 4 + nf) * 520 + lane * 8];
      blf[nf] = *(const short8*)&Bl[(wc * 4 + nf) * 520 + lane * 8];
    }
    #pragma unroll
    for (int m = 0; m < 4; ++m) {
      const short8 ahf = *(const short8*)&Ah[(wr * 4 + m) * 520 + lane * 8];
      const short8 alf = *(const short8*)&Al[(wr * 4 + m) * 520 + lane * 8];
      #pragma unroll
      for (int nf = 0; nf < 4; ++nf) {
        acc[m][nf] = __builtin_amdgcn_mfma_f32_16x16x32_bf16(ahf, bhf[nf], acc[m][nf], 0, 0, 0);
        acc[m][nf] = __builtin_amdgcn_mfma_f32_16x16x32_bf16(ahf, blf[nf], acc[m][nf], 0, 0, 0);
        acc[m][nf] = __builtin_amdgcn_mfma_f32_16x16x32_bf16(alf, bhf[nf], acc[m][nf], 0, 0, 0);
      }
    }
  }
  #pragma unroll
  for (int m = 0; m < 4; ++m)
    #pragma unroll
    for (int nf = 0; nf < 4; ++nf) {
      const int row = row0 + wr * 64 + m * 16 + ((lane >> 4) << 2);
      const int col = wc * 64 + nf * 16 + (lane & 15);
      if (!special) {
        #pragma unroll
        for (int ri = 0; ri < 4; ++ri)
          Cmat[(size_t)(row + ri) * Nseg + col0 + col] = acc[m][nf][ri];
      } else if (col < 80) {
        #pragma unroll
        for (int ri = 0; ri < 4; ++ri)
          Aout[(size_t)(row + ri) * 80 + col] = acc[m][nf][ri];
      }
    }
}

// ---------- norm_conv: atth/attl = split(att/den); Wo -> frag-native ------------------
__global__ __launch_bounds__(256) void norm_conv(
    const float* __restrict__ att, const float* __restrict__ den,
    const float* __restrict__ Wo,
    uint16_t* __restrict__ ath, uint16_t* __restrict__ atl,
    uint16_t* __restrict__ wfh, uint16_t* __restrict__ wfl) {
  const int bid = blockIdx.x;
  const int tid = threadIdx.x;
  if (bid < 4096) {
    const int m = bid;                      // att row b*2048+s
    const int hh = tid >> 5;                // head of cols [tid*8, tid*8+8)
    const float inv = 1.f / den[((size_t)(m >> 11) * 8 + hh) * SLEN + (m & 2047)];
    const size_t off = (size_t)m * 2048 + tid * 8;
    float4 a = *(const float4*)&att[off];
    float4 b = *(const float4*)&att[off + 4];
    a.x *= inv; a.y *= inv; a.z *= inv; a.w *= inv;
    b.x *= inv; b.y *= inv; b.z *= inv; b.w *= inv;
    short8 hi, lo;
    packsplit8(a, b, hi, lo);
    *(short8*)&ath[off] = hi;
    *(short8*)&atl[off] = lo;
  } else {
    const int g = (bid - 4096) * 256 + tid; // 0..524287
    const int lane_ = g & 63;
    const int cf = (g >> 6) & 7;
    const int kc = (g >> 9) & 63;
    const int ct2 = g >> 15;                // 0..15
    const int col = ct2 * 128 + cf * 16 + (lane_ & 15);
    const int kb = kc * 32 + 8 * (lane_ >> 4);
    float x[8];
    #pragma unroll
    for (int e = 0; e < 8; ++e) x[e] = Wo[(size_t)(kb + e) * 2048 + col];
    short8 hi, lo;
    packsplit8(make_float4(x[0], x[1], x[2], x[3]),
               make_float4(x[4], x[5], x[6], x[7]), hi, lo);
    *(short8*)&wfh[(size_t)g * 8] = hi;
    *(short8*)&wfl[(size_t)g * 8] = lo;
  }
}

// ---------- gemm_norm v3: out = attn_norm @ Wo, pre-converted, XCD-swizzled -----------
__global__ __launch_bounds__(256) void gemm_norm(
    const uint16_t* __restrict__ ath, const uint16_t* __restrict__ atl,
    const uint16_t* __restrict__ wfh, const uint16_t* __restrict__ wfl,
    float* __restrict__ C) {
  __shared__ uint16_t Ah[8 * 520], Al[8 * 520], Bh[8 * 520], Bl[8 * 520];
  const int tid = threadIdx.x;
  const int bid = blockIdx.x;          // 0..511
  const int work = (bid & 7) * 64 + (bid >> 3);
  const int ct2 = work & 15;
  const int col0 = ct2 * 128;
  const int row0 = (work >> 4) * 128;
  const int lane = tid & 63;
  const int wv = tid >> 6;
  const int wr = wv >> 1, wc = wv & 1;

  f32x4 acc[4][4];
  #pragma unroll
  for (int m = 0; m < 4; ++m)
    #pragma unroll
    for (int n = 0; n < 4; ++n) acc[m][n] = (f32x4){0.f, 0.f, 0.f, 0.f};

  const int ar = tid >> 1;
  const int akb = (tid & 1) * 16;
  const int ia0 = (ar >> 4) * 520 + (ar & 15) * 8 + (akb >> 3) * 128;
  const int bf_ = tid >> 5;
  const int boff = (tid & 31) * 16;
  const int ib = bf_ * 520 + boff;

  for (int kc = 0; kc < 64; ++kc) {
    const int k0 = kc * 32;
    const size_t aoff = (size_t)(row0 + ar) * 2048 + k0 + akb;
    const short8 a0h = *(const short8*)&ath[aoff];
    const short8 a1h = *(const short8*)&ath[aoff + 8];
    const short8 a0l = *(const short8*)&atl[aoff];
    const short8 a1l = *(const short8*)&atl[aoff + 8];
    const size_t boffg = ((size_t)(ct2 * 64 + kc) * 8 + bf_) * 512 + boff;
    const short8 b0h = *(const short8*)&wfh[boffg];
    const short8 b1h = *(const short8*)&wfh[boffg + 8];
    const short8 b0l = *(const short8*)&wfl[boffg];
    const short8 b1l = *(const short8*)&wfl[boffg + 8];
    __syncthreads();
    *(short8*)&Ah[ia0] = a0h;       *(short8*)&Ah[ia0 + 128] = a1h;
    *(short8*)&Al[ia0] = a0l;       *(short8*)&Al[ia0 + 128] = a1l;
    *(short8*)&Bh[ib] = b0h;        *(short8*)&Bh[ib + 8] = b1h;
    *(short8*)&Bl[ib] = b0l;        *(short8*)&Bl[ib + 8] = b1l;
    __syncthreads();
    short8 bhf[4], blf[4];
    #pragma unroll
    for (int nf = 0; nf < 4; ++nf) {
      bhf[nf] = *(const short8*)&Bh[(wc * 4 + nf) * 520 + lane * 8];
      blf[nf] = *(const short8*)&Bl[(wc * 4 + nf) * 520 + lane * 8];
    }
    #pragma unroll
    for (int m = 0; m < 4; ++m) {
      const short8 ahf = *(const short8*)&Ah[(wr * 4 + m) * 520 + lane * 8];
      const short8 alf = *(const short8*)&Al[(wr * 4 + m) * 520 + lane * 8];
      #pragma unroll
      for (int nf = 0; nf < 4; ++nf) {
        acc[m][nf] = __builtin_amdgcn_mfma_f32_16x16x32_bf16(ahf, bhf[nf], acc[m][nf], 0, 0, 0);
        acc[m][nf] = __builtin_amdgcn_mfma_f32_16x16x32_bf16(ahf, blf[nf], acc[m][nf], 0, 0, 0);
        acc[m][nf] = __builtin_amdgcn_mfma_f32_16x16x32_bf16(alf, bhf[nf], acc[m][nf], 0, 0, 0);
      }
    }
  }
  #pragma unroll
  for (int m = 0; m < 4; ++m)
    #pragma unroll
    for (int nf = 0; nf < 4; ++nf) {
      const int row = row0 + wr * 64 + m * 16 + ((lane >> 4) << 2);
      const int col = col0 + wc * 64 + nf * 16 + (lane & 15);
      #pragma unroll
      for (int ri = 0; ri < 4; ++ri)
        C[(size_t)(row + ri) * HID + col] = acc[m][nf][ri];
    }
}

// ------------- RoPE + rank contraction v3 (validated r17, unchanged) ------------------
__global__ __launch_bounds__(256) void qkv_rope(
    const float* __restrict__ Aall,
    const float* __restrict__ Bq, const float* __restrict__ Bk,
    const float* __restrict__ Bv,
    const float* __restrict__ fc, const float* __restrict__ fs,
    uint16_t* __restrict__ qhg, uint16_t* __restrict__ qlg,
    uint16_t* __restrict__ khg, uint16_t* __restrict__ klg,
    uint16_t* __restrict__ vvg) {
  const int m = blockIdx.x;        // 0..4095  (b*SLEN + s)
  const int s = m & (SLEN - 1);
  const int b = m >> 11;
  const int tid = threadIdx.x;
  __shared__ float Al[80];         // A_q[48] | A_k[16] | A_v[16]

  if (tid < 20) *(float4*)&Al[tid * 4] = *(const float4*)&Aall[(size_t)m * 80 + tid * 4];
  __syncthreads();

  const size_t tbase = (size_t)b * NH * SLEN * HD + (size_t)s * HD;
  if (tid < 128) {
    const int j = tid;
    const float cz = fc[s * 128 + j], sz = fs[s * 128 + j];
    float qe[8], qo[8];
    #pragma unroll
    for (int hh = 0; hh < 8; ++hh) { qe[hh] = 0.f; qo[hh] = 0.f; }
    #pragma unroll
    for (int r = 0; r < 6; ++r) {
      const float2 x = *(const float2*)&Bq[(size_t)m * 1536 + r * 256 + 2 * j];
      const float re = x.x * cz - x.y * sz;
      const float ro = x.x * sz + x.y * cz;
      #pragma unroll
      for (int hh = 0; hh < 8; ++hh) {
        const float a = Al[hh * 6 + r];
        qe[hh] = fmaf(a, re, qe[hh]);
        qo[hh] = fmaf(a, ro, qo[hh]);
      }
    }
    const float qs = SCALING / 6.f;
    #pragma unroll
    for (int hh = 0; hh < 8; ++hh) {
      const float x0 = qe[hh] * qs, x1 = qo[hh] * qs;
      const uint16_t h0 = bfhi(x0), h1 = bfhi(x1);
      const size_t eb = (tbase + (size_t)hh * SLEN * HD + 2 * j) >> 1;
      ((uint32_t*)qhg)[eb] = (uint32_t)h0 | ((uint32_t)h1 << 16);
      ((uint32_t*)qlg)[eb] = packbf2(x0 - bf2f(h0), x1 - bf2f(h1));
    }
  } else {
    const int j = tid - 128;
    const float cz = fc[s * 128 + j], sz = fs[s * 128 + j];
    float ke_[8], ko_[8], ve_[8], vo_[8];
    #pragma unroll
    for (int hh = 0; hh < 8; ++hh) { ke_[hh]=0.f; ko_[hh]=0.f; ve_[hh]=0.f; vo_[hh]=0.f; }
    #pragma unroll
    for (int r = 0; r < 2; ++r) {
      const float2 xk = *(const float2*)&Bk[(size_t)m * 512 + r * 256 + 2 * j];
      const float2 xv = *(const float2*)&Bv[(size_t)m * 512 + r * 256 + 2 * j];
      const float re = xk.x * cz - xk.y * sz;
      const float ro = xk.x * sz + xk.y * cz;
      #pragma unroll
      for (int hh = 0; hh < 8; ++hh) {
        const float ak = Al[48 + hh * 2 + r];
        const float av = Al[64 + hh * 2 + r];
        ke_[hh] = fmaf(ak, re, ke_[hh]);
        ko_[hh] = fmaf(ak, ro, ko_[hh]);
        ve_[hh] = fmaf(av, xv.x, ve_[hh]);
        vo_[hh] = fmaf(av, xv.y, vo_[hh]);
      }
    }
    #pragma unroll
    for (int hh = 0; hh < 8; ++hh) {
      const float x0 = ke_[hh] * 0.5f, x1 = ko_[hh] * 0.5f;
      const uint16_t h0 = bfhi(x0), h1 = bfhi(x1);
      const size_t eb = (tbase + (size_t)hh * SLEN * HD + 2 * j) >> 1;
      ((uint32_t*)khg)[eb] = (uint32_t)h0 | ((uint32_t)h1 << 16);
      ((uint32_t*)klg)[eb] = packbf2(x0 - bf2f(h0), x1 - bf2f(h1));
      ((uint32_t*)vvg)[eb] = packbf2(ve_[hh] * 0.5f, vo_[hh] * 0.5f);
    }
  }
}

// ------------- zero att + den (harness poisons ws; atomics need zeros) ----------------
__global__ __launch_bounds__(256) void zero_acc(float* __restrict__ att,
                                                float* __restrict__ den) {
  const int idx = blockIdx.x * 256 + threadIdx.x;   // float4 index
  const float4 z = {0.f, 0.f, 0.f, 0.f};
  *(float4*)&att[(size_t)idx * 4] = z;              // grid covers 8,388,608 floats
  if (idx < 8192) *(float4*)&den[(size_t)idx * 4] = z;   // 32768 floats
}

// ------------- causal softcapped attention v8 (validated r17, unchanged) --------------
#define KLD 264
#define VLD 40
#define PLD 40
__global__ __launch_bounds__(256, 2) void attn_mfma(
    const uint16_t* __restrict__ qhg, const uint16_t* __restrict__ qlg,
    const uint16_t* __restrict__ khg, const uint16_t* __restrict__ klg,
    const uint16_t* __restrict__ vvg, float* __restrict__ att,
    float* __restrict__ den_g) {
  __shared__ uint16_t Khs[32 * KLD];
  __shared__ uint16_t Kls[32 * KLD];
  __shared__ uint16_t Vts[256 * VLD];
  __shared__ uint16_t Ps[4 * 16 * PLD];
  const int tid = threadIdx.x;
  const int lane = tid & 63;
  const int w = tid >> 6;
  const int l15 = lane & 15;
  const int l4 = lane >> 4;
  const int bid = blockIdx.x;
  const int bh = bid & 15;
  const int p = (bid >> 4) & 15;
  const int hf = bid >> 8;
  const int b = bh >> 3, h = bh & 7;
  const size_t base = (size_t)bh * SLEN * HD;
  const uint16_t* khb = &khg[base];
  const uint16_t* klb = &klg[base];
  const uint16_t* vvb = &vvg[base];
  const int sr = tid & 31;
  const int sc = (tid >> 5) * 32;

  #pragma unroll
  for (int sub = 0; sub < 2; ++sub) {
    const int qt = (sub == 0) ? (31 - p) : p;
    const int q0 = qt * 64;
    short8 qh[8], ql[8];
    {
      const uint16_t* qhp = &qhg[base + (size_t)(q0 + w * 16 + l15) * HD + 8 * l4];
      const uint16_t* qlp = &qlg[base + (size_t)(q0 + w * 16 + l15) * HD + 8 * l4];
      #pragma unroll
      for (int f = 0; f < 8; ++f) {
        qh[f] = *(const short8*)&qhp[32 * f];
        ql[f] = *(const short8*)&qlp[32 * f];
      }
    }
    f32x4 acc[16];
    #pragma unroll
    for (int df = 0; df < 16; ++df) acc[df] = (f32x4){0.f, 0.f, 0.f, 0.f};
    float den[4] = {0.f, 0.f, 0.f, 0.f};

    const int myrow = q0 + w * 16 + l4 * 4;
    const int rowmax = q0 + w * 16 + 15;
    const int nkt = 2 * qt + 2;

    short8 kh8[4], kl8[4], vv8[4];
    {
      const uint16_t* kp = &khb[(size_t)(hf * 32 + sr) * HD + sc];
      const uint16_t* lp = &klb[(size_t)(hf * 32 + sr) * HD + sc];
      const uint16_t* vp = &vvb[(size_t)(hf * 32 + sr) * HD + sc];
      #pragma unroll
      for (int j = 0; j < 4; ++j) {
        kh8[j] = *(const short8*)&kp[8 * j];
        kl8[j] = *(const short8*)&lp[8 * j];
        vv8[j] = *(const short8*)&vp[8 * j];
      }
    }

    for (int kt = hf; kt < nkt; kt += 2) {
      const int k0 = kt * 32;
      #pragma unroll
      for (int j = 0; j < 4; ++j) {
        *(short8*)&Khs[sr * KLD + sc + 8 * j] = kh8[j];
        *(short8*)&Kls[sr * KLD + sc + 8 * j] = kl8[j];
      }
      #pragma unroll
      for (int j = 0; j < 4; ++j) {
        const short8 s8 = vv8[j];
        #pragma unroll
        for (int i = 0; i < 8; ++i)
          Vts[(sc + 8 * j + i) * VLD + sr] = (uint16_t)s8[i];
      }
      if (kt + 2 < nkt) {
        const uint16_t* kp = &khb[(size_t)(k0 + 64 + sr) * HD + sc];
        const uint16_t* lp = &klb[(size_t)(k0 + 64 + sr) * HD + sc];
        const uint16_t* vp = &vvb[(size_t)(k0 + 64 + sr) * HD + sc];
        #pragma unroll
        for (int j = 0; j < 4; ++j) {
          kh8[j] = *(const short8*)&kp[8 * j];
          kl8[j] = *(const short8*)&lp[8 * j];
          vv8[j] = *(const short8*)&vp[8 * j];
        }
      }
      asm volatile("s_waitcnt lgkmcnt(0)" ::: "memory");
      __builtin_amdgcn_sched_barrier(0);
      __builtin_amdgcn_s_barrier();
      __builtin_amdgcn_sched_barrier(0);
      if (k0 <= rowmax) {
        f32x4 sfr[2];
        __builtin_amdgcn_s_setprio(1);
        #pragma unroll
        for (int kf = 0; kf < 2; ++kf) {
          f32x4 c0 = (f32x4){0.f, 0.f, 0.f, 0.f};
          f32x4 c1 = c0, c2 = c0;
          #pragma unroll
          for (int dc = 0; dc < 8; ++dc) {
            const int off = (16 * kf + l15) * KLD + 32 * dc + 8 * l4;
            const short8 kh = *(const short8*)&Khs[off];
            const short8 kl = *(const short8*)&Kls[off];
            c0 = __builtin_amdgcn_mfma_f32_16x16x32_bf16(qh[dc], kh, c0, 0, 0, 0);
            c1 = __builtin_amdgcn_mfma_f32_16x16x32_bf16(qh[dc], kl, c1, 0, 0, 0);
            c2 = __builtin_amdgcn_mfma_f32_16x16x32_bf16(ql[dc], kh, c2, 0, 0, 0);
          }
          sfr[kf] = (c0 + c1) + c2;
        }
        __builtin_amdgcn_s_setprio(0);
        uint16_t* pw = &Ps[w * 16 * PLD];
        #pragma unroll
        for (int kf = 0; kf < 2; ++kf) {
          #pragma unroll
          for (int ri = 0; ri < 4; ++ri) {
            const float pd = sfr[kf][ri];
            const float t1 = exp2f(pd * 0.0577078016f);
            float e = exp2f(-144.26950409f * __builtin_amdgcn_rcpf(t1 + 1.f));
            if (k0 + 16 * kf + l15 > myrow + ri) e = 0.f;
            den[ri] += e;
            pw[(l4 * 4 + ri) * PLD + 16 * kf + l15] = bfhi(e);
          }
        }
        const short8 pa = *(const short8*)&pw[l15 * PLD + 8 * l4];
        __builtin_amdgcn_s_setprio(1);
        #pragma unroll
        for (int df = 0; df < 16; ++df) {
          const short8 vb = *(const short8*)&Vts[(16 * df + l15) * VLD + 8 * l4];
          acc[df] = __builtin_amdgcn_mfma_f32_16x16x32_bf16(pa, vb, acc[df], 0, 0, 0);
        }
        __builtin_amdgcn_s_setprio(0);
      }
      __builtin_amdgcn_sched_barrier(0);
      __builtin_amdgcn_s_barrier();
      __builtin_amdgcn_sched_barrier(0);
    }
    #pragma unroll
    for (int ri = 0; ri < 4; ++ri) {
      den[ri] += __shfl_xor(den[ri], 1);
      den[ri] += __shfl_xor(den[ri], 2);
      den[ri] += __shfl_xor(den[ri], 4);
      den[ri] += __shfl_xor(den[ri], 8);
    }
    if (l15 == 0) {
      #pragma unroll
      for (int ri = 0; ri < 4; ++ri)
        atomAddF(&den_g[(size_t)bh * SLEN + myrow + ri], den[ri]);
    }
    float* op = &att[((size_t)(b * SLEN + myrow)) * (NH * HD) + h * HD + l15];
    #pragma unroll
    for (int ri = 0; ri < 4; ++ri)
      #pragma unroll
      for (int df = 0; df < 16; ++df)
        atomAddF(&op[(size_t)ri * (NH * HD) + 16 * df], acc[df][ri]);
  }
}

extern "C" void kernel_launch(void* const* d_in, const int* in_sizes, int n_in,
                              void* d_out, int out_size, void* d_ws, size_t ws_size,
                              hipStream_t stream) {
  const float* hs  = (const float*)d_in[0];
  const float* fc  = (const float*)d_in[1];
  const float* fs  = (const float*)d_in[2];
  // d_in[3] = mask: pure causal, handled analytically.
  const float* WAq = (const float*)d_in[4];
  const float* WAk = (const float*)d_in[5];
  const float* WAv = (const float*)d_in[6];
  const float* WBq = (const float*)d_in[7];
  const float* WBk = (const float*)d_in[8];
  const float* WBv = (const float*)d_in[9];
  const float* Wo  = (const float*)d_in[10];
  float* out = (float*)d_out;

  // Workspace (floats), peak 127 MB. Lifetime-based aliasing:
  //  [0,10.49M)   Bq/Bk/Bv fp32 (proj->rope); att=[0,8.39M), den=Bv[0] (post-rope)
  //  [10.49,31.46M) q/k/v bf16 (rope->attn)
  //     pre-rope:  hsh/hsl @10.49M (conv->proj), wfh/wfl @18.87M (conv->proj)
  //     post-attn: atth/attl @10.49M, wofh/wofl @18.87M (norm_conv->gemm_norm)
  //  [31.46M,31.79M) Aall
  float* ws   = (float*)d_ws;
  float* Bq   = ws;
  float* Bk   = Bq + (size_t)MTOT * 1536;
  float* Bv   = Bk + (size_t)MTOT * 512;
  uint16_t* qh = (uint16_t*)(Bv + (size_t)MTOT * 512);
  uint16_t* ql = qh + (size_t)8388608;
  uint16_t* kh = ql + (size_t)8388608;
  uint16_t* kl = kh + (size_t)8388608;
  uint16_t* vv = kl + (size_t)8388608;
  float* Aall = ws + (size_t)31457280;
  float* att  = ws;
  float* den  = Bv;
  uint16_t* hsh  = (uint16_t*)(ws + (size_t)10485760);   // 8,388,608 shorts
  uint16_t* hsl  = hsh + (size_t)8388608;
  uint16_t* wfh  = (uint16_t*)(ws + (size_t)18874368);   // 5,505,024 shorts
  uint16_t* wfl  = wfh + (size_t)5505024;
  uint16_t* atth = (uint16_t*)(ws + (size_t)10485760);   // 8,388,608 shorts
  uint16_t* attl = atth + (size_t)8388608;
  uint16_t* wofh = (uint16_t*)(ws + (size_t)18874368);   // 4,194,304 shorts
  uint16_t* wofl = wofh + (size_t)4194304;

  conv_pre<<<dim3(4096 + 2688), 256, 0, stream>>>(hs, WBq, WBk, WBv, WAq, WAk, WAv,
                                                  hsh, hsl, wfh, wfl);
  gemm_proj<<<dim3(672), 256, 0, stream>>>(hsh, hsl, wfh, wfl, Bq, Bk, Bv, Aall);
  qkv_rope<<<MTOT, 256, 0, stream>>>(Aall, Bq, Bk, Bv, fc, fs, qh, ql, kh, kl, vv);
  zero_acc<<<8192, 256, 0, stream>>>(att, den);
  attn_mfma<<<dim3(512), 256, 0, stream>>>(qh, ql, kh, kl, vv, att, den);
  norm_conv<<<dim3(4096 + 2048), 256, 0, stream>>>(att, den, Wo, atth, attl, wofh, wofl);
  gemm_norm<<<dim3(512), 256, 0, stream>>>(atth, attl, wofh, wofl, out);
}